// Round 6
// baseline (328.832 us; speedup 1.0000x reference)
//
#include <hip/hip_runtime.h>
#include <hip/hip_bf16.h>

#define B_  2
#define S_  2048
#define DM_ 1024
#define H_  16
#define DK_ 64
#define SK_ 40   // SAMPLE_K
#define U_  40   // top-k u
#define CH_ 128  // attn chunk columns
#define NCH_ (S_ / CH_)  // 16
#define VCH_ 64  // vmean chunks per (b,h)

typedef __attribute__((ext_vector_type(8))) short short8;
typedef __attribute__((ext_vector_type(4))) short short4v;
typedef __attribute__((ext_vector_type(4))) float f32x4;
typedef unsigned short u16;

union BF16S { __hip_bfloat16 h; short s; };
static __device__ __forceinline__ short f2bs(float x) {
    BF16S u; u.h = __float2bfloat16(x); return u.s;
}
static __device__ __forceinline__ void fsplit(float x, short& h, short& l) {
    BF16S u; u.h = __float2bfloat16(x);
    h = u.s;
    BF16S v; v.h = __float2bfloat16(x - __bfloat162float(u.h));
    l = v.s;
}

// async global->LDS, 16 bytes per lane. LDS dest must be wave-uniform base + lane*16.
static __device__ __forceinline__ void gload16(const void* g, void* s) {
    __builtin_amdgcn_global_load_lds(
        (const __attribute__((address_space(1))) void*)g,
        (__attribute__((address_space(3))) void*)s, 16, 0, 0);
}

// LDS bank swizzle (involution): flip byte bits [6:4] with bits [9:7] (row bits 1..3).
// Turns the 8-way conflict of 64B-row ds_read_b128 column reads into 2-way (free).
static __device__ __forceinline__ int swzb(int b) {
    return b ^ (((b >> 7) & 7) << 4);
}

// =====================================================================
// NEW PATH kernels
// =====================================================================

// One-dispatch prep: [0,2048) hs->hi/lo planes, [2048,3072) weight transpose+cvt,
// [3072] zero the vmean accumulator.
__global__ __launch_bounds__(256) void conv_all(
    const float* __restrict__ hs,
    const float* __restrict__ wq, const float* __restrict__ wk,
    const float* __restrict__ wv, const float* __restrict__ fcw,
    u16* __restrict__ Ahi, u16* __restrict__ Alo,
    u16* __restrict__ qh, u16* __restrict__ ql,
    u16* __restrict__ kh, u16* __restrict__ kl,
    u16* __restrict__ vh, u16* __restrict__ fh,
    float* __restrict__ vmean_acc) {
    __shared__ float T[64][65];
    int bid = blockIdx.x, tid = threadIdx.x;
    if (bid < 2048) {
        size_t i = ((size_t)bid * 256 + tid) * 8;
        float a[8];
        *(float4*)&a[0] = *(const float4*)(hs + i);
        *(float4*)&a[4] = *(const float4*)(hs + i + 4);
        short8 h, l;
#pragma unroll
        for (int e = 0; e < 8; ++e) {
            short hh, ll;
            fsplit(a[e], hh, ll);
            h[e] = hh; l[e] = ll;
        }
        *(short8*)&Ahi[i] = h;
        *(short8*)&Alo[i] = l;
        return;
    }
    if (bid >= 3072) {
        for (int j = tid; j < B_ * H_ * DK_; j += 256) vmean_acc[j] = 0.f;
        return;
    }
    int mode = (bid - 2048) >> 8;
    int tb = (bid - 2048) & 255;
    int ty = tb >> 4, tx = tb & 15;
    const float* src = (mode == 0) ? wq : (mode == 1) ? wk : (mode == 2) ? wv : fcw;
    u16* dh = (mode == 0) ? qh : (mode == 1) ? kh : (mode == 2) ? vh : fh;
    u16* dl = (mode == 0) ? ql : kl;
    bool split = (mode < 2);
    int r = tid >> 2, cq = (tid & 3) * 16;

    const float* sp = src + (size_t)(ty * 64 + r) * 1024 + tx * 64 + cq;
#pragma unroll
    for (int j = 0; j < 16; j += 4) *(float4*)&T[r][cq + j] = *(const float4*)(sp + j);
    __syncthreads();

    short8 h0, h1, l0, l1;
#pragma unroll
    for (int j = 0; j < 8; ++j) {
        short hh, ll;
        fsplit(T[cq + j][r], hh, ll);
        h0[j] = hh; l0[j] = ll;
        fsplit(T[cq + 8 + j][r], hh, ll);
        h1[j] = hh; l1[j] = ll;
    }
    size_t off = (size_t)(tx * 64 + r) * 1024 + ty * 64 + cq;
    *(short8*)&dh[off] = h0;
    *(short8*)&dh[off + 8] = h1;
    if (split) {
        *(short8*)&dl[off] = l0;
        *(short8*)&dl[off + 8] = l1;
    }
}

// merged q+k projection: one block stages the shared A panel (hi,lo) once and
// both weight panels -> 96 MFMA per wave-step from 24 ds_reads (was 2x16 reads
// for 2x48 MFMA in separate blocks). 96 KB LDS, 2-deep counted-vmcnt pipeline,
// swizzled LDS, XCD-chunked. Per-accumulator MFMA order identical to v7.
__global__ __launch_bounds__(256, 2) void gemm_qk_v8(
    const u16* __restrict__ Ahi, const u16* __restrict__ Alo,
    const u16* __restrict__ Wqh, const u16* __restrict__ Wql,
    const u16* __restrict__ Wkh, const u16* __restrict__ Wkl,
    float* __restrict__ q, float* __restrict__ k) {
    // [buf][plane: Ah,Al,Bqh,Bql,Bkh,Bkl][128*32] = 96 KB
    __shared__ alignas(16) u16 lds[2][6][128 * 32];
    int bid = (int)blockIdx.x;
    int xcd = bid & 7, ii = bid >> 3;          // ii in 0..31
    int rr = xcd * 32 + ii;                    // tile 0..255
    int by = rr >> 3, bx = rr & 7;

    int tid = threadIdx.x, lane = tid & 63, w = tid >> 6;
    int wr = w >> 1, wc = w & 1;
    int ml = lane & 15, kq = lane >> 4;

    f32x4 accq[4][4], acck[4][4];
#pragma unroll
    for (int i = 0; i < 4; ++i)
#pragma unroll
        for (int j = 0; j < 4; ++j) {
            accq[i][j] = (f32x4){0.f, 0.f, 0.f, 0.f};
            acck[i][j] = (f32x4){0.f, 0.f, 0.f, 0.f};
        }

    const u16* Agh = Ahi + (size_t)(by * 128) * 1024;
    const u16* Agl = Alo + (size_t)(by * 128) * 1024;
    const u16* Bqh_g = Wqh + (size_t)(bx * 128) * 1024;
    const u16* Bql_g = Wql + (size_t)(bx * 128) * 1024;
    const u16* Bkh_g = Wkh + (size_t)(bx * 128) * 1024;
    const u16* Bkl_g = Wkl + (size_t)(bx * 128) * 1024;

    int pl0 = tid * 16, pl1 = 4096 + tid * 16;
    int d0 = swzb(pl0), d1 = swzb(pl1);
    int gs0 = (d0 >> 6) * 1024 + ((d0 & 63) >> 1);
    int gs1 = (d1 >> 6) * 1024 + ((d1 & 63) >> 1);
    int ld0 = tid * 8, ld1 = 2048 + tid * 8;

    int offA[4], offB[4];
#pragma unroll
    for (int mt = 0; mt < 4; ++mt) {
        int d = (wr * 64 + mt * 16 + ml) * 64 + kq * 16;
        offA[mt] = swzb(d);
    }
#pragma unroll
    for (int nt = 0; nt < 4; ++nt) {
        int d = (wc * 64 + nt * 16 + ml) * 64 + kq * 16;
        offB[nt] = swzb(d);
    }

    auto STAGE = [&](int bf, int k0) {
        gload16(Agh + gs0 + k0, &lds[bf][0][ld0]);
        gload16(Agh + gs1 + k0, &lds[bf][0][ld1]);
        gload16(Agl + gs0 + k0, &lds[bf][1][ld0]);
        gload16(Agl + gs1 + k0, &lds[bf][1][ld1]);
        gload16(Bqh_g + gs0 + k0, &lds[bf][2][ld0]);
        gload16(Bqh_g + gs1 + k0, &lds[bf][2][ld1]);
        gload16(Bql_g + gs0 + k0, &lds[bf][3][ld0]);
        gload16(Bql_g + gs1 + k0, &lds[bf][3][ld1]);
        gload16(Bkh_g + gs0 + k0, &lds[bf][4][ld0]);
        gload16(Bkh_g + gs1 + k0, &lds[bf][4][ld1]);
        gload16(Bkl_g + gs0 + k0, &lds[bf][5][ld0]);
        gload16(Bkl_g + gs1 + k0, &lds[bf][5][ld1]);
    };

    STAGE(0, 0);
    STAGE(1, 32);
    int cur = 0;
    for (int t = 0; t < 32; ++t) {
        if (t == 31) asm volatile("s_waitcnt vmcnt(0)" ::: "memory");
        else         asm volatile("s_waitcnt vmcnt(12)" ::: "memory");
        __builtin_amdgcn_s_barrier();
        __builtin_amdgcn_sched_barrier(0);

        const char* Ah_ = (const char*)lds[cur][0];
        const char* Al_ = (const char*)lds[cur][1];
        short8 a_h[4], a_l[4], b_h[4], b_l[4];
#pragma unroll
        for (int mt = 0; mt < 4; ++mt) a_h[mt] = *(const short8*)(Ah_ + offA[mt]);
#pragma unroll
        for (int mt = 0; mt < 4; ++mt) a_l[mt] = *(const short8*)(Al_ + offA[mt]);

        // ---- q: hi*hi then corrections (same per-acc order as v7)
        {
            const char* Bh_ = (const char*)lds[cur][2];
            const char* Bl_ = (const char*)lds[cur][3];
#pragma unroll
            for (int nt = 0; nt < 4; ++nt) b_h[nt] = *(const short8*)(Bh_ + offB[nt]);
#pragma unroll
            for (int nt = 0; nt < 4; ++nt) b_l[nt] = *(const short8*)(Bl_ + offB[nt]);
            __builtin_amdgcn_s_setprio(1);
#pragma unroll
            for (int mt = 0; mt < 4; ++mt)
#pragma unroll
                for (int nt = 0; nt < 4; ++nt)
                    accq[mt][nt] = __builtin_amdgcn_mfma_f32_16x16x32_bf16(a_h[mt], b_h[nt], accq[mt][nt], 0, 0, 0);
#pragma unroll
            for (int mt = 0; mt < 4; ++mt)
#pragma unroll
                for (int nt = 0; nt < 4; ++nt) {
                    accq[mt][nt] = __builtin_amdgcn_mfma_f32_16x16x32_bf16(a_h[mt], b_l[nt], accq[mt][nt], 0, 0, 0);
                    accq[mt][nt] = __builtin_amdgcn_mfma_f32_16x16x32_bf16(a_l[mt], b_h[nt], accq[mt][nt], 0, 0, 0);
                }
            __builtin_amdgcn_s_setprio(0);
        }
        // ---- k: reuse b-frag registers
        {
            const char* Bh_ = (const char*)lds[cur][4];
            const char* Bl_ = (const char*)lds[cur][5];
#pragma unroll
            for (int nt = 0; nt < 4; ++nt) b_h[nt] = *(const short8*)(Bh_ + offB[nt]);
#pragma unroll
            for (int nt = 0; nt < 4; ++nt) b_l[nt] = *(const short8*)(Bl_ + offB[nt]);
            __builtin_amdgcn_s_setprio(1);
#pragma unroll
            for (int mt = 0; mt < 4; ++mt)
#pragma unroll
                for (int nt = 0; nt < 4; ++nt)
                    acck[mt][nt] = __builtin_amdgcn_mfma_f32_16x16x32_bf16(a_h[mt], b_h[nt], acck[mt][nt], 0, 0, 0);
#pragma unroll
            for (int mt = 0; mt < 4; ++mt)
#pragma unroll
                for (int nt = 0; nt < 4; ++nt) {
                    acck[mt][nt] = __builtin_amdgcn_mfma_f32_16x16x32_bf16(a_h[mt], b_l[nt], acck[mt][nt], 0, 0, 0);
                    acck[mt][nt] = __builtin_amdgcn_mfma_f32_16x16x32_bf16(a_l[mt], b_h[nt], acck[mt][nt], 0, 0, 0);
                }
            __builtin_amdgcn_s_setprio(0);
        }

        if (t < 31) {
            __builtin_amdgcn_s_barrier();       // all waves consumed buf[cur]
            __builtin_amdgcn_sched_barrier(0);
            if (t < 30) STAGE(cur, (t + 2) * 32);
        }
        cur ^= 1;
    }
#pragma unroll
    for (int mt = 0; mt < 4; ++mt)
#pragma unroll
        for (int nt = 0; nt < 4; ++nt)
#pragma unroll
            for (int r2 = 0; r2 < 4; ++r2) {
                int row = by * 128 + wr * 64 + mt * 16 + kq * 4 + r2;
                int col = bx * 128 + wc * 64 + nt * 16 + ml;
                q[(size_t)row * 1024 + col] = accq[mt][nt][r2] * 0.125f;
                k[(size_t)row * 1024 + col] = acck[mt][nt][r2];
            }
}

// v projection: plain bf16, 32 KB LDS, same pipeline. vmean column-sum epilogue.
__global__ __launch_bounds__(256) void gemm_v_v8(const u16* __restrict__ Ahi,
                                                 const u16* __restrict__ Wvh,
                                                 float* __restrict__ v,
                                                 float* __restrict__ vmean_acc) {
    __shared__ alignas(16) u16 lds[2][2][128 * 32];  // 32 KB
    int bid = (int)blockIdx.x;
    int xcd = bid & 7, ii = bid >> 3;          // 0..31
    int rr = xcd * 32 + ii;
    int by = rr >> 3, bx = rr & 7;

    int tid = threadIdx.x, lane = tid & 63, w = tid >> 6;
    int wr = w >> 1, wc = w & 1;
    int ml = lane & 15, kq = lane >> 4;

    f32x4 acc[4][4];
#pragma unroll
    for (int i = 0; i < 4; ++i)
#pragma unroll
        for (int j = 0; j < 4; ++j) acc[i][j] = (f32x4){0.f, 0.f, 0.f, 0.f};

    const u16* Agh = Ahi + (size_t)(by * 128) * 1024;
    const u16* Bgh = Wvh + (size_t)(bx * 128) * 1024;

    int pl0 = tid * 16, pl1 = 4096 + tid * 16;
    int d0 = swzb(pl0), d1 = swzb(pl1);
    int gs0 = (d0 >> 6) * 1024 + ((d0 & 63) >> 1);
    int gs1 = (d1 >> 6) * 1024 + ((d1 & 63) >> 1);
    int ld0 = tid * 8, ld1 = 2048 + tid * 8;

    int offA[4], offB[4];
#pragma unroll
    for (int mt = 0; mt < 4; ++mt) {
        int d = (wr * 64 + mt * 16 + ml) * 64 + kq * 16;
        offA[mt] = swzb(d);
    }
#pragma unroll
    for (int nt = 0; nt < 4; ++nt) {
        int d = (wc * 64 + nt * 16 + ml) * 64 + kq * 16;
        offB[nt] = swzb(d);
    }

    auto STAGE = [&](int bf, int k0) {
        gload16(Agh + gs0 + k0, &lds[bf][0][ld0]);
        gload16(Agh + gs1 + k0, &lds[bf][0][ld1]);
        gload16(Bgh + gs0 + k0, &lds[bf][1][ld0]);
        gload16(Bgh + gs1 + k0, &lds[bf][1][ld1]);
    };

    STAGE(0, 0);
    STAGE(1, 32);
    int cur = 0;
    for (int t = 0; t < 32; ++t) {
        if (t == 31) asm volatile("s_waitcnt vmcnt(0)" ::: "memory");
        else         asm volatile("s_waitcnt vmcnt(4)" ::: "memory");
        __builtin_amdgcn_s_barrier();
        __builtin_amdgcn_sched_barrier(0);

        const char* Ah_ = (const char*)lds[cur][0];
        const char* Bh_ = (const char*)lds[cur][1];
        short8 a_h[4], b_h[4];
#pragma unroll
        for (int mt = 0; mt < 4; ++mt) a_h[mt] = *(const short8*)(Ah_ + offA[mt]);
#pragma unroll
        for (int nt = 0; nt < 4; ++nt) b_h[nt] = *(const short8*)(Bh_ + offB[nt]);

        __builtin_amdgcn_s_setprio(1);
#pragma unroll
        for (int mt = 0; mt < 4; ++mt)
#pragma unroll
            for (int nt = 0; nt < 4; ++nt)
                acc[mt][nt] = __builtin_amdgcn_mfma_f32_16x16x32_bf16(a_h[mt], b_h[nt], acc[mt][nt], 0, 0, 0);
        __builtin_amdgcn_s_setprio(0);

        if (t < 31) {
            __builtin_amdgcn_s_barrier();
            __builtin_amdgcn_sched_barrier(0);
            if (t < 30) STAGE(cur, (t + 2) * 32);
        }
        cur ^= 1;
    }
#pragma unroll
    for (int mt = 0; mt < 4; ++mt)
#pragma unroll
        for (int nt = 0; nt < 4; ++nt)
#pragma unroll
            for (int r2 = 0; r2 < 4; ++r2) {
                int row = by * 128 + wr * 64 + mt * 16 + kq * 4 + r2;
                int col = bx * 128 + wc * 64 + nt * 16 + ml;
                v[(size_t)row * 1024 + col] = acc[mt][nt][r2];
            }
    {
        // per-column partial sums of this block's 128 rows -> vmean accumulator
        int b = by >> 4;
#pragma unroll
        for (int nt = 0; nt < 4; ++nt) {
            float s = 0.f;
#pragma unroll
            for (int mt = 0; mt < 4; ++mt)
#pragma unroll
                for (int r2 = 0; r2 < 4; ++r2) s += acc[mt][nt][r2];
            s += __shfl_xor(s, 16, 64);
            s += __shfl_xor(s, 32, 64);
            if (kq == 0) {
                int col = bx * 128 + wc * 64 + nt * 16 + ml;
                int h = col >> 6, d = col & 63;
                atomicAdd(&vmean_acc[(b * H_ + h) * DK_ + d], s);
            }
        }
    }
}

// m-score v4: wave per (b,l), all 16 heads. Contiguous 2KB wave loads of each
// sampled k-row half (vs 8-segment 32B gathers). Bit-identical to v3: same
// per-lane 8-elem dot, same shfl_xor 1/2/4 tree, 8 partial sums combined in the
// exact binary-tree order of the old shfl 8/16/32 reduction.
__global__ void m_score_v4(const float* __restrict__ q, const float* __restrict__ k,
                           const int* __restrict__ idxs, float* __restrict__ m_out,
                           int* __restrict__ rowmap) {
    int gw = blockIdx.x * 4 + (threadIdx.x >> 6);  // 0..4095 = b*2048 + l
    int lane = threadIdx.x & 63;
    int l = gw & (S_ - 1);
    int b = gw >> 11;
    int h8 = lane >> 3, dc = lane & 7;

    const float* qr = q + ((size_t)(b * S_ + l)) * DM_ + h8 * DK_ + dc * 8;
    float4 qa0 = *(const float4*)qr;
    float4 qa1 = *(const float4*)(qr + 4);
    float4 qb0 = *(const float4*)(qr + 512);
    float4 qb1 = *(const float4*)(qr + 516);
    const float* kb = k + (size_t)b * S_ * DM_ + h8 * DK_ + dc * 8;

    float p0[8], p1[8];
#pragma unroll
    for (int j = 0; j < 8; ++j) { p0[j] = 0.f; p1[j] = 0.f; }
    float mx0 = -INFINITY, mx1 = -INFINITY;

#pragma unroll 8
    for (int s = 0; s < SK_; ++s) {
        int idx = idxs[l * SK_ + s];
        idx = (idx < 0) ? 0 : (idx >= S_ ? S_ - 1 : idx);
        const float* kr = kb + (size_t)idx * DM_;
        {
            float4 k0 = *(const float4*)kr;
            float4 k1 = *(const float4*)(kr + 4);
            float d = qa0.x * k0.x + qa0.y * k0.y + qa0.z * k0.z + qa0.w * k0.w +
                      qa1.x * k1.x + qa1.y * k1.y + qa1.z * k1.z + qa1.w * k1.w;
            d += __shfl_xor(d, 1, 64);
            d += __shfl_xor(d, 2, 64);
            d += __shfl_xor(d, 4, 64);
            mx0 = fmaxf(mx0, d);
            p0[s & 7] += d;
        }
        {
            float4 k0 = *(const float4*)(kr + 512);
            float4 k1 = *(const float4*)(kr + 516);
            float d = qb0.x * k0.x + qb0.y * k0.y + qb0.z * k0.z + qb0.w * k0.w +
                      qb1.x * k1.x + qb1.y * k1.y + qb1.z * k1.z + qb1.w * k1.w;
            d += __shfl_xor(d, 1, 64);
            d += __shfl_xor(d, 2, 64);
            d += __shfl_xor(d, 4, 64);
            mx1 = fmaxf(mx1, d);
            p1[s & 7] += d;
        }
    }
    if (dc == 0) {
        float sm0 = ((p0[0] + p0[1]) + (p0[2] + p0[3])) + ((p0[4] + p0[5]) + (p0[6] + p0[7]));
        float sm1 = ((p1[0] + p1[1]) + (p1[2] + p1[3])) + ((p1[4] + p1[5]) + (p1[6] + p1[7]));
        size_t o0 = (size_t)(b * H_ + h8) * S_ + l;
        size_t o1 = (size_t)(b * H_ + 8 + h8) * S_ + l;
        m_out[o0] = mx0 - sm0 * (1.f / (float)S_);
        m_out[o1] = mx1 - sm1 * (1.f / (float)S_);
        rowmap[o0] = -1;
        rowmap[o1] = -1;
    }
}

// ctx one-pass with INLINE chunk-combine for selected rows (attn_combine fused).
// Each selected (bh,u) appears exactly once -> no redundant combine work.
__global__ void ctx_fill4(const float* __restrict__ vm,
                          const float* __restrict__ Opart,
                          const float* __restrict__ Mpart,
                          const float* __restrict__ Lpart,
                          const int* __restrict__ rowmap, u16* __restrict__ ctx) {
    size_t i = ((size_t)blockIdx.x * 256 + threadIdx.x) * 4;  // over B*S*DM
    int c = (int)(i & (DM_ - 1));
    size_t bl = i >> 10;
    int l = (int)(bl & (S_ - 1));
    int b = (int)(bl >> 11);
    int h = c >> 6, d = c & (DK_ - 1);
    int bh = b * H_ + h;
    int u = rowmap[(size_t)bh * S_ + l];
    float4 val;
    if (u >= 0) {
        float m = -1e30f;
#pragma unroll
        for (int c2 = 0; c2 < NCH_; ++c2)
            m = fmaxf(m, Mpart[(size_t)(bh * NCH_ + c2) * 48 + u]);
        float lf = 0.f;
        float o0 = 0.f, o1 = 0.f, o2 = 0.f, o3 = 0.f;
#pragma unroll
        for (int c2 = 0; c2 < NCH_; ++c2) {
            float wf = __expf(Mpart[(size_t)(bh * NCH_ + c2) * 48 + u] - m);
            lf += wf * Lpart[(size_t)(bh * NCH_ + c2) * 48 + u];
            const float* op = Opart + ((size_t)(bh * NCH_ + c2) * 48 + u) * 64 + d;
            o0 += wf * op[0];
            o1 += wf * op[1];
            o2 += wf * op[2];
            o3 += wf * op[3];
        }
        val.x = o0 / lf; val.y = o1 / lf; val.z = o2 / lf; val.w = o3 / lf;
    } else {
        val = *(const float4*)(vm + bh * DK_ + d);
        const float is = 1.f / (float)S_;
        val.x *= is; val.y *= is; val.z *= is; val.w *= is;
    }
    short4v o;
    o[0] = f2bs(val.x); o[1] = f2bs(val.y); o[2] = f2bs(val.z); o[3] = f2bs(val.w);
    *(short4v*)&ctx[i] = o;
}

// fc GEMM: ctx(bf16) @ FcT(bf16)^T -> fp32. Tile 128x64, BK=32,
// reordered 2-deep pipeline + swizzled LDS, XCD-chunked.
__global__ __launch_bounds__(256) void gemm_fc_v7(const u16* __restrict__ A,
                                                  const u16* __restrict__ Bt,
                                                  float* __restrict__ C) {
    __shared__ alignas(16) u16 lds[2][6144];  // 24 KB
    int bid = (int)blockIdx.x;
    int lb = (bid & 7) * 64 + (bid >> 3);
    int by = lb >> 4, bx = lb & 15;
    int tid = threadIdx.x, lane = tid & 63, w = tid >> 6;
    int wr = w >> 1, wc = w & 1;
    int ml = lane & 15, kq = lane >> 4;

    f32x4 acc[4][2];
#pragma unroll
    for (int i = 0; i < 4; ++i)
#pragma unroll
        for (int j = 0; j < 2; ++j) acc[i][j] = (f32x4){0.f, 0.f, 0.f, 0.f};

    const u16* Ag = A + (size_t)(by * 128) * 1024;
    const u16* Bg = Bt + (size_t)(bx * 64) * 1024;

    int pl0 = tid * 16, pl1 = 4096 + tid * 16;
    int d0 = swzb(pl0), d1 = swzb(pl1);
    int gs0 = (d0 >> 6) * 1024 + ((d0 & 63) >> 1);
    int gs1 = (d1 >> 6) * 1024 + ((d1 & 63) >> 1);
    int ld0 = tid * 8, ld1 = 2048 + tid * 8, ldB = 4096 + tid * 8;

    int offA[4], offB[2];
#pragma unroll
    for (int mt = 0; mt < 4; ++mt) {
        int d = (wr * 64 + mt * 16 + ml) * 64 + kq * 16;
        offA[mt] = swzb(d);
    }
#pragma unroll
    for (int nt = 0; nt < 2; ++nt) {
        int d = (wc * 32 + nt * 16 + ml) * 64 + kq * 16;
        offB[nt] = 8192 + swzb(d);
    }

    auto STAGE = [&](int bf, int k0) {
        gload16(Ag + gs0 + k0, &lds[bf][ld0]);
        gload16(Ag + gs1 + k0, &lds[bf][ld1]);
        gload16(Bg + gs0 + k0, &lds[bf][ldB]);
    };

    STAGE(0, 0);
    STAGE(1, 32);
    int cur = 0;
    for (int t = 0; t < 32; ++t) {
        if (t == 31) asm volatile("s_waitcnt vmcnt(0)" ::: "memory");
        else         asm volatile("s_waitcnt vmcnt(3)" ::: "memory");
        __builtin_amdgcn_s_barrier();
        __builtin_amdgcn_sched_barrier(0);

        const char* L = (const char*)lds[cur];
        short8 af[4], bf2[2];
#pragma unroll
        for (int mt = 0; mt < 4; ++mt) af[mt] = *(const short8*)(L + offA[mt]);
#pragma unroll
        for (int nt = 0; nt < 2; ++nt) bf2[nt] = *(const short8*)(L + offB[nt]);

        __builtin_amdgcn_s_setprio(1);
#pragma unroll
        for (int mt = 0; mt < 4; ++mt)
#pragma unroll
            for (int nt = 0; nt < 2; ++nt)
                acc[mt][nt] = __builtin_amdgcn_mfma_f32_16x16x32_bf16(af[mt], bf2[nt], acc[mt][nt], 0, 0, 0);
        __builtin_amdgcn_s_setprio(0);

        if (t < 31) {
            __builtin_amdgcn_s_barrier();
            __builtin_amdgcn_sched_barrier(0);
            if (t < 30) STAGE(cur, (t + 2) * 32);
        }
        cur ^= 1;
    }
#pragma unroll
    for (int mt = 0; mt < 4; ++mt)
#pragma unroll
        for (int nt = 0; nt < 2; ++nt)
#pragma unroll
            for (int r = 0; r < 4; ++r) {
                int row = by * 128 + wr * 64 + mt * 16 + kq * 4 + r;
                int col = bx * 64 + wc * 32 + nt * 16 + ml;
                C[(size_t)row * 1024 + col] = acc[mt][nt][r];
            }
}

// split-K flash attention with fused Q-gather (reads q + mtop directly).
__global__ __launch_bounds__(256) void attn_chunk2(const float* __restrict__ q,
                                                   const int* __restrict__ mtop,
                                                   const float* __restrict__ k,
                                                   const float* __restrict__ v,
                                                   float* __restrict__ Opart,
                                                   float* __restrict__ Mpart,
                                                   float* __restrict__ Lpart) {
    __shared__ alignas(16) __hip_bfloat16 Qs[48][72];
    __shared__ alignas(16) __hip_bfloat16 Vt[64][136];
    __shared__ alignas(16) __hip_bfloat16 Ps[48][136];
    __shared__ float mpart[4][48], lpart[4][48];
    __shared__ float mrow[48];
    int blk = blockIdx.x;
    int bh = blk / NCH_, ch = blk % NCH_;
    int b = bh >> 4, h = bh & 15;
    int c0 = ch * CH_;
    int tid = threadIdx.x, lane = tid & 63, w = tid >> 6;
    int ml = lane & 15, kq = lane >> 4;

    {
        int u = tid >> 2, dq = (tid & 3) * 16;
        if (u < U_) {
            int row = mtop[bh * U_ + u];
            row = (row < 0) ? 0 : (row >= S_ ? S_ - 1 : row);
            const float* src = q + ((size_t)(b * S_ + row)) * DM_ + h * DK_ + dq;
#pragma unroll
            for (int j = 0; j < 16; j += 4) {
                float4 v4 = *(const float4*)(src + j);
                Qs[u][dq + j + 0] = __float2bfloat16(v4.x);
                Qs[u][dq + j + 1] = __float2bfloat16(v4.y);
                Qs[u][dq + j + 2] = __float2bfloat16(v4.z);
                Qs[u][dq + j + 3] = __float2bfloat16(v4.w);
            }
        } else if (u < 48) {
#pragma unroll
            for (int j = 0; j < 16; ++j) Qs[u][dq + j] = __float2bfloat16(0.f);
        }
    }
    {
        int klocal = tid >> 1, dq = (tid & 1) * 32;
        const float* vr = v + (size_t)(b * S_ + c0 + klocal) * DM_ + h * DK_ + dq;
#pragma unroll
        for (int jj = 0; jj < 32; jj += 4) {
            float4 v4 = *(const float4*)(vr + jj);
            Vt[dq + jj + 0][klocal] = __float2bfloat16(v4.x);
            Vt[dq + jj + 1][klocal] = __float2bfloat16(v4.y);
            Vt[dq + jj + 2][klocal] = __float2bfloat16(v4.z);
            Vt[dq + jj + 3][klocal] = __float2bfloat16(v4.w);
        }
    }
    __syncthreads();

    const float* Kb = k + (size_t)b * S_ * DM_ + h * DK_;
    f32x4 sreg[3][2];
#pragma unroll
    for (int i = 0; i < 3; ++i)
#pragma unroll
        for (int j = 0; j < 2; ++j) sreg[i][j] = (f32x4){0.f, 0.f, 0.f, 0.f};
#pragma unroll
    for (int ntl = 0; ntl < 2; ++ntl) {
        int krow = c0 + (w * 2 + ntl) * 16 + ml;
        const float* kr = Kb + (size_t)krow * DM_;
        float4 x0 = *(const float4*)(kr + kq * 8);
        float4 x1 = *(const float4*)(kr + kq * 8 + 4);
        float4 y0 = *(const float4*)(kr + 32 + kq * 8);
        float4 y1 = *(const float4*)(kr + 32 + kq * 8 + 4);
        short8 b0, b1;
        b0[0] = f2bs(x0.x); b0[1] = f2bs(x0.y); b0[2] = f2bs(x0.z); b0[3] = f2bs(x0.w);
        b0[4] = f2bs(x1.x); b0[5] = f2bs(x1.y); b0[6] = f2bs(x1.z); b0[7] = f2bs(x1.w);
        b1[0] = f2bs(y0.x); b1[1] = f2bs(y0.y); b1[2] = f2bs(y0.z); b1[3] = f2bs(y0.w);
        b1[4] = f2bs(y1.x); b1[5] = f2bs(y1.y); b1[6] = f2bs(y1.z); b1[7] = f2bs(y1.w);
#pragma unroll
        for (int mt = 0; mt < 3; ++mt) {
            short8 a0 = *(const short8*)&Qs[mt * 16 + ml][kq * 8];
            short8 a1 = *(const short8*)&Qs[mt * 16 + ml][32 + kq * 8];
            sreg[mt][ntl] = __builtin_amdgcn_mfma_f32_16x16x32_bf16(a0, b0, sreg[mt][ntl], 0, 0, 0);
            sreg[mt][ntl] = __builtin_amdgcn_mfma_f32_16x16x32_bf16(a1, b1, sreg[mt][ntl], 0, 0, 0);
        }
    }

    {
        float vmx[3][4];
#pragma unroll
        for (int mt = 0; mt < 3; ++mt)
#pragma unroll
            for (int r = 0; r < 4; ++r)
                vmx[mt][r] = fmaxf(sreg[mt][0][r], sreg[mt][1][r]);
#pragma unroll
        for (int mask = 1; mask <= 8; mask <<= 1)
#pragma unroll
            for (int mt = 0; mt < 3; ++mt)
#pragma unroll
                for (int r = 0; r < 4; ++r)
                    vmx[mt][r] = fmaxf(vmx[mt][r], __shfl_xor(vmx[mt][r], mask, 64));
        if (ml == 0)
#pragma unroll
            for (int mt = 0; mt < 3; ++mt)
#pragma unroll
                for (int r = 0; r < 4; ++r)
                    mpart[w][mt * 16 + kq * 4 + r] = vmx[mt][r];
    }
    __syncthreads();
    if (tid < 48)
        mrow[tid] = fmaxf(fmaxf(mpart[0][tid], mpart[1][tid]),
                          fmaxf(mpart[2][tid], mpart[3][tid]));
    __syncthreads();

    {
        float vsum[3][4] = {{0.f}};
#pragma unroll
        for (int mt = 0; mt < 3; ++mt)
#pragma unroll
            for (int ntl = 0; ntl < 2; ++ntl) {
                int col = (w * 2 + ntl) * 16 + ml;
#pragma unroll
                for (int r = 0; r < 4; ++r) {
                    int row = mt * 16 + kq * 4 + r;
                    float p = __expf(sreg[mt][ntl][r] - mrow[row]);
                    Ps[row][col] = __float2bfloat16(p);
                    vsum[mt][r] += p;
                }
            }
#pragma unroll
        for (int mask = 1; mask <= 8; mask <<= 1)
#pragma unroll
            for (int mt = 0; mt < 3; ++mt)
#pragma unroll
                for (int r = 0; r < 4; ++r)
                    vsum[mt][r] += __shfl_xor(vsum[mt][r], mask, 64);
        if (ml == 0)
#pragma unroll
            for (int mt = 0; mt < 3; ++mt)
#pragma unroll
                for (int r = 0; r < 4; ++r)
                    lpart[w][mt * 16 + kq * 4 + r] = vsum[mt][r];
    }
    __syncthreads();

    f32x4 oreg[3];
#pragma unroll
    for (int i = 0; i < 3; ++i) oreg[i] = (f32x4){0.f, 0.f, 0.f, 0.f};
#pragma unroll
    for (int kt = 0; kt < 4; ++kt) {
        short8 bfq = *(const short8*)&Vt[w * 16 + ml][kt * 32 + kq * 8];
#pragma unroll
        for (int mt = 0; mt < 3; ++mt) {
            short8 af = *(const short8*)&Ps[mt * 16 + ml][kt * 32 + kq * 8];
            oreg[mt] = __builtin_amdgcn_mfma_f32_16x16x32_bf16(af, bfq, oreg[mt], 0, 0, 0);
        }
    }
#pragma unroll
    for (int mt = 0; mt < 3; ++mt)
#pragma unroll
        for (int r = 0; r < 4; ++r) {
            int row = mt * 16 + kq * 4 + r;
            Opart[((size_t)blk * 48 + row) * 64 + w * 16 + ml] = oreg[mt][r];
        }
    if (tid < 48) {
        Mpart[(size_t)blk * 48 + tid] = mrow[tid];
        Lpart[(size_t)blk * 48 + tid] =
            lpart[0][tid] + lpart[1][tid] + lpart[2][tid] + lpart[3][tid];
    }
}

// =====================================================================
// OLD PATH kernels (fallback when workspace < 66 MB) — unchanged
// =====================================================================

__global__ __launch_bounds__(256) void gemm_qkv(const float* __restrict__ hs,
                                                const float* __restrict__ wq,
                                                const float* __restrict__ wk,
                                                const float* __restrict__ wv,
                                                float* __restrict__ q,
                                                float* __restrict__ k,
                                                float* __restrict__ v) {
    __shared__ alignas(16) __hip_bfloat16 Ah[64][40], Al[64][40];
    __shared__ alignas(16) __hip_bfloat16 Bh[128][40], Bl[128][40];
    int idx = blockIdx.x;
    int by = idx / 24;
    int r = idx % 24;
    int mode = r >> 3, bx = r & 7;
    const float* Bm = (mode == 0) ? wq : (mode == 1) ? wk : wv;
    float* C = (mode == 0) ? q : (mode == 1) ? k : v;
    float scale = (mode == 0) ? 0.125f : 1.0f;
    bool split = (mode < 2);

    int tid = threadIdx.x, lane = tid & 63, w = tid >> 6;
    int ml = lane & 15, kq = lane >> 4;

    f32x4 acc[4][2];
#pragma unroll
    for (int i = 0; i < 4; ++i)
#pragma unroll
        for (int j = 0; j < 2; ++j) acc[i][j] = (f32x4){0.f, 0.f, 0.f, 0.f};

    const float* Ab = hs + (size_t)(by * 64) * DM_;
    const float* Bb = Bm + bx * 128;
    int ar = tid >> 2, akq = (tid & 3) * 8;
    int bcol = tid & 127, bkh = tid >> 7;

    for (int k0 = 0; k0 < DM_; k0 += 32) {
        {
            float av[8];
            *(float4*)&av[0] = *(const float4*)(Ab + (size_t)ar * DM_ + k0 + akq);
            *(float4*)&av[4] = *(const float4*)(Ab + (size_t)ar * DM_ + k0 + akq + 4);
            short8 hv, lv;
#pragma unroll
            for (int e = 0; e < 8; ++e) {
                __hip_bfloat16 hb = __float2bfloat16(av[e]);
                hv[e] = ((BF16S){hb}).s;
                lv[e] = f2bs(av[e] - __bfloat162float(hb));
            }
            *(short8*)&Ah[ar][akq] = hv;
            if (split) *(short8*)&Al[ar][akq] = lv;
        }
        {
            float be[16];
            const float* bp = Bb + (size_t)(k0 + bkh * 16) * DM_ + bcol;
#pragma unroll
            for (int j = 0; j < 16; ++j) be[j] = bp[(size_t)j * DM_];
            short8 h0, h1, l0, l1;
#pragma unroll
            for (int e = 0; e < 8; ++e) {
                __hip_bfloat16 hb = __float2bfloat16(be[e]);
                h0[e] = ((BF16S){hb}).s;
                l0[e] = f2bs(be[e] - __bfloat162float(hb));
                __hip_bfloat16 hb2 = __float2bfloat16(be[e + 8]);
                h1[e] = ((BF16S){hb2}).s;
                l1[e] = f2bs(be[e + 8] - __bfloat162float(hb2));
            }
            *(short8*)&Bh[bcol][bkh * 16] = h0;
            *(short8*)&Bh[bcol][bkh * 16 + 8] = h1;
            if (split) {
                *(short8*)&Bl[bcol][bkh * 16] = l0;
                *(short8*)&Bl[bcol][bkh * 16 + 8] = l1;
            }
        }
        __syncthreads();
        short8 ah[4], al[4], bh[2], bl[2];
#pragma unroll
        for (int mt = 0; mt < 4; ++mt) ah[mt] = *(const short8*)&Ah[mt * 16 + ml][kq * 8];
#pragma unroll
        for (int nt = 0; nt < 2; ++nt) bh[nt] = *(const short8*)&Bh[w * 32 + nt * 16 + ml][kq * 8];
        if (split) {
#pragma unroll
            for (int mt = 0; mt < 4; ++mt) al[mt] = *(const short8*)&Al[mt * 16 + ml][kq * 8];
#pragma unroll
            for (int nt = 0; nt < 2; ++nt) bl[nt] = *(const short8*)&Bl[w * 32 + nt * 16 + ml][kq * 8];
#pragma unroll
            for (int mt = 0; mt < 4; ++mt)
#pragma unroll
                for (int nt = 0; nt < 2; ++nt) {
                    acc[mt][nt] = __builtin_amdgcn_mfma_f32_16x16x32_bf16(ah[mt], bh[nt], acc[mt][nt], 0, 0, 0);
                    acc[mt][nt] = __builtin_amdgcn_mfma_f32_16x16x32_bf16(ah[mt], bl[nt], acc[mt][nt], 0, 0, 0);
                    acc[mt][nt] = __builtin_amdgcn_mfma_f32_16x16x32_bf16(al[mt], bh[nt], acc[mt][nt], 0, 0, 0);
                }
        } else {
#pragma unroll
            for (int mt = 0; mt < 4; ++mt)
#pragma unroll
                for (int nt = 0; nt < 2; ++nt)
                    acc[mt][nt] = __builtin_amdgcn_mfma_f32_16x16x32_bf16(ah[mt], bh[nt], acc[mt][nt], 0, 0, 0);
        }
        __syncthreads();
    }
#pragma unroll
    for (int mt = 0; mt < 4; ++mt)
#pragma unroll
        for (int nt = 0; nt < 2; ++nt)
#pragma unroll
            for (int r2 = 0; r2 < 4; ++r2) {
                int row = by * 64 + mt * 16 + kq * 4 + r2;
                int col = bx * 128 + w * 32 + nt * 16 + ml;
                C[(size_t)row * DM_ + col] = acc[mt][nt][r2] * scale;
            }
}

__global__ __launch_bounds__(256) void mfma_gemm_v2(const float* __restrict__ A,
                                                    const float* __restrict__ Bm,
                                                    float* __restrict__ C,
                                                    int M, int N, int K, float scale) {
    __shared__ alignas(16) __hip_bfloat16 Asb[64][40];
    __shared__ alignas(16) __hip_bfloat16 Bsb[128][40];
    int nbx = N >> 7;
    int by = blockIdx.x / nbx, bx = blockIdx.x % nbx;
    int tid = threadIdx.x, lane = tid & 63, w = tid >> 6;
    int ml = lane & 15, kq = lane >> 4;

    f32x4 acc[4][2];
#pragma unroll
    for (int i = 0; i < 4; ++i)
#pragma unroll
        for (int j = 0; j < 2; ++j) acc[i][j] = (f32x4){0.f, 0.f, 0.f, 0.f};

    const float* Ab = A + (size_t)(by * 64) * K;
    const float* Bb = Bm + bx * 128;
    int ar = tid >> 2, akq = (tid & 3) * 8;
    int bcol = tid & 127, bkh = tid >> 7;

    for (int k0 = 0; k0 < K; k0 += 32) {
        {
            float av[8];
            *(float4*)&av[0] = *(const float4*)(Ab + (size_t)ar * K + k0 + akq);
            *(float4*)&av[4] = *(const float4*)(Ab + (size_t)ar * K + k0 + akq + 4);
            short8 hv;
#pragma unroll
            for (int e = 0; e < 8; ++e) hv[e] = f2bs(av[e]);
            *(short8*)&Asb[ar][akq] = hv;
        }
        {
            float be[16];
            const float* bp = Bb + (size_t)(k0 + bkh * 16) * N + bcol;
#pragma unroll
            for (int j = 0; j < 16; ++j) be[j] = bp[(size_t)j * N];
            short8 h0, h1;
#pragma unroll
            for (int e = 0; e < 8; ++e) {
                h0[e] = f2bs(be[e]);
                h1[e] = f2bs(be[e + 8]);
            }
            *(short8*)&Bsb[bcol][bkh * 16] = h0;
            *(short8*)&Bsb[bcol][bkh * 16 + 8] = h1;
        }
        __syncthreads();
        short8 af[4], bf[2];
#pragma unroll
        for (int mt = 0; mt < 4; ++mt) af[mt] = *(const short8*)&Asb[mt * 16 + ml][kq * 8];
#pragma unroll
        for (int nt = 0; nt < 2; ++nt) bf[nt] = *(const short8*)&Bsb[w * 32 + nt * 16 + ml][kq * 8];
#pragma unroll
        for (int mt = 0; mt < 4; ++mt)
#pragma unroll
            for (int nt = 0; nt < 2; ++nt)
                acc[mt][nt] = __builtin_amdgcn_mfma_f32_16x16x32_bf16(af[mt], bf[nt], acc[mt][nt], 0, 0, 0);
        __syncthreads();
    }
#pragma unroll
    for (int mt = 0; mt < 4; ++mt)
#pragma unroll
        for (int nt = 0; nt < 2; ++nt)
#pragma unroll
            for (int r = 0; r < 4; ++r) {
                int row = by * 64 + mt * 16 + kq * 4 + r;
                int col = bx * 128 + w * 32 + nt * 16 + ml;
                C[(size_t)row * N + col] = acc[mt][nt][r] * scale;
            }
}

__global__ void m_score_v3(const float* __restrict__ q, const float* __restrict__ k,
                           const int* __restrict__ idxs, float* __restrict__ m_out,
                           int* __restrict__ rowmap) {
    int gwave = blockIdx.x * 4 + (threadIdx.x >> 6);
    int lane = threadIdx.x & 63;
    if (gwave >= B_ * H_ * S_) return;
    int l = gwave % S_;
    int bh = gwave / S_;
    int h = bh & 15, b = bh >> 4;
    int sl = lane >> 3;
    int dc = lane & 7;

    const float* qr = q + ((size_t)(b * S_ + l)) * DM_ + h * DK_ + dc * 8;
    float4 q0 = *(const float4*)qr;
    float4 q1 = *(const float4*)(qr + 4);
    const float* kb = k + (size_t)b * S_ * DM_ + h * DK_ + dc * 8;

    float mx = -INFINITY, sm = 0.f;
#pragma unroll
    for (int c = 0; c < 5; ++c) {
        int s = c * 8 + sl;
        int idx = idxs[l * SK_ + s];
        idx = (idx < 0) ? 0 : (idx >= S_ ? S_ - 1 : idx);
        const float* kr = kb + (size_t)idx * DM_;
        float4 k0 = *(const float4*)kr;
        float4 k1 = *(const float4*)(kr + 4);
        float d = q0.x * k0.x + q0.y * k0.y + q0.z * k0.z + q0.w * k0.w +
                  q1.x * k1.x + q1.y * k1.y + q1.z * k1.z + q1.w * k1.w;
        d += __shfl_xor(d, 1, 64);
        d += __shfl_xor(d, 2, 64);
        d += __shfl_xor(d, 4, 64);
        mx = fmaxf(mx, d);
        sm += d;
    }
#pragma unroll
    for (int off = 8; off <= 32; off <<= 1) {
        mx = fmaxf(mx, __shfl_xor(mx, off, 64));
        sm += __shfl_xor(sm, off, 64);
    }
    if (lane == 0) {
        m_out[(size_t)bh * S_ + l] = mx - sm * (1.f / (float)S_);
        rowmap[(size_t)bh * S_ + l] = -1;
    }
}

__global__ void topk_wave(const float* __restrict__ m, int* __restrict__ mtop,
                          int* __restrict__ rowmap) {
    int bh = blockIdx.x;
    int lane = threadIdx.x;
    const float* mb = m + (size_t)bh * S_;
    float vals[32];
#pragma unroll
    for (int j = 0; j < 32; ++j) vals[j] = mb[j * 64 + lane];
    float lmax = -INFINITY;
    int lj = 0;
#pragma unroll
    for (int j = 0; j < 32; ++j)
        if (vals[j] > lmax) { lmax = vals[j]; lj = j; }

    for (int it = 0; it < U_; ++it) {
        float wv = lmax;
        int wi = lj * 64 + lane;
#pragma unroll
        for (int off = 1; off < 64; off <<= 1) {
            float ov = __shfl_xor(wv, off, 64);
            int oi = __shfl_xor(wi, off, 64);
            if (ov > wv || (ov == wv && oi < wi)) { wv = ov; wi = oi; }
        }
        if (lane == 0) {
            mtop[bh * U_ + it] = wi;
            rowmap[(size_t)bh * S_ + wi] = it;
        }
        if ((wi & 63) == lane) {
            int jw = wi >> 6;
#pragma unroll
            for (int t = 0; t < 32; ++t)
                if (t == jw) vals[t] = -INFINITY;
            lmax = -INFINITY;
            lj = 0;
#pragma unroll
            for (int t = 0; t < 32; ++t)
                if (vals[t] > lmax) { lmax = vals[t]; lj = t; }
        }
    }
}

__global__ void vmean_part(const float* __restrict__ v, float* __restrict__ vpart) {
    __shared__ float part[4][DK_];
    int blk = blockIdx.x;
    int bh = blk >> 6, ch = blk & (VCH_ - 1);
    int b = bh >> 4, h = bh & 15;
    int tid = threadIdx.x, wave = tid >> 6, lane = tid & 63;
    const float* vb = v + (size_t)(b * S_ + ch * 32) * DM_ + h * DK_;
    float s = 0.f;
#pragma unroll
    for (int i = 0; i < 8; ++i)
        s += vb[(size_t)(i * 4 + wave) * DM_ + lane];
    part[wave][lane] = s;
    __syncthreads();
    if (tid < DK_)
        vpart[(size_t)blk * DK_ + tid] =
            part[0][tid] + part[1][tid] + part[2][tid] + part[3][tid];
}

__global__ void vmean_comb(const float* __restrict__ vpart, float* __restrict__ vm) {
    int bh = blockIdx.x, lane = threadIdx.x;
    float s = 0.f;
    for (int c = 0; c < VCH_; ++c)
        s += vpart[(size_t)(bh * VCH_ + c) * DK_ + lane];
    vm[bh * DK_ + lane] = s * (1.f / (float)S_);
}

__global__ void gather_qsel(const float* __restrict__ q, const int* __restrict__ mtop,
                            float* __restrict__ qsel) {
    int bh = blockIdx.x;
    int b = bh >> 4, h = bh & 15;
    int tid = threadIdx.x;
    int u = tid >> 2, dq = (tid & 3) * 16;
    if (u >= 48) return;
    float* dst = qsel + ((size_t)bh * 48 + u) * 64 + dq;
    if (u < U_) {
        int row = mtop[bh * U_ + u];
        row = (row < 0) ? 0 : (row >= S_ ? S_ - 1 : row);
        const float* src = q + ((size_t)(b * S_ + row)) * DM_ + h * DK_ + dq;
#pragma unroll
        for (int j = 0; j < 16; j += 4) *(float4*)(dst + j) = *(const float4*)(src + j);
    } else {
        float4 z = {0.f, 0.f, 0.f, 0.f};
#pragma unroll
        for (int j = 0; j < 16; j += 4) *(float4*)(dst + j) = z;
    }
}

__global__ __launch_bounds__(256) void attn_chunk(const float* __restrict__ qsel,
                                                  const float* __restrict__ k,
                                                  const float* __restrict__ v,
                                                  float* __restrict__ Opart,
                                                  float* __restrict__ Mpart,
                                                  float* __restrict__ Lpart) {
    __shared__ alignas(16) __hip_bfloat16 Qs[48][72];
    __shared__ alignas(16) __hip_bfloat16 Vt[64][136];
    __shared__ alignas(16) __hip_bfloat16 Ps[48][136];
    __shared__ float mpart[4][48], lpart[4][48];
    __shared__ float mrow[48];
    int blk = blockIdx.x;
    int bh = blk / NCH_, ch = blk % NCH_;
    int b = bh >> 4, h = bh & 15;
    int c0 = ch * CH_;
    int tid = threadIdx.x, lane = tid & 63, w = tid >> 6;
    int ml = lane & 15, kq = lane >> 4;

    {
        int u = tid >> 2, dq = (tid & 3) * 16;
        if (u < 48) {
            const float* src = qsel + ((size_t)bh * 48 + u) * 64 + dq;
#pragma unroll
            for (int j = 0; j < 16; j += 4) {
                float4 v4 = *(const float4*)(src + j);
                Qs[u][dq + j + 0] = __float2bfloat16(v4.x);
                Qs[u][dq + j + 1] = __float2bfloat16(v4.y);
                Qs[u][dq + j + 2] = __float2bfloat16(v4.z);
                Qs[u][dq + j + 3] = __float2bfloat16(v4.w);
            }
        }
    }
    {
        int klocal = tid >> 1, dq = (tid & 1) * 32;
        const float* vr = v + (size_t)(b * S_ + c0 + klocal) * DM_ + h * DK_ + dq;
#pragma unroll
        for (int jj = 0; jj < 32; jj += 4) {
            float4 v4 = *(const float4*)(vr + jj);
            Vt[dq + jj + 0][klocal] = __float2bfloat16(v4.x);
            Vt[dq + jj + 1][klocal] = __float2bfloat16(v4.y);
            Vt[dq + jj + 2][klocal] = __float2bfloat16(v4.z);
            Vt[dq + jj + 3][klocal] = __float2bfloat16(v4.w);
        }
    }
    __syncthreads();

    const float* Kb = k + (size_t)b * S_ * DM_ + h * DK_;
    f32x4 sreg[3][2];
#pragma unroll
    for (int i = 0; i < 3; ++i)
#pragma unroll
        for (int j = 0; j < 2; ++j) sreg[i][j] = (f32x4){0.f, 0.f, 0.f, 0.f};
#pragma unroll
    for (int ntl = 0; ntl < 2; ++ntl) {
        int krow = c0 + (w * 2 + ntl) * 16 + ml;
        const float* kr = Kb + (size_t)krow * DM_;
        float4 x0 = *(const float4*)(kr + kq * 8);
        float4 x1 = *(const float4*)(kr + kq * 8 + 4);
        float4 y0 = *(const float4*)(kr + 32 + kq * 8);
        float4 y1 = *(const float4*)(kr + 32 + kq * 8 + 4);
        short8 b0, b1;
        b0[0] = f2bs(x0.x); b0[1] = f2bs(x0.y); b0[2] = f2bs(x0.z); b0[3] = f2bs(x0.w);
        b0[4] = f2bs(x1.x); b0[5] = f2bs(x1.y); b0[6] = f2bs(x1.z); b0[7] = f2bs(x1.w);
        b1[0] = f2bs(y0.x); b1[1] = f2bs(y0.y); b1[2] = f2bs(y0.z); b1[3] = f2bs(y0.w);
        b1[4] = f2bs(y1.x); b1[5] = f2bs(y1.y); b1[6] = f2bs(y1.z); b1[7] = f2bs(y1.w);
#pragma unroll
        for (int mt = 0; mt < 3; ++mt) {
            short8 a0 = *(const short8*)&Qs[mt * 16 + ml][kq * 8];
            short8 a1 = *(const short8*)&Qs[mt * 16 + ml][32 + kq * 8];
            sreg[mt][ntl] = __builtin_amdgcn_mfma_f32_16x16x32_bf16(a0, b0, sreg[mt][ntl], 0, 0, 0);
            sreg[mt][ntl] = __builtin_amdgcn_mfma_f32_16x16x32_bf16(a1, b1, sreg[mt][ntl], 0, 0, 0);
        }
    }

    {
        float vmx[3][4];
#pragma unroll
        for (int mt = 0; mt < 3; ++mt)
#pragma unroll
            for (int r = 0; r < 4; ++r)
                vmx[mt][r] = fmaxf(sreg[mt][0][r], sreg[mt][1][r]);
#pragma unroll
        for (int mask = 1; mask <= 8; mask <<= 1)
#pragma unroll
            for (int mt = 0; mt < 3; ++mt)
#pragma unroll
                for (int r = 0; r < 4; ++r)
                    vmx[mt][r] = fmaxf(vmx[mt][r], __shfl_xor(vmx[mt][r], mask, 64));
        if (ml == 0)
#pragma unroll
            for (int mt = 0; mt < 3; ++mt)
#pragma unroll
                for (int r = 0; r < 4; ++r)
                    mpart[w][mt * 16 + kq * 4 + r] = vmx[mt][r];
    }
    __syncthreads();
    if (tid < 48)
        mrow[tid] = fmaxf(fmaxf(mpart[0][tid], mpart[1][tid]),
                          fmaxf(mpart[2][tid], mpart[3][tid]));
    __syncthreads();

    {
        float vsum[3][4] = {{0.f}};
#pragma unroll
        for (int mt = 0; mt < 3; ++mt)
#pragma unroll
            for (int ntl = 0; ntl < 2; ++ntl) {
                int col = (w * 2 + ntl) * 16 + ml;
#pragma unroll
                for (int r = 0; r < 4; ++r) {
                    int row = mt * 16 + kq * 4 + r;
                    float p = __expf(sreg[mt][ntl][r] - mrow[row]);
                    Ps[row][col] = __float2bfloat16(p);
                    vsum[mt][r] += p;
                }
            }
#pragma unroll
        for (int mask = 1; mask <= 8; mask <<= 1)
#pragma unroll
            for (int mt = 0; mt < 3; ++mt)
#pragma unroll
                for (int r = 0; r < 4; ++r)
                    vsum[mt][r] += __shfl_xor(vsum[mt][r], mask, 64);
        if (ml == 0)
#pragma unroll
            for (int mt = 0; mt < 3; ++mt)
#pragma unroll
                for (int r = 0; r < 4; ++r)
                    lpart[w][mt * 16 + kq * 4 + r] = vsum[mt][r];
    }
    __syncthreads();

    f32x4 oreg[3];
#pragma unroll
    for (int i = 0; i < 3; ++i) oreg[i] = (f32x4){0.f, 0.f, 0.f, 0.f};
#pragma unroll
    for (int kt = 0; kt < 4; ++kt) {
        short8 bfq = *(const short8*)&Vt[w * 16 + ml][kt * 32 + kq * 8];
#pragma unroll
        for (int mt = 0; mt < 3; ++mt) {
            short8 af = *(const short8*)&Ps[mt * 16 + ml][kt * 32 + kq * 8];
            oreg[mt] = __builtin_amdgcn_mfma_f32_16x16x32_bf16(af, bfq, oreg[mt], 0, 0, 0);
        }
    }
#pragma unroll
    for (int mt = 0; mt < 3; ++mt)
#pragma unroll
        for (int r = 0; r < 4; ++r) {
            int row = mt * 16 + kq * 4 + r;
            Opart[((size_t)blk * 48 + row) * 64 + w * 16 + ml] = oreg[mt][r];
        }
    if (tid < 48) {
        Mpart[(size_t)blk * 48 + tid] = mrow[tid];
        Lpart[(size_t)blk * 48 + tid] =
            lpart[0][tid] + lpart[1][tid] + lpart[2][tid] + lpart[3][tid];
    }
}

__global__ void attn_combine(const float* __restrict__ Opart, const float* __restrict__ Mpart,
                             const float* __restrict__ Lpart, float* __restrict__ upd) {
    __shared__ float wfac[NCH_][48];
    __shared__ float lfin[48];
    int bh = blockIdx.x, tid = threadIdx.x;
    if (tid < 48) {
        float m = -1e30f;
        for (int c = 0; c < NCH_; ++c)
            m = fmaxf(m, Mpart[(size_t)(bh * NCH_ + c) * 48 + tid]);
        float l = 0.f;
        for (int c = 0; c < NCH_; ++c) {
            float wf = __expf(Mpart[(size_t)(bh * NCH_ + c) * 48 + tid] - m);
            wfac[c][tid] = wf;
            l += wf * Lpart[(size_t)(bh * NCH_ + c) * 48 + tid];
        }
        lfin[tid] = l;
    }
    __syncthreads();
    for (int e = tid; e < U_ * DK_; e += 256) {
        int row = e >> 6, col = e & 63;
        float o = 0.f;
        for (int c = 0; c < NCH_; ++c)
            o += wfac[c][row] * Opart[((size_t)(bh * NCH_ + c) * 48 + row) * 64 + col];
        upd[((size_t)bh * U_ + row) * DK_ + col] = o / lfin[row];
    }
}

__global__ void ctx_fill2(const float* __restrict__ vm, const float* __restrict__ upd,
                          const int* __restrict__ rowmap, float* __restrict__ ctx) {
    size_t i = ((size_t)blockIdx.x * 256 + threadIdx.x) * 4;
    int c = (int)(i & (DM_ - 1));
    size_t bl = i >> 10;
    int l = (int)(bl & (S_ - 1));
    int b = (int)(bl >> 11);
    int h = c >> 6, d = c & (DK_ - 1);
    int bh = b * H_ + h;
    int u = rowmap[(size_t)bh * S_ + l];
    float4 val;
    if (u >= 0)
        val = *(const float4*)(upd + ((size_t)bh * U_ + u) * DK_ + d);
    else
        val = *(const float4*)(vm + bh * DK_ + d);
    *(float4*)(ctx + i) = val;
}

// bias + residual + LayerNorm. Wave shfl reduce + 2 barriers, float4 I/O.
__global__ void ln_kernel(const float* __restrict__ fcout, const float* __restrict__ fcb,
                          const float* __restrict__ resid,
                          const float* __restrict__ lnw, const float* __restrict__ lnb,
                          float* __restrict__ out) {
    __shared__ float sred[8];
    int row = blockIdx.x, tid = threadIdx.x, lane = tid & 63, w = tid >> 6;
    size_t base = (size_t)row * DM_ + tid * 4;
    float4 f = *(const float4*)(fcout + base);
    float4 bb = *(const float4*)(fcb + tid * 4);
    float4 rs = *(const float4*)(resid + base);
    float x[4] = {f.x + bb.x + rs.x, f.y + bb.y + rs.y,
                  f.z + bb.z + rs.z, f.w + bb.w + rs.w};
    float s = x[0] + x[1] + x[2] + x[3];
#pragma unroll
    for (int off = 1; off < 64; off <<= 1) s += __shfl_xor(s, off, 64);
    if (lane == 0) sred[w] = s;
    __syncthreads();
    float mu = (sred[0] + sred[1] + sred[2] + sred[3]) * (1.f / (float)DM_);
    float vs = 0.f;
#pragma unroll
    for (int j = 0; j < 4; ++j) { float d = x[j] - mu; vs += d * d; }
#pragma unroll
    for (int off = 1; off < 64; off <<= 1) vs += __shfl_xor(vs, off, 64);
    if (lane == 0) sred[4 + w] = vs;
    __syncthreads();
    float rstd = rsqrtf((sred[4] + sred[5] + sred[6] + sred[7]) * (1.f / (float)DM_) + 1e-6f);
    float4 wv = *(const float4*)(lnw + tid * 4);
    float4 bv = *(const float4*)(lnb + tid * 4);
    float4 o;
    o.x = (x[0] - mu) * rstd * wv.x + bv.x;
    o.y = (x[1] - mu) * rstd * wv.y + bv.y;
    o.z = (x[2] - mu) * rstd * wv.z + bv.z;
    o.w = (x[3] - mu) * rstd * wv.w + bv.w;
    *(float4*)(out + base) = o;
}

// ================= launch =================

extern "C" void kernel_launch(void* const* d_in, const int* in_sizes, int n_in,
                              void* d_out, int out_size, void* d_ws, size_t ws_size,
                              hipStream_t stream) {
    if (n_in < 9 || d_ws == nullptr || d_out == nullptr) return;

    const float* hs  = (const float*)d_in[0];
    const float* wq  = (const float*)d_in[1];
    const float* wk  = (const float*)d_in[2];
    const float* wv  = (const float*)d_in[3];
    const float* fcw = (const float*)d_in[4];
    const float* fcb = (const float*)d_in[5];
    const float* lnw = (const float*)d_in[6];
    const float* lnb = (const float*)d_in[7];
    const int* idxs  = (const int*)d_in[8];

    const size_t MD = (size_t)B_ * S_ * DM_;  // 4194304
    const int M = B_ * S_;                    // 4096
    float* out = (float*)d_out;
    char* base = (char*)d_ws;

    if (ws_size >= 66ull * 1024 * 1024) {
        // ---- NEW PATH
        float* q   = (float*)base;                       // 16 MB [later ctx]
        float* k   = (float*)(base + (16ull << 20));     // 16 MB [later fcout]
        u16* Ahi   = (u16*)(base + (32ull << 20));       // 8 MB [later Opart]
        u16* Alo   = (u16*)(base + (40ull << 20));       // 8 MB
        u16* Wqh   = (u16*)(base + (48ull << 20));       // 6 x 2 MB
        u16* Wql   = Wqh + (1u << 20);
        u16* Wkh   = Wql + (1u << 20);
        u16* Wkl   = Wkh + (1u << 20);
        u16* Wvh   = Wkl + (1u << 20);
        u16* Fct   = Wvh + (1u << 20);
        float* mbuf  = (float*)(base + (60ull << 20));         // B*H*S = 65536 f
        float* vmean = mbuf + (size_t)B_ * H_ * S_;            // 2048 f (raw sum)
        int* mtop    = (int*)(vmean + B_ * H_ * DK_);          // 1280 i
        int* rowmap  = (int*)(mtop + B_ * H_ * U_);            // 65536 i
        float* v = out;
        // Opart over Ahi/Alo (dead after gemm_qk/v); q stays live for attn gather
        float* Opart = (float*)(base + (32ull << 20));
        float* Mpart = Opart + (size_t)512 * 48 * 64;
        float* Lpart = Mpart + (size_t)512 * 48;
        u16* ctxb = (u16*)q;     // after attn (q dead post-attn_chunk2)
        float* fcout = k;        // after k dead (post-attn_chunk2)

        conv_all<<<3073, 256, 0, stream>>>(hs, wq, wk, wv, fcw, Ahi, Alo,
                                           Wqh, Wql, Wkh, Wkl, Wvh, Fct, vmean);
        gemm_qk_v8<<<256, 256, 0, stream>>>(Ahi, Alo, Wqh, Wql, Wkh, Wkl, q, k);
        gemm_v_v8<<<256, 256, 0, stream>>>(Ahi, Wvh, v, vmean);

        m_score_v4<<<(B_ * S_) / 4, 256, 0, stream>>>(q, k, idxs, mbuf, rowmap);
        topk_wave<<<B_ * H_, 64, 0, stream>>>(mbuf, mtop, rowmap);

        attn_chunk2<<<B_ * H_ * NCH_, 256, 0, stream>>>(q, mtop, k, v, Opart, Mpart, Lpart);

        ctx_fill4<<<(int)(MD / 1024), 256, 0, stream>>>(vmean, Opart, Mpart, Lpart, rowmap, ctxb);

        gemm_fc_v7<<<512, 256, 0, stream>>>(ctxb, Fct, fcout);
        ln_kernel<<<M, 256, 0, stream>>>(fcout, fcb, hs, lnw, lnb, out);
        return;
    }

    // ---- OLD PATH (fallback, needs >= 34 MB)
    if (ws_size < 34ull * 1024 * 1024) return;
    float* ws = (float*)d_ws;
    float* q = ws;
    float* k = ws + MD;
    float* mbuf = ws + 2 * MD;
    float* vmean = mbuf + (size_t)B_ * H_ * S_;
    float* upd = vmean + B_ * H_ * DK_;
    int* mtop = (int*)(upd + (size_t)B_ * H_ * U_ * DK_);
    float* qsel = (float*)(mtop + B_ * H_ * U_);
    float* vpart = qsel + (size_t)B_ * H_ * 48 * 64;
    int* rowmap = (int*)(vpart + (size_t)B_ * H_ * VCH_ * DK_);
    float* v = out;
    float* Opart = q;
    float* Mpart = Opart + (size_t)512 * 48 * 64;
    float* Lpart = Mpart + (size_t)512 * 48;
    float* ctx = q;
    float* fcout = k;

    gemm_qkv<<<1536, 256, 0, stream>>>(hs, wq, wk, wv, q, k, v);

    m_score_v3<<<(B_ * H_ * S_) / 4, 256, 0, stream>>>(q, k, idxs, mbuf, rowmap);
    topk_wave<<<B_ * H_, 64, 0, stream>>>(mbuf, mtop, rowmap);
    vmean_part<<<B_ * H_ * VCH_, 256, 0, stream>>>(v, vpart);
    vmean_comb<<<B_ * H_, 64, 0, stream>>>(vpart, vmean);
    gather_qsel<<<B_ * H_, 256, 0, stream>>>(q, mtop, qsel);

    attn_chunk<<<B_ * H_ * NCH_, 256, 0, stream>>>(qsel, k, v, Opart, Mpart, Lpart);
    attn_combine<<<B_ * H_, 256, 0, stream>>>(Opart, Mpart, Lpart, upd);

    ctx_fill2<<<(int)(MD / 1024), 256, 0, stream>>>(vmean, upd, rowmap, ctx);

    mfma_gemm_v2<<<512, 256, 0, stream>>>(ctx, fcw, fcout, M, DM_, DM_, 1.0f);
    ln_kernel<<<M, 256, 0, stream>>>(fcout, fcb, hs, lnw, lnb, out);
}

// Round 7
// 301.084 us; speedup vs baseline: 1.0922x; 1.0922x over previous
//
#include <hip/hip_runtime.h>
#include <hip/hip_bf16.h>

#define B_  2
#define S_  2048
#define DM_ 1024
#define H_  16
#define DK_ 64
#define SK_ 40   // SAMPLE_K
#define U_  40   // top-k u
#define CH_ 128  // attn chunk columns
#define NCH_ (S_ / CH_)  // 16
#define VCH_ 64  // vmean chunks per (b,h)

typedef __attribute__((ext_vector_type(8))) short short8;
typedef __attribute__((ext_vector_type(4))) short short4v;
typedef __attribute__((ext_vector_type(4))) float f32x4;
typedef unsigned short u16;

union BF16S { __hip_bfloat16 h; short s; };
static __device__ __forceinline__ short f2bs(float x) {
    BF16S u; u.h = __float2bfloat16(x); return u.s;
}
static __device__ __forceinline__ void fsplit(float x, short& h, short& l) {
    BF16S u; u.h = __float2bfloat16(x);
    h = u.s;
    BF16S v; v.h = __float2bfloat16(x - __bfloat162float(u.h));
    l = v.s;
}

// async global->LDS, 16 bytes per lane. LDS dest must be wave-uniform base + lane*16.
static __device__ __forceinline__ void gload16(const void* g, void* s) {
    __builtin_amdgcn_global_load_lds(
        (const __attribute__((address_space(1))) void*)g,
        (__attribute__((address_space(3))) void*)s, 16, 0, 0);
}

// LDS bank swizzle (involution): flip byte bits [6:4] with bits [9:7] (row bits 1..3).
// Turns the 8-way conflict of 64B-row ds_read_b128 column reads into 2-way (free).
static __device__ __forceinline__ int swzb(int b) {
    return b ^ (((b >> 7) & 7) << 4);
}

// =====================================================================
// NEW PATH kernels
// =====================================================================

// One-dispatch prep: [0,2048) hs->hi/lo planes, [2048,3072) weight transpose+cvt,
// [3072] zero the vmean accumulator.
__global__ __launch_bounds__(256) void conv_all(
    const float* __restrict__ hs,
    const float* __restrict__ wq, const float* __restrict__ wk,
    const float* __restrict__ wv, const float* __restrict__ fcw,
    u16* __restrict__ Ahi, u16* __restrict__ Alo,
    u16* __restrict__ qh, u16* __restrict__ ql,
    u16* __restrict__ kh, u16* __restrict__ kl,
    u16* __restrict__ vh, u16* __restrict__ fh,
    float* __restrict__ vmean_acc) {
    __shared__ float T[64][65];
    int bid = blockIdx.x, tid = threadIdx.x;
    if (bid < 2048) {
        size_t i = ((size_t)bid * 256 + tid) * 8;
        float a[8];
        *(float4*)&a[0] = *(const float4*)(hs + i);
        *(float4*)&a[4] = *(const float4*)(hs + i + 4);
        short8 h, l;
#pragma unroll
        for (int e = 0; e < 8; ++e) {
            short hh, ll;
            fsplit(a[e], hh, ll);
            h[e] = hh; l[e] = ll;
        }
        *(short8*)&Ahi[i] = h;
        *(short8*)&Alo[i] = l;
        return;
    }
    if (bid >= 3072) {
        for (int j = tid; j < B_ * H_ * DK_; j += 256) vmean_acc[j] = 0.f;
        return;
    }
    int mode = (bid - 2048) >> 8;
    int tb = (bid - 2048) & 255;
    int ty = tb >> 4, tx = tb & 15;
    const float* src = (mode == 0) ? wq : (mode == 1) ? wk : (mode == 2) ? wv : fcw;
    u16* dh = (mode == 0) ? qh : (mode == 1) ? kh : (mode == 2) ? vh : fh;
    u16* dl = (mode == 0) ? ql : kl;
    bool split = (mode < 2);
    int r = tid >> 2, cq = (tid & 3) * 16;

    const float* sp = src + (size_t)(ty * 64 + r) * 1024 + tx * 64 + cq;
#pragma unroll
    for (int j = 0; j < 16; j += 4) *(float4*)&T[r][cq + j] = *(const float4*)(sp + j);
    __syncthreads();

    short8 h0, h1, l0, l1;
#pragma unroll
    for (int j = 0; j < 8; ++j) {
        short hh, ll;
        fsplit(T[cq + j][r], hh, ll);
        h0[j] = hh; l0[j] = ll;
        fsplit(T[cq + 8 + j][r], hh, ll);
        h1[j] = hh; l1[j] = ll;
    }
    size_t off = (size_t)(tx * 64 + r) * 1024 + ty * 64 + cq;
    *(short8*)&dh[off] = h0;
    *(short8*)&dh[off + 8] = h1;
    if (split) {
        *(short8*)&dl[off] = l0;
        *(short8*)&dl[off + 8] = l1;
    }
}

// fused q/k/v projection (R5 known-good). 2-deep counted-vmcnt pipeline with
// MFMA-before-bar2. Swizzled LDS, mode-striped XCD chunking. v-mode epilogue
// accumulates column sums -> vmean.
__global__ __launch_bounds__(256) void gemm_qkv_v7(
    const u16* __restrict__ Ahi, const u16* __restrict__ Alo,
    const u16* __restrict__ Wqh, const u16* __restrict__ Wql,
    const u16* __restrict__ Wkh, const u16* __restrict__ Wkl,
    const u16* __restrict__ Wvh,
    float* __restrict__ q, float* __restrict__ k, float* __restrict__ v,
    float* __restrict__ vmean_acc) {
    __shared__ alignas(16) u16 lds[2][4][128 * 32];  // 64 KB
    int bid = (int)blockIdx.x;
    int xcd = bid & 7, ii = bid >> 3;          // ii in 0..95
    int mode = ii >> 5;                        // 0..2 (q,k,v)
    int rr = xcd * 32 + (ii & 31);             // tile within mode, 0..255
    int by = rr >> 3, bx = rr & 7;
    const u16* Bh = (mode == 0) ? Wqh : (mode == 1) ? Wkh : Wvh;
    const u16* Bl = (mode == 0) ? Wql : Wkl;  // unused for v
    float* C = (mode == 0) ? q : (mode == 1) ? k : v;
    float scale = (mode == 0) ? 0.125f : 1.0f;
    bool split = (mode < 2);

    int tid = threadIdx.x, lane = tid & 63, w = tid >> 6;
    int wr = w >> 1, wc = w & 1;
    int ml = lane & 15, kq = lane >> 4;

    f32x4 acc[4][4];
#pragma unroll
    for (int i = 0; i < 4; ++i)
#pragma unroll
        for (int j = 0; j < 4; ++j) acc[i][j] = (f32x4){0.f, 0.f, 0.f, 0.f};

    const u16* Agh = Ahi + (size_t)(by * 128) * 1024;
    const u16* Agl = Alo + (size_t)(by * 128) * 1024;
    const u16* Bgh = Bh + (size_t)(bx * 128) * 1024;
    const u16* Bgl = Bl + (size_t)(bx * 128) * 1024;

    int pl0 = tid * 16, pl1 = 4096 + tid * 16;
    int d0 = swzb(pl0), d1 = swzb(pl1);
    int gs0 = (d0 >> 6) * 1024 + ((d0 & 63) >> 1);
    int gs1 = (d1 >> 6) * 1024 + ((d1 & 63) >> 1);
    int ld0 = tid * 8, ld1 = 2048 + tid * 8;

    int offA[4], offB[4];
#pragma unroll
    for (int mt = 0; mt < 4; ++mt) {
        int d = (wr * 64 + mt * 16 + ml) * 64 + kq * 16;
        offA[mt] = swzb(d);
    }
#pragma unroll
    for (int nt = 0; nt < 4; ++nt) {
        int d = (wc * 64 + nt * 16 + ml) * 64 + kq * 16;
        offB[nt] = swzb(d);
    }

    auto STAGE = [&](int bf, int k0) {
        gload16(Agh + gs0 + k0, &lds[bf][0][ld0]);
        gload16(Agh + gs1 + k0, &lds[bf][0][ld1]);
        gload16(Bgh + gs0 + k0, &lds[bf][2][ld0]);
        gload16(Bgh + gs1 + k0, &lds[bf][2][ld1]);
        if (split) {
            gload16(Agl + gs0 + k0, &lds[bf][1][ld0]);
            gload16(Agl + gs1 + k0, &lds[bf][1][ld1]);
            gload16(Bgl + gs0 + k0, &lds[bf][3][ld0]);
            gload16(Bgl + gs1 + k0, &lds[bf][3][ld1]);
        }
    };

    STAGE(0, 0);
    STAGE(1, 32);
    int cur = 0;
    for (int t = 0; t < 32; ++t) {
        if (t == 31)      asm volatile("s_waitcnt vmcnt(0)" ::: "memory");
        else if (split)   asm volatile("s_waitcnt vmcnt(8)" ::: "memory");
        else              asm volatile("s_waitcnt vmcnt(4)" ::: "memory");
        __builtin_amdgcn_s_barrier();           // tile t visible to all waves
        __builtin_amdgcn_sched_barrier(0);

        const char* Ah_ = (const char*)lds[cur][0];
        const char* Al_ = (const char*)lds[cur][1];
        const char* Bh_ = (const char*)lds[cur][2];
        const char* Bl_ = (const char*)lds[cur][3];
        short8 a_h[4], b_h[4], a_l[4], b_l[4];
#pragma unroll
        for (int mt = 0; mt < 4; ++mt) a_h[mt] = *(const short8*)(Ah_ + offA[mt]);
#pragma unroll
        for (int nt = 0; nt < 4; ++nt) b_h[nt] = *(const short8*)(Bh_ + offB[nt]);
        if (split) {
#pragma unroll
            for (int mt = 0; mt < 4; ++mt) a_l[mt] = *(const short8*)(Al_ + offA[mt]);
#pragma unroll
            for (int nt = 0; nt < 4; ++nt) b_l[nt] = *(const short8*)(Bl_ + offB[nt]);
        }

        __builtin_amdgcn_s_setprio(1);
#pragma unroll
        for (int mt = 0; mt < 4; ++mt)
#pragma unroll
            for (int nt = 0; nt < 4; ++nt)
                acc[mt][nt] = __builtin_amdgcn_mfma_f32_16x16x32_bf16(a_h[mt], b_h[nt], acc[mt][nt], 0, 0, 0);
        if (split) {
#pragma unroll
            for (int mt = 0; mt < 4; ++mt)
#pragma unroll
                for (int nt = 0; nt < 4; ++nt) {
                    acc[mt][nt] = __builtin_amdgcn_mfma_f32_16x16x32_bf16(a_h[mt], b_l[nt], acc[mt][nt], 0, 0, 0);
                    acc[mt][nt] = __builtin_amdgcn_mfma_f32_16x16x32_bf16(a_l[mt], b_h[nt], acc[mt][nt], 0, 0, 0);
                }
        }
        __builtin_amdgcn_s_setprio(0);

        if (t < 31) {
            __builtin_amdgcn_s_barrier();       // all waves consumed buf[cur]
            __builtin_amdgcn_sched_barrier(0);
            if (t < 30) STAGE(cur, (t + 2) * 32);
        }
        cur ^= 1;
    }
#pragma unroll
    for (int mt = 0; mt < 4; ++mt)
#pragma unroll
        for (int nt = 0; nt < 4; ++nt)
#pragma unroll
            for (int r2 = 0; r2 < 4; ++r2) {
                int row = by * 128 + wr * 64 + mt * 16 + kq * 4 + r2;
                int col = bx * 128 + wc * 64 + nt * 16 + ml;
                C[(size_t)row * 1024 + col] = acc[mt][nt][r2] * scale;
            }
    if (mode == 2) {
        int b = by >> 4;
#pragma unroll
        for (int nt = 0; nt < 4; ++nt) {
            float s = 0.f;
#pragma unroll
            for (int mt = 0; mt < 4; ++mt)
#pragma unroll
                for (int r2 = 0; r2 < 4; ++r2) s += acc[mt][nt][r2];
            s += __shfl_xor(s, 16, 64);
            s += __shfl_xor(s, 32, 64);
            if (kq == 0) {
                int col = bx * 128 + wc * 64 + nt * 16 + ml;
                int h = col >> 6, d = col & 63;
                atomicAdd(&vmean_acc[(b * H_ + h) * DK_ + d], s);
            }
        }
    }
}

// m-score v5: v3's wave math (bit-identical) with locality block-shaping.
// One 1024-thread block = all 16 heads of one (b,l): the 16 waves share the
// same 40 sampled k-rows and read adjacent 256B slices concurrently -> every
// fetched line is consumed 16x on the same CU. 65536 waves total (full TLP).
__global__ __launch_bounds__(1024) void m_score_v5(const float* __restrict__ q,
                                                   const float* __restrict__ k,
                                                   const int* __restrict__ idxs,
                                                   float* __restrict__ m_out,
                                                   int* __restrict__ rowmap) {
    int blk = blockIdx.x;              // b*S + l
    int l = blk & (S_ - 1);
    int b = blk >> 11;
    int h = threadIdx.x >> 6;          // wave index = head
    int lane = threadIdx.x & 63;
    int sl = lane >> 3;                // sample slot 0..7
    int dc = lane & 7;                 // d-chunk 0..7

    const float* qr = q + ((size_t)(b * S_ + l)) * DM_ + h * DK_ + dc * 8;
    float4 q0 = *(const float4*)qr;
    float4 q1 = *(const float4*)(qr + 4);
    const float* kb = k + (size_t)b * S_ * DM_ + h * DK_ + dc * 8;

    float mx = -INFINITY, sm = 0.f;
#pragma unroll
    for (int c = 0; c < 5; ++c) {
        int s = c * 8 + sl;
        int idx = idxs[l * SK_ + s];
        idx = (idx < 0) ? 0 : (idx >= S_ ? S_ - 1 : idx);
        const float* kr = kb + (size_t)idx * DM_;
        float4 k0 = *(const float4*)kr;
        float4 k1 = *(const float4*)(kr + 4);
        float d = q0.x * k0.x + q0.y * k0.y + q0.z * k0.z + q0.w * k0.w +
                  q1.x * k1.x + q1.y * k1.y + q1.z * k1.z + q1.w * k1.w;
        d += __shfl_xor(d, 1, 64);
        d += __shfl_xor(d, 2, 64);
        d += __shfl_xor(d, 4, 64);
        mx = fmaxf(mx, d);
        sm += d;
    }
#pragma unroll
    for (int off = 8; off <= 32; off <<= 1) {
        mx = fmaxf(mx, __shfl_xor(mx, off, 64));
        sm += __shfl_xor(sm, off, 64);
    }
    if (lane == 0) {
        size_t o = (size_t)(b * H_ + h) * S_ + l;
        m_out[o] = mx - sm * (1.f / (float)S_);
        rowmap[o] = -1;
    }
}

// top-40, single wave per (b,h), register-resident, barrier-free.
__global__ void topk_wave(const float* __restrict__ m, int* __restrict__ mtop,
                          int* __restrict__ rowmap) {
    int bh = blockIdx.x;
    int lane = threadIdx.x;
    const float* mb = m + (size_t)bh * S_;
    float vals[32];
#pragma unroll
    for (int j = 0; j < 32; ++j) vals[j] = mb[j * 64 + lane];
    float lmax = -INFINITY;
    int lj = 0;
#pragma unroll
    for (int j = 0; j < 32; ++j)
        if (vals[j] > lmax) { lmax = vals[j]; lj = j; }

    for (int it = 0; it < U_; ++it) {
        float wv = lmax;
        int wi = lj * 64 + lane;
#pragma unroll
        for (int off = 1; off < 64; off <<= 1) {
            float ov = __shfl_xor(wv, off, 64);
            int oi = __shfl_xor(wi, off, 64);
            if (ov > wv || (ov == wv && oi < wi)) { wv = ov; wi = oi; }
        }
        if (lane == 0) {
            mtop[bh * U_ + it] = wi;
            rowmap[(size_t)bh * S_ + wi] = it;
        }
        if ((wi & 63) == lane) {
            int jw = wi >> 6;
#pragma unroll
            for (int t = 0; t < 32; ++t)
                if (t == jw) vals[t] = -INFINITY;
            lmax = -INFINITY;
            lj = 0;
#pragma unroll
            for (int t = 0; t < 32; ++t)
                if (vals[t] > lmax) { lmax = vals[t]; lj = t; }
        }
    }
}

// ctx one-pass with INLINE chunk-combine for selected rows (attn_combine fused).
__global__ void ctx_fill4(const float* __restrict__ vm,
                          const float* __restrict__ Opart,
                          const float* __restrict__ Mpart,
                          const float* __restrict__ Lpart,
                          const int* __restrict__ rowmap, u16* __restrict__ ctx) {
    size_t i = ((size_t)blockIdx.x * 256 + threadIdx.x) * 4;  // over B*S*DM
    int c = (int)(i & (DM_ - 1));
    size_t bl = i >> 10;
    int l = (int)(bl & (S_ - 1));
    int b = (int)(bl >> 11);
    int h = c >> 6, d = c & (DK_ - 1);
    int bh = b * H_ + h;
    int u = rowmap[(size_t)bh * S_ + l];
    float4 val;
    if (u >= 0) {
        float m = -1e30f;
#pragma unroll
        for (int c2 = 0; c2 < NCH_; ++c2)
            m = fmaxf(m, Mpart[(size_t)(bh * NCH_ + c2) * 48 + u]);
        float lf = 0.f;
        float o0 = 0.f, o1 = 0.f, o2 = 0.f, o3 = 0.f;
#pragma unroll
        for (int c2 = 0; c2 < NCH_; ++c2) {
            float wf = __expf(Mpart[(size_t)(bh * NCH_ + c2) * 48 + u] - m);
            lf += wf * Lpart[(size_t)(bh * NCH_ + c2) * 48 + u];
            const float* op = Opart + ((size_t)(bh * NCH_ + c2) * 48 + u) * 64 + d;
            o0 += wf * op[0];
            o1 += wf * op[1];
            o2 += wf * op[2];
            o3 += wf * op[3];
        }
        val.x = o0 / lf; val.y = o1 / lf; val.z = o2 / lf; val.w = o3 / lf;
    } else {
        val = *(const float4*)(vm + bh * DK_ + d);
        const float is = 1.f / (float)S_;
        val.x *= is; val.y *= is; val.z *= is; val.w *= is;
    }
    short4v o;
    o[0] = f2bs(val.x); o[1] = f2bs(val.y); o[2] = f2bs(val.z); o[3] = f2bs(val.w);
    *(short4v*)&ctx[i] = o;
}

// fc GEMM: ctx(bf16) @ FcT(bf16)^T -> fp32. Tile 128x64, BK=32,
// reordered 2-deep pipeline + swizzled LDS, XCD-chunked.
__global__ __launch_bounds__(256) void gemm_fc_v7(const u16* __restrict__ A,
                                                  const u16* __restrict__ Bt,
                                                  float* __restrict__ C) {
    __shared__ alignas(16) u16 lds[2][6144];  // 24 KB
    int bid = (int)blockIdx.x;
    int lb = (bid & 7) * 64 + (bid >> 3);
    int by = lb >> 4, bx = lb & 15;
    int tid = threadIdx.x, lane = tid & 63, w = tid >> 6;
    int wr = w >> 1, wc = w & 1;
    int ml = lane & 15, kq = lane >> 4;

    f32x4 acc[4][2];
#pragma unroll
    for (int i = 0; i < 4; ++i)
#pragma unroll
        for (int j = 0; j < 2; ++j) acc[i][j] = (f32x4){0.f, 0.f, 0.f, 0.f};

    const u16* Ag = A + (size_t)(by * 128) * 1024;
    const u16* Bg = Bt + (size_t)(bx * 64) * 1024;

    int pl0 = tid * 16, pl1 = 4096 + tid * 16;
    int d0 = swzb(pl0), d1 = swzb(pl1);
    int gs0 = (d0 >> 6) * 1024 + ((d0 & 63) >> 1);
    int gs1 = (d1 >> 6) * 1024 + ((d1 & 63) >> 1);
    int ld0 = tid * 8, ld1 = 2048 + tid * 8, ldB = 4096 + tid * 8;

    int offA[4], offB[2];
#pragma unroll
    for (int mt = 0; mt < 4; ++mt) {
        int d = (wr * 64 + mt * 16 + ml) * 64 + kq * 16;
        offA[mt] = swzb(d);
    }
#pragma unroll
    for (int nt = 0; nt < 2; ++nt) {
        int d = (wc * 32 + nt * 16 + ml) * 64 + kq * 16;
        offB[nt] = 8192 + swzb(d);
    }

    auto STAGE = [&](int bf, int k0) {
        gload16(Ag + gs0 + k0, &lds[bf][ld0]);
        gload16(Ag + gs1 + k0, &lds[bf][ld1]);
        gload16(Bg + gs0 + k0, &lds[bf][ldB]);
    };

    STAGE(0, 0);
    STAGE(1, 32);
    int cur = 0;
    for (int t = 0; t < 32; ++t) {
        if (t == 31) asm volatile("s_waitcnt vmcnt(0)" ::: "memory");
        else         asm volatile("s_waitcnt vmcnt(3)" ::: "memory");
        __builtin_amdgcn_s_barrier();
        __builtin_amdgcn_sched_barrier(0);

        const char* L = (const char*)lds[cur];
        short8 af[4], bf2[2];
#pragma unroll
        for (int mt = 0; mt < 4; ++mt) af[mt] = *(const short8*)(L + offA[mt]);
#pragma unroll
        for (int nt = 0; nt < 2; ++nt) bf2[nt] = *(const short8*)(L + offB[nt]);

        __builtin_amdgcn_s_setprio(1);
#pragma unroll
        for (int mt = 0; mt < 4; ++mt)
#pragma unroll
            for (int nt = 0; nt < 2; ++nt)
                acc[mt][nt] = __builtin_amdgcn_mfma_f32_16x16x32_bf16(af[mt], bf2[nt], acc[mt][nt], 0, 0, 0);
        __builtin_amdgcn_s_setprio(0);

        if (t < 31) {
            __builtin_amdgcn_s_barrier();
            __builtin_amdgcn_sched_barrier(0);
            if (t < 30) STAGE(cur, (t + 2) * 32);
        }
        cur ^= 1;
    }
#pragma unroll
    for (int mt = 0; mt < 4; ++mt)
#pragma unroll
        for (int nt = 0; nt < 2; ++nt)
#pragma unroll
            for (int r = 0; r < 4; ++r) {
                int row = by * 128 + wr * 64 + mt * 16 + kq * 4 + r;
                int col = bx * 64 + wc * 32 + nt * 16 + ml;
                C[(size_t)row * 1024 + col] = acc[mt][nt][r];
            }
}

// split-K flash attention with fused Q-gather (reads q + mtop directly).
__global__ __launch_bounds__(256) void attn_chunk2(const float* __restrict__ q,
                                                   const int* __restrict__ mtop,
                                                   const float* __restrict__ k,
                                                   const float* __restrict__ v,
                                                   float* __restrict__ Opart,
                                                   float* __restrict__ Mpart,
                                                   float* __restrict__ Lpart) {
    __shared__ alignas(16) __hip_bfloat16 Qs[48][72];
    __shared__ alignas(16) __hip_bfloat16 Vt[64][136];
    __shared__ alignas(16) __hip_bfloat16 Ps[48][136];
    __shared__ float mpart[4][48], lpart[4][48];
    __shared__ float mrow[48];
    int blk = blockIdx.x;
    int bh = blk / NCH_, ch = blk % NCH_;
    int b = bh >> 4, h = bh & 15;
    int c0 = ch * CH_;
    int tid = threadIdx.x, lane = tid & 63, w = tid >> 6;
    int ml = lane & 15, kq = lane >> 4;

    {
        int u = tid >> 2, dq = (tid & 3) * 16;
        if (u < U_) {
            int row = mtop[bh * U_ + u];
            row = (row < 0) ? 0 : (row >= S_ ? S_ - 1 : row);
            const float* src = q + ((size_t)(b * S_ + row)) * DM_ + h * DK_ + dq;
#pragma unroll
            for (int j = 0; j < 16; j += 4) {
                float4 v4 = *(const float4*)(src + j);
                Qs[u][dq + j + 0] = __float2bfloat16(v4.x);
                Qs[u][dq + j + 1] = __float2bfloat16(v4.y);
                Qs[u][dq + j + 2] = __float2bfloat16(v4.z);
                Qs[u][dq + j + 3] = __float2bfloat16(v4.w);
            }
        } else if (u < 48) {
#pragma unroll
            for (int j = 0; j < 16; ++j) Qs[u][dq + j] = __float2bfloat16(0.f);
        }
    }
    {
        int klocal = tid >> 1, dq = (tid & 1) * 32;
        const float* vr = v + (size_t)(b * S_ + c0 + klocal) * DM_ + h * DK_ + dq;
#pragma unroll
        for (int jj = 0; jj < 32; jj += 4) {
            float4 v4 = *(const float4*)(vr + jj);
            Vt[dq + jj + 0][klocal] = __float2bfloat16(v4.x);
            Vt[dq + jj + 1][klocal] = __float2bfloat16(v4.y);
            Vt[dq + jj + 2][klocal] = __float2bfloat16(v4.z);
            Vt[dq + jj + 3][klocal] = __float2bfloat16(v4.w);
        }
    }
    __syncthreads();

    const float* Kb = k + (size_t)b * S_ * DM_ + h * DK_;
    f32x4 sreg[3][2];
#pragma unroll
    for (int i = 0; i < 3; ++i)
#pragma unroll
        for (int j = 0; j < 2; ++j) sreg[i][j] = (f32x4){0.f, 0.f, 0.f, 0.f};
#pragma unroll
    for (int ntl = 0; ntl < 2; ++ntl) {
        int krow = c0 + (w * 2 + ntl) * 16 + ml;
        const float* kr = Kb + (size_t)krow * DM_;
        float4 x0 = *(const float4*)(kr + kq * 8);
        float4 x1 = *(const float4*)(kr + kq * 8 + 4);
        float4 y0 = *(const float4*)(kr + 32 + kq * 8);
        float4 y1 = *(const float4*)(kr + 32 + kq * 8 + 4);
        short8 b0, b1;
        b0[0] = f2bs(x0.x); b0[1] = f2bs(x0.y); b0[2] = f2bs(x0.z); b0[3] = f2bs(x0.w);
        b0[4] = f2bs(x1.x); b0[5] = f2bs(x1.y); b0[6] = f2bs(x1.z); b0[7] = f2bs(x1.w);
        b1[0] = f2bs(y0.x); b1[1] = f2bs(y0.y); b1[2] = f2bs(y0.z); b1[3] = f2bs(y0.w);
        b1[4] = f2bs(y1.x); b1[5] = f2bs(y1.y); b1[6] = f2bs(y1.z); b1[7] = f2bs(y1.w);
#pragma unroll
        for (int mt = 0; mt < 3; ++mt) {
            short8 a0 = *(const short8*)&Qs[mt * 16 + ml][kq * 8];
            short8 a1 = *(const short8*)&Qs[mt * 16 + ml][32 + kq * 8];
            sreg[mt][ntl] = __builtin_amdgcn_mfma_f32_16x16x32_bf16(a0, b0, sreg[mt][ntl], 0, 0, 0);
            sreg[mt][ntl] = __builtin_amdgcn_mfma_f32_16x16x32_bf16(a1, b1, sreg[mt][ntl], 0, 0, 0);
        }
    }

    {
        float vmx[3][4];
#pragma unroll
        for (int mt = 0; mt < 3; ++mt)
#pragma unroll
            for (int r = 0; r < 4; ++r)
                vmx[mt][r] = fmaxf(sreg[mt][0][r], sreg[mt][1][r]);
#pragma unroll
        for (int mask = 1; mask <= 8; mask <<= 1)
#pragma unroll
            for (int mt = 0; mt < 3; ++mt)
#pragma unroll
                for (int r = 0; r < 4; ++r)
                    vmx[mt][r] = fmaxf(vmx[mt][r], __shfl_xor(vmx[mt][r], mask, 64));
        if (ml == 0)
#pragma unroll
            for (int mt = 0; mt < 3; ++mt)
#pragma unroll
                for (int r = 0; r < 4; ++r)
                    mpart[w][mt * 16 + kq * 4 + r] = vmx[mt][r];
    }
    __syncthreads();
    if (tid < 48)
        mrow[tid] = fmaxf(fmaxf(mpart[0][tid], mpart[1][tid]),
                          fmaxf(mpart[2][tid], mpart[3][tid]));
    __syncthreads();

    {
        float vsum[3][4] = {{0.f}};
#pragma unroll
        for (int mt = 0; mt < 3; ++mt)
#pragma unroll
            for (int ntl = 0; ntl < 2; ++ntl) {
                int col = (w * 2 + ntl) * 16 + ml;
#pragma unroll
                for (int r = 0; r < 4; ++r) {
                    int row = mt * 16 + kq * 4 + r;
                    float p = __expf(sreg[mt][ntl][r] - mrow[row]);
                    Ps[row][col] = __float2bfloat16(p);
                    vsum[mt][r] += p;
                }
            }
#pragma unroll
        for (int mask = 1; mask <= 8; mask <<= 1)
#pragma unroll
            for (int mt = 0; mt < 3; ++mt)
#pragma unroll
                for (int r = 0; r < 4; ++r)
                    vsum[mt][r] += __shfl_xor(vsum[mt][r], mask, 64);
        if (ml == 0)
#pragma unroll
            for (int mt = 0; mt < 3; ++mt)
#pragma unroll
                for (int r = 0; r < 4; ++r)
                    lpart[w][mt * 16 + kq * 4 + r] = vsum[mt][r];
    }
    __syncthreads();

    f32x4 oreg[3];
#pragma unroll
    for (int i = 0; i < 3; ++i) oreg[i] = (f32x4){0.f, 0.f, 0.f, 0.f};
#pragma unroll
    for (int kt = 0; kt < 4; ++kt) {
        short8 bfq = *(const short8*)&Vt[w * 16 + ml][kt * 32 + kq * 8];
#pragma unroll
        for (int mt = 0; mt < 3; ++mt) {
            short8 af = *(const short8*)&Ps[mt * 16 + ml][kt * 32 + kq * 8];
            oreg[mt] = __builtin_amdgcn_mfma_f32_16x16x32_bf16(af, bfq, oreg[mt], 0, 0, 0);
        }
    }
#pragma unroll
    for (int mt = 0; mt < 3; ++mt)
#pragma unroll
        for (int r = 0; r < 4; ++r) {
            int row = mt * 16 + kq * 4 + r;
            Opart[((size_t)blk * 48 + row) * 64 + w * 16 + ml] = oreg[mt][r];
        }
    if (tid < 48) {
        Mpart[(size_t)blk * 48 + tid] = mrow[tid];
        Lpart[(size_t)blk * 48 + tid] =
            lpart[0][tid] + lpart[1][tid] + lpart[2][tid] + lpart[3][tid];
    }
}

// =====================================================================
// OLD PATH kernels (fallback when workspace < 66 MB) — unchanged
// =====================================================================

__global__ __launch_bounds__(256) void gemm_qkv(const float* __restrict__ hs,
                                                const float* __restrict__ wq,
                                                const float* __restrict__ wk,
                                                const float* __restrict__ wv,
                                                float* __restrict__ q,
                                                float* __restrict__ k,
                                                float* __restrict__ v) {
    __shared__ alignas(16) __hip_bfloat16 Ah[64][40], Al[64][40];
    __shared__ alignas(16) __hip_bfloat16 Bh[128][40], Bl[128][40];
    int idx = blockIdx.x;
    int by = idx / 24;
    int r = idx % 24;
    int mode = r >> 3, bx = r & 7;
    const float* Bm = (mode == 0) ? wq : (mode == 1) ? wk : wv;
    float* C = (mode == 0) ? q : (mode == 1) ? k : v;
    float scale = (mode == 0) ? 0.125f : 1.0f;
    bool split = (mode < 2);

    int tid = threadIdx.x, lane = tid & 63, w = tid >> 6;
    int ml = lane & 15, kq = lane >> 4;

    f32x4 acc[4][2];
#pragma unroll
    for (int i = 0; i < 4; ++i)
#pragma unroll
        for (int j = 0; j < 2; ++j) acc[i][j] = (f32x4){0.f, 0.f, 0.f, 0.f};

    const float* Ab = hs + (size_t)(by * 64) * DM_;
    const float* Bb = Bm + bx * 128;
    int ar = tid >> 2, akq = (tid & 3) * 8;
    int bcol = tid & 127, bkh = tid >> 7;

    for (int k0 = 0; k0 < DM_; k0 += 32) {
        {
            float av[8];
            *(float4*)&av[0] = *(const float4*)(Ab + (size_t)ar * DM_ + k0 + akq);
            *(float4*)&av[4] = *(const float4*)(Ab + (size_t)ar * DM_ + k0 + akq + 4);
            short8 hv, lv;
#pragma unroll
            for (int e = 0; e < 8; ++e) {
                __hip_bfloat16 hb = __float2bfloat16(av[e]);
                hv[e] = ((BF16S){hb}).s;
                lv[e] = f2bs(av[e] - __bfloat162float(hb));
            }
            *(short8*)&Ah[ar][akq] = hv;
            if (split) *(short8*)&Al[ar][akq] = lv;
        }
        {
            float be[16];
            const float* bp = Bb + (size_t)(k0 + bkh * 16) * DM_ + bcol;
#pragma unroll
            for (int j = 0; j < 16; ++j) be[j] = bp[(size_t)j * DM_];
            short8 h0, h1, l0, l1;
#pragma unroll
            for (int e = 0; e < 8; ++e) {
                __hip_bfloat16 hb = __float2bfloat16(be[e]);
                h0[e] = ((BF16S){hb}).s;
                l0[e] = f2bs(be[e] - __bfloat162float(hb));
                __hip_bfloat16 hb2 = __float2bfloat16(be[e + 8]);
                h1[e] = ((BF16S){hb2}).s;
                l1[e] = f2bs(be[e + 8] - __bfloat162float(hb2));
            }
            *(short8*)&Bh[bcol][bkh * 16] = h0;
            *(short8*)&Bh[bcol][bkh * 16 + 8] = h1;
            if (split) {
                *(short8*)&Bl[bcol][bkh * 16] = l0;
                *(short8*)&Bl[bcol][bkh * 16 + 8] = l1;
            }
        }
        __syncthreads();
        short8 ah[4], al[4], bh[2], bl[2];
#pragma unroll
        for (int mt = 0; mt < 4; ++mt) ah[mt] = *(const short8*)&Ah[mt * 16 + ml][kq * 8];
#pragma unroll
        for (int nt = 0; nt < 2; ++nt) bh[nt] = *(const short8*)&Bh[w * 32 + nt * 16 + ml][kq * 8];
        if (split) {
#pragma unroll
            for (int mt = 0; mt < 4; ++mt) al[mt] = *(const short8*)&Al[mt * 16 + ml][kq * 8];
#pragma unroll
            for (int nt = 0; nt < 2; ++nt) bl[nt] = *(const short8*)&Bl[w * 32 + nt * 16 + ml][kq * 8];
#pragma unroll
            for (int mt = 0; mt < 4; ++mt)
#pragma unroll
                for (int nt = 0; nt < 2; ++nt) {
                    acc[mt][nt] = __builtin_amdgcn_mfma_f32_16x16x32_bf16(ah[mt], bh[nt], acc[mt][nt], 0, 0, 0);
                    acc[mt][nt] = __builtin_amdgcn_mfma_f32_16x16x32_bf16(ah[mt], bl[nt], acc[mt][nt], 0, 0, 0);
                    acc[mt][nt] = __builtin_amdgcn_mfma_f32_16x16x32_bf16(al[mt], bh[nt], acc[mt][nt], 0, 0, 0);
                }
        } else {
#pragma unroll
            for (int mt = 0; mt < 4; ++mt)
#pragma unroll
                for (int nt = 0; nt < 2; ++nt)
                    acc[mt][nt] = __builtin_amdgcn_mfma_f32_16x16x32_bf16(ah[mt], bh[nt], acc[mt][nt], 0, 0, 0);
        }
        __syncthreads();
    }
#pragma unroll
    for (int mt = 0; mt < 4; ++mt)
#pragma unroll
        for (int nt = 0; nt < 2; ++nt)
#pragma unroll
            for (int r2 = 0; r2 < 4; ++r2) {
                int row = by * 64 + mt * 16 + kq * 4 + r2;
                int col = bx * 128 + w * 32 + nt * 16 + ml;
                C[(size_t)row * DM_ + col] = acc[mt][nt][r2] * scale;
            }
}

__global__ __launch_bounds__(256) void mfma_gemm_v2(const float* __restrict__ A,
                                                    const float* __restrict__ Bm,
                                                    float* __restrict__ C,
                                                    int M, int N, int K, float scale) {
    __shared__ alignas(16) __hip_bfloat16 Asb[64][40];
    __shared__ alignas(16) __hip_bfloat16 Bsb[128][40];
    int nbx = N >> 7;
    int by = blockIdx.x / nbx, bx = blockIdx.x % nbx;
    int tid = threadIdx.x, lane = tid & 63, w = tid >> 6;
    int ml = lane & 15, kq = lane >> 4;

    f32x4 acc[4][2];
#pragma unroll
    for (int i = 0; i < 4; ++i)
#pragma unroll
        for (int j = 0; j < 2; ++j) acc[i][j] = (f32x4){0.f, 0.f, 0.f, 0.f};

    const float* Ab = A + (size_t)(by * 64) * K;
    const float* Bb = Bm + bx * 128;
    int ar = tid >> 2, akq = (tid & 3) * 8;
    int bcol = tid & 127, bkh = tid >> 7;

    for (int k0 = 0; k0 < K; k0 += 32) {
        {
            float av[8];
            *(float4*)&av[0] = *(const float4*)(Ab + (size_t)ar * K + k0 + akq);
            *(float4*)&av[4] = *(const float4*)(Ab + (size_t)ar * K + k0 + akq + 4);
            short8 hv;
#pragma unroll
            for (int e = 0; e < 8; ++e) hv[e] = f2bs(av[e]);
            *(short8*)&Asb[ar][akq] = hv;
        }
        {
            float be[16];
            const float* bp = Bb + (size_t)(k0 + bkh * 16) * N + bcol;
#pragma unroll
            for (int j = 0; j < 16; ++j) be[j] = bp[(size_t)j * N];
            short8 h0, h1;
#pragma unroll
            for (int e = 0; e < 8; ++e) {
                h0[e] = f2bs(be[e]);
                h1[e] = f2bs(be[e + 8]);
            }
            *(short8*)&Bsb[bcol][bkh * 16] = h0;
            *(short8*)&Bsb[bcol][bkh * 16 + 8] = h1;
        }
        __syncthreads();
        short8 af[4], bf[2];
#pragma unroll
        for (int mt = 0; mt < 4; ++mt) af[mt] = *(const short8*)&Asb[mt * 16 + ml][kq * 8];
#pragma unroll
        for (int nt = 0; nt < 2; ++nt) bf[nt] = *(const short8*)&Bsb[w * 32 + nt * 16 + ml][kq * 8];
#pragma unroll
        for (int mt = 0; mt < 4; ++mt)
#pragma unroll
            for (int nt = 0; nt < 2; ++nt)
                acc[mt][nt] = __builtin_amdgcn_mfma_f32_16x16x32_bf16(af[mt], bf[nt], acc[mt][nt], 0, 0, 0);
        __syncthreads();
    }
#pragma unroll
    for (int mt = 0; mt < 4; ++mt)
#pragma unroll
        for (int nt = 0; nt < 2; ++nt)
#pragma unroll
            for (int r = 0; r < 4; ++r) {
                int row = by * 64 + mt * 16 + kq * 4 + r;
                int col = bx * 128 + w * 32 + nt * 16 + ml;
                C[(size_t)row * N + col] = acc[mt][nt][r] * scale;
            }
}

__global__ void m_score_v3(const float* __restrict__ q, const float* __restrict__ k,
                           const int* __restrict__ idxs, float* __restrict__ m_out,
                           int* __restrict__ rowmap) {
    int gwave = blockIdx.x * 4 + (threadIdx.x >> 6);
    int lane = threadIdx.x & 63;
    if (gwave >= B_ * H_ * S_) return;
    int l = gwave % S_;
    int bh = gwave / S_;
    int h = bh & 15, b = bh >> 4;
    int sl = lane >> 3;
    int dc = lane & 7;

    const float* qr = q + ((size_t)(b * S_ + l)) * DM_ + h * DK_ + dc * 8;
    float4 q0 = *(const float4*)qr;
    float4 q1 = *(const float4*)(qr + 4);
    const float* kb = k + (size_t)b * S_ * DM_ + h * DK_ + dc * 8;

    float mx = -INFINITY, sm = 0.f;
#pragma unroll
    for (int c = 0; c < 5; ++c) {
        int s = c * 8 + sl;
        int idx = idxs[l * SK_ + s];
        idx = (idx < 0) ? 0 : (idx >= S_ ? S_ - 1 : idx);
        const float* kr = kb + (size_t)idx * DM_;
        float4 k0 = *(const float4*)kr;
        float4 k1 = *(const float4*)(kr + 4);
        float d = q0.x * k0.x + q0.y * k0.y + q0.z * k0.z + q0.w * k0.w +
                  q1.x * k1.x + q1.y * k1.y + q1.z * k1.z + q1.w * k1.w;
        d += __shfl_xor(d, 1, 64);
        d += __shfl_xor(d, 2, 64);
        d += __shfl_xor(d, 4, 64);
        mx = fmaxf(mx, d);
        sm += d;
    }
#pragma unroll
    for (int off = 8; off <= 32; off <<= 1) {
        mx = fmaxf(mx, __shfl_xor(mx, off, 64));
        sm += __shfl_xor(sm, off, 64);
    }
    if (lane == 0) {
        m_out[(size_t)bh * S_ + l] = mx - sm * (1.f / (float)S_);
        rowmap[(size_t)bh * S_ + l] = -1;
    }
}

__global__ void vmean_part(const float* __restrict__ v, float* __restrict__ vpart) {
    __shared__ float part[4][DK_];
    int blk = blockIdx.x;
    int bh = blk >> 6, ch = blk & (VCH_ - 1);
    int b = bh >> 4, h = bh & 15;
    int tid = threadIdx.x, wave = tid >> 6, lane = tid & 63;
    const float* vb = v + (size_t)(b * S_ + ch * 32) * DM_ + h * DK_;
    float s = 0.f;
#pragma unroll
    for (int i = 0; i < 8; ++i)
        s += vb[(size_t)(i * 4 + wave) * DM_ + lane];
    part[wave][lane] = s;
    __syncthreads();
    if (tid < DK_)
        vpart[(size_t)blk * DK_ + tid] =
            part[0][tid] + part[1][tid] + part[2][tid] + part[3][tid];
}

__global__ void vmean_comb(const float* __restrict__ vpart, float* __restrict__ vm) {
    int bh = blockIdx.x, lane = threadIdx.x;
    float s = 0.f;
    for (int c = 0; c < VCH_; ++c)
        s += vpart[(size_t)(bh * VCH_ + c) * DK_ + lane];
    vm[bh * DK_ + lane] = s * (1.f / (float)S_);
}

__global__ void gather_qsel(const float* __restrict__ q, const int* __restrict__ mtop,
                            float* __restrict__ qsel) {
    int bh = blockIdx.x;
    int b = bh >> 4, h = bh & 15;
    int tid = threadIdx.x;
    int u = tid >> 2, dq = (tid & 3) * 16;
    if (u >= 48) return;
    float* dst = qsel + ((size_t)bh * 48 + u) * 64 + dq;
    if (u < U_) {
        int row = mtop[bh * U_ + u];
        row = (row < 0) ? 0 : (row >= S_ ? S_ - 1 : row);
        const float* src = q + ((size_t)(b * S_ + row)) * DM_ + h * DK_ + dq;
#pragma unroll
        for (int j = 0; j < 16; j += 4) *(float4*)(dst + j) = *(const float4*)(src + j);
    } else {
        float4 z = {0.f, 0.f, 0.f, 0.f};
#pragma unroll
        for (int j = 0; j < 16; j += 4) *(float4*)(dst + j) = z;
    }
}

__global__ __launch_bounds__(256) void attn_chunk(const float* __restrict__ qsel,
                                                  const float* __restrict__ k,
                                                  const float* __restrict__ v,
                                                  float* __restrict__ Opart,
                                                  float* __restrict__ Mpart,
                                                  float* __restrict__ Lpart) {
    __shared__ alignas(16) __hip_bfloat16 Qs[48][72];
    __shared__ alignas(16) __hip_bfloat16 Vt[64][136];
    __shared__ alignas(16) __hip_bfloat16 Ps[48][136];
    __shared__ float mpart[4][48], lpart[4][48];
    __shared__ float mrow[48];
    int blk = blockIdx.x;
    int bh = blk / NCH_, ch = blk % NCH_;
    int b = bh >> 4, h = bh & 15;
    int c0 = ch * CH_;
    int tid = threadIdx.x, lane = tid & 63, w = tid >> 6;
    int ml = lane & 15, kq = lane >> 4;

    {
        int u = tid >> 2, dq = (tid & 3) * 16;
        if (u < 48) {
            const float* src = qsel + ((size_t)bh * 48 + u) * 64 + dq;
#pragma unroll
            for (int j = 0; j < 16; j += 4) {
                float4 v4 = *(const float4*)(src + j);
                Qs[u][dq + j + 0] = __float2bfloat16(v4.x);
                Qs[u][dq + j + 1] = __float2bfloat16(v4.y);
                Qs[u][dq + j + 2] = __float2bfloat16(v4.z);
                Qs[u][dq + j + 3] = __float2bfloat16(v4.w);
            }
        }
    }
    {
        int klocal = tid >> 1, dq = (tid & 1) * 32;
        const float* vr = v + (size_t)(b * S_ + c0 + klocal) * DM_ + h * DK_ + dq;
#pragma unroll
        for (int jj = 0; jj < 32; jj += 4) {
            float4 v4 = *(const float4*)(vr + jj);
            Vt[dq + jj + 0][klocal] = __float2bfloat16(v4.x);
            Vt[dq + jj + 1][klocal] = __float2bfloat16(v4.y);
            Vt[dq + jj + 2][klocal] = __float2bfloat16(v4.z);
            Vt[dq + jj + 3][klocal] = __float2bfloat16(v4.w);
        }
    }
    __syncthreads();

    const float* Kb = k + (size_t)b * S_ * DM_ + h * DK_;
    f32x4 sreg[3][2];
#pragma unroll
    for (int i = 0; i < 3; ++i)
#pragma unroll
        for (int j = 0; j < 2; ++j) sreg[i][j] = (f32x4){0.f, 0.f, 0.f, 0.f};
#pragma unroll
    for (int ntl = 0; ntl < 2; ++ntl) {
        int krow = c0 + (w * 2 + ntl) * 16 + ml;
        const float* kr = Kb + (size_t)krow * DM_;
        float4 x0 = *(const float4*)(kr + kq * 8);
        float4 x1 = *(const float4*)(kr + kq * 8 + 4);
        float4 y0 = *(const float4*)(kr + 32 + kq * 8);
        float4 y1 = *(const float4*)(kr + 32 + kq * 8 + 4);
        short8 b0, b1;
        b0[0] = f2bs(x0.x); b0[1] = f2bs(x0.y); b0[2] = f2bs(x0.z); b0[3] = f2bs(x0.w);
        b0[4] = f2bs(x1.x); b0[5] = f2bs(x1.y); b0[6] = f2bs(x1.z); b0[7] = f2bs(x1.w);
        b1[0] = f2bs(y0.x); b1[1] = f2bs(y0.y); b1[2] = f2bs(y0.z); b1[3] = f2bs(y0.w);
        b1[4] = f2bs(y1.x); b1[5] = f2bs(y1.y); b1[6] = f2bs(y1.z); b1[7] = f2bs(y1.w);
#pragma unroll
        for (int mt = 0; mt < 3; ++mt) {
            short8 a0 = *(const short8*)&Qs[mt * 16 + ml][kq * 8];
            short8 a1 = *(const short8*)&Qs[mt * 16 + ml][32 + kq * 8];
            sreg[mt][ntl] = __builtin_amdgcn_mfma_f32_16x16x32_bf16(a0, b0, sreg[mt][ntl], 0, 0, 0);
            sreg[mt][ntl] = __builtin_amdgcn_mfma_f32_16x16x32_bf16(a1, b1, sreg[mt][ntl], 0, 0, 0);
        }
    }

    {
        float vmx[3][4];
#pragma unroll
        for (int mt = 0; mt < 3; ++mt)
#pragma unroll
            for (int r = 0; r < 4; ++r)
                vmx[mt][r] = fmaxf(sreg[mt][0][r], sreg[mt][1][r]);
#pragma unroll
        for (int mask = 1; mask <= 8; mask <<= 1)
#pragma unroll
            for (int mt = 0; mt < 3; ++mt)
#pragma unroll
                for (int r = 0; r < 4; ++r)
                    vmx[mt][r] = fmaxf(vmx[mt][r], __shfl_xor(vmx[mt][r], mask, 64));
        if (ml == 0)
#pragma unroll
            for (int mt = 0; mt < 3; ++mt)
#pragma unroll
                for (int r = 0; r < 4; ++r)
                    mpart[w][mt * 16 + kq * 4 + r] = vmx[mt][r];
    }
    __syncthreads();
    if (tid < 48)
        mrow[tid] = fmaxf(fmaxf(mpart[0][tid], mpart[1][tid]),
                          fmaxf(mpart[2][tid], mpart[3][tid]));
    __syncthreads();

    {
        float vsum[3][4] = {{0.f}};
#pragma unroll
        for (int mt = 0; mt < 3; ++mt)
#pragma unroll
            for (int ntl = 0; ntl < 2; ++ntl) {
                int col = (w * 2 + ntl) * 16 + ml;
#pragma unroll
                for (int r = 0; r < 4; ++r) {
                    int row = mt * 16 + kq * 4 + r;
                    float p = __expf(sreg[mt][ntl][r] - mrow[row]);
                    Ps[row][col] = __float2bfloat16(p);
                    vsum[mt][r] += p;
                }
            }
#pragma unroll
        for (int mask = 1; mask <= 8; mask <<= 1)
#pragma unroll
            for (int mt = 0; mt < 3; ++mt)
#pragma unroll
                for (int r = 0; r < 4; ++r)
                    vsum[mt][r] += __shfl_xor(vsum[mt][r], mask, 64);
        if (ml == 0)
#pragma unroll
            for (int mt = 0; mt < 3; ++mt)
#pragma unroll
                for (int r = 0; r < 4; ++r)
                    lpart[w][mt * 16 + kq * 4 + r] = vsum[mt][r];
    }
    __syncthreads();

    f32x4 oreg[3];
#pragma unroll
    for (int i = 0; i < 3; ++i) oreg[i] = (f32x4){0.f, 0.f, 0.f, 0.f};
#pragma unroll
    for (int kt = 0; kt < 4; ++kt) {
        short8 bfq = *(const short8*)&Vt[w * 16 + ml][kt * 32 + kq * 8];
#pragma unroll
        for (int mt = 0; mt < 3; ++mt) {
            short8 af = *(const short8*)&Ps[mt * 16 + ml][kt * 32 + kq * 8];
            oreg[mt] = __builtin_amdgcn_mfma_f32_16x16x32_bf16(af, bfq, oreg[mt], 0, 0, 0);
        }
    }
#pragma unroll
    for (int mt = 0; mt < 3; ++mt)
#pragma unroll
        for (int r = 0; r < 4; ++r) {
            int row = mt * 16 + kq * 4 + r;
            Opart[((size_t)blk * 48 + row) * 64 + w * 16 + ml] = oreg[mt][r];
        }
    if (tid < 48) {
        Mpart[(size_t)blk * 48 + tid] = mrow[tid];
        Lpart[(size_t)blk * 48 + tid] =
            lpart[0][tid] + lpart[1][tid] + lpart[2][tid] + lpart[3][tid];
    }
}

__global__ void attn_combine(const float* __restrict__ Opart, const float* __restrict__ Mpart,
                             const float* __restrict__ Lpart, float* __restrict__ upd) {
    __shared__ float wfac[NCH_][48];
    __shared__ float lfin[48];
    int bh = blockIdx.x, tid = threadIdx.x;
    if (tid < 48) {
        float m = -1e30f;
        for (int c = 0; c < NCH_; ++c)
            m = fmaxf(m, Mpart[(size_t)(bh * NCH_ + c) * 48 + tid]);
        float l = 0.f;
        for (int c = 0; c < NCH_; ++c) {
            float wf = __expf(Mpart[(size_t)(bh * NCH_ + c) * 48 + tid] - m);
            wfac[c][tid] = wf;
            l += wf * Lpart[(size_t)(bh * NCH_ + c) * 48 + tid];
        }
        lfin[tid] = l;
    }
    __syncthreads();
    for (int e = tid; e < U_ * DK_; e += 256) {
        int row = e >> 6, col = e & 63;
        float o = 0.f;
        for (int c = 0; c < NCH_; ++c)
            o += wfac[c][row] * Opart[((size_t)(bh * NCH_ + c) * 48 + row) * 64 + col];
        upd[((size_t)bh * U_ + row) * DK_ + col] = o / lfin[row];
    }
}

__global__ void ctx_fill2(const float* __restrict__ vm, const float* __restrict__ upd,
                          const int* __restrict__ rowmap, float* __restrict__ ctx) {
    size_t i = ((size_t)blockIdx.x * 256 + threadIdx.x) * 4;
    int c = (int)(i & (DM_ - 1));
    size_t bl = i >> 10;
    int l = (int)(bl & (S_ - 1));
    int b = (int)(bl >> 11);
    int h = c >> 6, d = c & (DK_ - 1);
    int bh = b * H_ + h;
    int u = rowmap[(size_t)bh * S_ + l];
    float4 val;
    if (u >= 0)
        val = *(const float4*)(upd + ((size_t)bh * U_ + u) * DK_ + d);
    else
        val = *(const float4*)(vm + bh * DK_ + d);
    *(float4*)(ctx + i) = val;
}

// bias + residual + LayerNorm. Wave shfl reduce + 2 barriers, float4 I/O.
__global__ void ln_kernel(const float* __restrict__ fcout, const float* __restrict__ fcb,
                          const float* __restrict__ resid,
                          const float* __restrict__ lnw, const float* __restrict__ lnb,
                          float* __restrict__ out) {
    __shared__ float sred[8];
    int row = blockIdx.x, tid = threadIdx.x, lane = tid & 63, w = tid >> 6;
    size_t base = (size_t)row * DM_ + tid * 4;
    float4 f = *(const float4*)(fcout + base);
    float4 bb = *(const float4*)(fcb + tid * 4);
    float4 rs = *(const float4*)(resid + base);
    float x[4] = {f.x + bb.x + rs.x, f.y + bb.y + rs.y,
                  f.z + bb.z + rs.z, f.w + bb.w + rs.w};
    float s = x[0] + x[1] + x[2] + x[3];
#pragma unroll
    for (int off = 1; off < 64; off <<= 1) s += __shfl_xor(s, off, 64);
    if (lane == 0) sred[w] = s;
    __syncthreads();
    float mu = (sred[0] + sred[1] + sred[2] + sred[3]) * (1.f / (float)DM_);
    float vs = 0.f;
#pragma unroll
    for (int j = 0; j < 4; ++j) { float d = x[j] - mu; vs += d * d; }
#pragma unroll
    for (int off = 1; off < 64; off <<= 1) vs += __shfl_xor(vs, off, 64);
    if (lane == 0) sred[4 + w] = vs;
    __syncthreads();
    float rstd = rsqrtf((sred[4] + sred[5] + sred[6] + sred[7]) * (1.f / (float)DM_) + 1e-6f);
    float4 wv = *(const float4*)(lnw + tid * 4);
    float4 bv = *(const float4*)(lnb + tid * 4);
    float4 o;
    o.x = (x[0] - mu) * rstd * wv.x + bv.x;
    o.y = (x[1] - mu) * rstd * wv.y + bv.y;
    o.z = (x[2] - mu) * rstd * wv.z + bv.z;
    o.w = (x[3] - mu) * rstd * wv.w + bv.w;
    *(float4*)(out + base) = o;
}

// ================= launch =================

extern "C" void kernel_launch(void* const* d_in, const int* in_sizes, int n_in,
                              void* d_out, int out_size, void* d_ws, size_t ws_size,
                              hipStream_t stream) {
    if (n_in < 9 || d_ws == nullptr || d_out == nullptr) return;

    const float* hs  = (const float*)d_in[0];
    const float* wq  = (const float*)d_in[1];
    const float* wk  = (const float*)d_in[2];
    const float* wv  = (const float*)d_in[3];
    const float* fcw = (const float*)d_in[4];
    const float* fcb = (const float*)d_in[5];
    const float* lnw = (const float*)d_in[6];
    const float* lnb = (const float*)d_in[7];
    const int* idxs  = (const int*)d_in[8];

    const size_t MD = (size_t)B_ * S_ * DM_;  // 4194304
    const int M = B_ * S_;                    // 4096
    float* out = (float*)d_out;
    char* base = (char*)d_ws;

    if (ws_size >= 66ull * 1024 * 1024) {
        // ---- NEW PATH
        float* q   = (float*)base;                       // 16 MB [later ctx]
        float* k   = (float*)(base + (16ull << 20));     // 16 MB [later fcout]
        u16* Ahi   = (u16*)(base + (32ull << 20));       // 8 MB [later Opart]
        u16* Alo   = (u16*)(base + (40ull << 20));       // 8 MB
        u16* Wqh   = (u16*)(base + (48ull << 20));       // 6 x 2 MB
        u16* Wql   = Wqh + (1u << 20);
        u16* Wkh   = Wql + (1u << 20);
        u16* Wkl   = Wkh + (1u << 20);
        u16* Wvh   = Wkl + (1u << 20);
        u16* Fct   = Wvh + (1u << 20);
        float* mbuf  = (float*)(base + (60ull << 20));         // B*H*S = 65536 f
        float* vmean = mbuf + (size_t)B_ * H_ * S_;            // 2048 f (raw sum)
        int* mtop    = (int*)(vmean + B_ * H_ * DK_);          // 1280 i
        int* rowmap  = (int*)(mtop + B_ * H_ * U_);            // 65536 i
        float* v = out;
        // Opart over Ahi/Alo (dead after gemm_qkv_v7); q stays live for attn gather
        float* Opart = (float*)(base + (32ull << 20));
        float* Mpart = Opart + (size_t)512 * 48 * 64;
        float* Lpart = Mpart + (size_t)512 * 48;
        u16* ctxb = (u16*)q;     // after attn (q dead post-attn_chunk2)
        float* fcout = k;        // after k dead (post-attn_chunk2)

        conv_all<<<3073, 256, 0, stream>>>(hs, wq, wk, wv, fcw, Ahi, Alo,
                                           Wqh, Wql, Wkh, Wkl, Wvh, Fct, vmean);
        gemm_qkv_v7<<<768, 256, 0, stream>>>(Ahi, Alo, Wqh, Wql, Wkh, Wkl, Wvh,
                                             q, k, v, vmean);

        m_score_v5<<<B_ * S_, 1024, 0, stream>>>(q, k, idxs, mbuf, rowmap);
        topk_wave<<<B_ * H_, 64, 0, stream>>>(mbuf, mtop, rowmap);

        attn_chunk2<<<B_ * H_ * NCH_, 256, 0, stream>>>(q, mtop, k, v, Opart, Mpart, Lpart);

        ctx_fill4<<<(int)(MD / 1024), 256, 0, stream>>>(vmean, Opart, Mpart, Lpart, rowmap, ctxb);

        gemm_fc_v7<<<512, 256, 0, stream>>>(ctxb, Fct, fcout);
        ln_kernel<<<M, 256, 0, stream>>>(fcout, fcb, hs, lnw, lnb, out);
        return;
    }

    // ---- OLD PATH (fallback, needs >= 34 MB)
    if (ws_size < 34ull * 1024 * 1024) return;
    float* ws = (float*)d_ws;
    float* q = ws;
    float* k = ws + MD;
    float* mbuf = ws + 2 * MD;
    float* vmean = mbuf + (size_t)B_ * H_ * S_;
    float* upd = vmean + B_ * H_ * DK_;
    int* mtop = (int*)(upd + (size_t)B_ * H_ * U_ * DK_);
    float* qsel = (float*)(mtop + B_ * H_ * U_);
    float* vpart = qsel + (size_t)B_ * H_ * 48 * 64;
    int* rowmap = (int*)(vpart + (size_t)B_ * H_ * VCH_ * DK_);
    float* v = out;
    float* Opart = q;
    float* Mpart = Opart + (size_t)512 * 48 * 64;
    float* Lpart = Mpart + (size_t)512 * 48;
    float* ctx = q;
    float* fcout = k;

    gemm_qkv<<<1536, 256, 0, stream>>>(hs, wq, wk, wv, q, k, v);

    m_score_v3<<<(B_ * H_ * S_) / 4, 256, 0, stream>>>(q, k, idxs, mbuf, rowmap);
    topk_wave<<<B_ * H_, 64, 0, stream>>>(mbuf, mtop, rowmap);
    vmean_part<<<B_ * H_ * VCH_, 256, 0, stream>>>(v, vpart);
    vmean_comb<<<B_ * H_, 64, 0, stream>>>(vpart, vmean);
    gather_qsel<<<B_ * H_, 256, 0, stream>>>(q, mtop, qsel);

    attn_chunk<<<B_ * H_ * NCH_, 256, 0, stream>>>(qsel, k, v, Opart, Mpart, Lpart);
    attn_combine<<<B_ * H_, 256, 0, stream>>>(Opart, Mpart, Lpart, upd);

    ctx_fill2<<<(int)(MD / 1024), 256, 0, stream>>>(vmean, upd, rowmap, ctx);

    mfma_gemm_v2<<<512, 256, 0, stream>>>(ctx, fcw, fcout, M, DM_, DM_, 1.0f);
    ln_kernel<<<M, 256, 0, stream>>>(fcout, fcb, hs, lnw, lnb, out);
}

// Round 8
// 284.183 us; speedup vs baseline: 1.1571x; 1.0595x over previous
//
#include <hip/hip_runtime.h>
#include <hip/hip_bf16.h>

#define B_  2
#define S_  2048
#define DM_ 1024
#define H_  16
#define DK_ 64
#define SK_ 40   // SAMPLE_K
#define U_  40   // top-k u
#define CH_ 128  // attn chunk columns
#define NCH_ (S_ / CH_)  // 16
#define VCH_ 64  // vmean chunks per (b,h)

typedef __attribute__((ext_vector_type(8))) short short8;
typedef __attribute__((ext_vector_type(4))) short short4v;
typedef __attribute__((ext_vector_type(4))) float f32x4;
typedef unsigned short u16;

union BF16S { __hip_bfloat16 h; short s; };
static __device__ __forceinline__ short f2bs(float x) {
    BF16S u; u.h = __float2bfloat16(x); return u.s;
}
static __device__ __forceinline__ void fsplit(float x, short& h, short& l) {
    BF16S u; u.h = __float2bfloat16(x);
    h = u.s;
    BF16S v; v.h = __float2bfloat16(x - __bfloat162float(u.h));
    l = v.s;
}

// async global->LDS, 16 bytes per lane. LDS dest must be wave-uniform base + lane*16.
static __device__ __forceinline__ void gload16(const void* g, void* s) {
    __builtin_amdgcn_global_load_lds(
        (const __attribute__((address_space(1))) void*)g,
        (__attribute__((address_space(3))) void*)s, 16, 0, 0);
}

// LDS bank swizzle (involution): flip byte bits [6:4] with bits [9:7] (row bits 1..3).
// Turns the 8-way conflict of 64B-row ds_read_b128 column reads into 2-way (free).
static __device__ __forceinline__ int swzb(int b) {
    return b ^ (((b >> 7) & 7) << 4);
}

// =====================================================================
// NEW PATH kernels
// =====================================================================

// One-dispatch prep: [0,2048) hs->hi/lo planes, [2048,3072) weight transpose+cvt,
// [3072] zero the vmean accumulator.
__global__ __launch_bounds__(256) void conv_all(
    const float* __restrict__ hs,
    const float* __restrict__ wq, const float* __restrict__ wk,
    const float* __restrict__ wv, const float* __restrict__ fcw,
    u16* __restrict__ Ahi, u16* __restrict__ Alo,
    u16* __restrict__ qh, u16* __restrict__ ql,
    u16* __restrict__ kh, u16* __restrict__ kl,
    u16* __restrict__ vh, u16* __restrict__ fh,
    float* __restrict__ vmean_acc) {
    __shared__ float T[64][65];
    int bid = blockIdx.x, tid = threadIdx.x;
    if (bid < 2048) {
        size_t i = ((size_t)bid * 256 + tid) * 8;
        float a[8];
        *(float4*)&a[0] = *(const float4*)(hs + i);
        *(float4*)&a[4] = *(const float4*)(hs + i + 4);
        short8 h, l;
#pragma unroll
        for (int e = 0; e < 8; ++e) {
            short hh, ll;
            fsplit(a[e], hh, ll);
            h[e] = hh; l[e] = ll;
        }
        *(short8*)&Ahi[i] = h;
        *(short8*)&Alo[i] = l;
        return;
    }
    if (bid >= 3072) {
        for (int j = tid; j < B_ * H_ * DK_; j += 256) vmean_acc[j] = 0.f;
        return;
    }
    int mode = (bid - 2048) >> 8;
    int tb = (bid - 2048) & 255;
    int ty = tb >> 4, tx = tb & 15;
    const float* src = (mode == 0) ? wq : (mode == 1) ? wk : (mode == 2) ? wv : fcw;
    u16* dh = (mode == 0) ? qh : (mode == 1) ? kh : (mode == 2) ? vh : fh;
    u16* dl = (mode == 0) ? ql : kl;
    bool split = (mode < 2);
    int r = tid >> 2, cq = (tid & 3) * 16;

    const float* sp = src + (size_t)(ty * 64 + r) * 1024 + tx * 64 + cq;
#pragma unroll
    for (int j = 0; j < 16; j += 4) *(float4*)&T[r][cq + j] = *(const float4*)(sp + j);
    __syncthreads();

    short8 h0, h1, l0, l1;
#pragma unroll
    for (int j = 0; j < 8; ++j) {
        short hh, ll;
        fsplit(T[cq + j][r], hh, ll);
        h0[j] = hh; l0[j] = ll;
        fsplit(T[cq + 8 + j][r], hh, ll);
        h1[j] = hh; l1[j] = ll;
    }
    size_t off = (size_t)(tx * 64 + r) * 1024 + ty * 64 + cq;
    *(short8*)&dh[off] = h0;
    *(short8*)&dh[off + 8] = h1;
    if (split) {
        *(short8*)&dl[off] = l0;
        *(short8*)&dl[off + 8] = l1;
    }
}

// fused q/k/v projection (R5 known-good). 2-deep counted-vmcnt pipeline with
// MFMA-before-bar2. Swizzled LDS, mode-striped XCD chunking. v-mode epilogue
// accumulates column sums -> vmean.
__global__ __launch_bounds__(256) void gemm_qkv_v7(
    const u16* __restrict__ Ahi, const u16* __restrict__ Alo,
    const u16* __restrict__ Wqh, const u16* __restrict__ Wql,
    const u16* __restrict__ Wkh, const u16* __restrict__ Wkl,
    const u16* __restrict__ Wvh,
    float* __restrict__ q, float* __restrict__ k, float* __restrict__ v,
    float* __restrict__ vmean_acc) {
    __shared__ alignas(16) u16 lds[2][4][128 * 32];  // 64 KB
    int bid = (int)blockIdx.x;
    int xcd = bid & 7, ii = bid >> 3;          // ii in 0..95
    int mode = ii >> 5;                        // 0..2 (q,k,v)
    int rr = xcd * 32 + (ii & 31);             // tile within mode, 0..255
    int by = rr >> 3, bx = rr & 7;
    const u16* Bh = (mode == 0) ? Wqh : (mode == 1) ? Wkh : Wvh;
    const u16* Bl = (mode == 0) ? Wql : Wkl;  // unused for v
    float* C = (mode == 0) ? q : (mode == 1) ? k : v;
    float scale = (mode == 0) ? 0.125f : 1.0f;
    bool split = (mode < 2);

    int tid = threadIdx.x, lane = tid & 63, w = tid >> 6;
    int wr = w >> 1, wc = w & 1;
    int ml = lane & 15, kq = lane >> 4;

    f32x4 acc[4][4];
#pragma unroll
    for (int i = 0; i < 4; ++i)
#pragma unroll
        for (int j = 0; j < 4; ++j) acc[i][j] = (f32x4){0.f, 0.f, 0.f, 0.f};

    const u16* Agh = Ahi + (size_t)(by * 128) * 1024;
    const u16* Agl = Alo + (size_t)(by * 128) * 1024;
    const u16* Bgh = Bh + (size_t)(bx * 128) * 1024;
    const u16* Bgl = Bl + (size_t)(bx * 128) * 1024;

    int pl0 = tid * 16, pl1 = 4096 + tid * 16;
    int d0 = swzb(pl0), d1 = swzb(pl1);
    int gs0 = (d0 >> 6) * 1024 + ((d0 & 63) >> 1);
    int gs1 = (d1 >> 6) * 1024 + ((d1 & 63) >> 1);
    int ld0 = tid * 8, ld1 = 2048 + tid * 8;

    int offA[4], offB[4];
#pragma unroll
    for (int mt = 0; mt < 4; ++mt) {
        int d = (wr * 64 + mt * 16 + ml) * 64 + kq * 16;
        offA[mt] = swzb(d);
    }
#pragma unroll
    for (int nt = 0; nt < 4; ++nt) {
        int d = (wc * 64 + nt * 16 + ml) * 64 + kq * 16;
        offB[nt] = swzb(d);
    }

    auto STAGE = [&](int bf, int k0) {
        gload16(Agh + gs0 + k0, &lds[bf][0][ld0]);
        gload16(Agh + gs1 + k0, &lds[bf][0][ld1]);
        gload16(Bgh + gs0 + k0, &lds[bf][2][ld0]);
        gload16(Bgh + gs1 + k0, &lds[bf][2][ld1]);
        if (split) {
            gload16(Agl + gs0 + k0, &lds[bf][1][ld0]);
            gload16(Agl + gs1 + k0, &lds[bf][1][ld1]);
            gload16(Bgl + gs0 + k0, &lds[bf][3][ld0]);
            gload16(Bgl + gs1 + k0, &lds[bf][3][ld1]);
        }
    };

    STAGE(0, 0);
    STAGE(1, 32);
    int cur = 0;
    for (int t = 0; t < 32; ++t) {
        if (t == 31)      asm volatile("s_waitcnt vmcnt(0)" ::: "memory");
        else if (split)   asm volatile("s_waitcnt vmcnt(8)" ::: "memory");
        else              asm volatile("s_waitcnt vmcnt(4)" ::: "memory");
        __builtin_amdgcn_s_barrier();           // tile t visible to all waves
        __builtin_amdgcn_sched_barrier(0);

        const char* Ah_ = (const char*)lds[cur][0];
        const char* Al_ = (const char*)lds[cur][1];
        const char* Bh_ = (const char*)lds[cur][2];
        const char* Bl_ = (const char*)lds[cur][3];
        short8 a_h[4], b_h[4], a_l[4], b_l[4];
#pragma unroll
        for (int mt = 0; mt < 4; ++mt) a_h[mt] = *(const short8*)(Ah_ + offA[mt]);
#pragma unroll
        for (int nt = 0; nt < 4; ++nt) b_h[nt] = *(const short8*)(Bh_ + offB[nt]);
        if (split) {
#pragma unroll
            for (int mt = 0; mt < 4; ++mt) a_l[mt] = *(const short8*)(Al_ + offA[mt]);
#pragma unroll
            for (int nt = 0; nt < 4; ++nt) b_l[nt] = *(const short8*)(Bl_ + offB[nt]);
        }

        __builtin_amdgcn_s_setprio(1);
#pragma unroll
        for (int mt = 0; mt < 4; ++mt)
#pragma unroll
            for (int nt = 0; nt < 4; ++nt)
                acc[mt][nt] = __builtin_amdgcn_mfma_f32_16x16x32_bf16(a_h[mt], b_h[nt], acc[mt][nt], 0, 0, 0);
        if (split) {
#pragma unroll
            for (int mt = 0; mt < 4; ++mt)
#pragma unroll
                for (int nt = 0; nt < 4; ++nt) {
                    acc[mt][nt] = __builtin_amdgcn_mfma_f32_16x16x32_bf16(a_h[mt], b_l[nt], acc[mt][nt], 0, 0, 0);
                    acc[mt][nt] = __builtin_amdgcn_mfma_f32_16x16x32_bf16(a_l[mt], b_h[nt], acc[mt][nt], 0, 0, 0);
                }
        }
        __builtin_amdgcn_s_setprio(0);

        if (t < 31) {
            __builtin_amdgcn_s_barrier();       // all waves consumed buf[cur]
            __builtin_amdgcn_sched_barrier(0);
            if (t < 30) STAGE(cur, (t + 2) * 32);
        }
        cur ^= 1;
    }
#pragma unroll
    for (int mt = 0; mt < 4; ++mt)
#pragma unroll
        for (int nt = 0; nt < 4; ++nt)
#pragma unroll
            for (int r2 = 0; r2 < 4; ++r2) {
                int row = by * 128 + wr * 64 + mt * 16 + kq * 4 + r2;
                int col = bx * 128 + wc * 64 + nt * 16 + ml;
                C[(size_t)row * 1024 + col] = acc[mt][nt][r2] * scale;
            }
    if (mode == 2) {
        int b = by >> 4;
#pragma unroll
        for (int nt = 0; nt < 4; ++nt) {
            float s = 0.f;
#pragma unroll
            for (int mt = 0; mt < 4; ++mt)
#pragma unroll
                for (int r2 = 0; r2 < 4; ++r2) s += acc[mt][nt][r2];
            s += __shfl_xor(s, 16, 64);
            s += __shfl_xor(s, 32, 64);
            if (kq == 0) {
                int col = bx * 128 + wc * 64 + nt * 16 + ml;
                int h = col >> 6, d = col & 63;
                atomicAdd(&vmean_acc[(b * H_ + h) * DK_ + d], s);
            }
        }
    }
}

// m-score v3 + rowmap init (R5-verified high-TLP config: 4 waves/block, 16384 blocks).
__global__ void m_score_v3(const float* __restrict__ q, const float* __restrict__ k,
                           const int* __restrict__ idxs, float* __restrict__ m_out,
                           int* __restrict__ rowmap) {
    int gwave = blockIdx.x * 4 + (threadIdx.x >> 6);
    int lane = threadIdx.x & 63;
    if (gwave >= B_ * H_ * S_) return;
    int l = gwave % S_;
    int bh = gwave / S_;
    int h = bh & 15, b = bh >> 4;
    int sl = lane >> 3;
    int dc = lane & 7;

    const float* qr = q + ((size_t)(b * S_ + l)) * DM_ + h * DK_ + dc * 8;
    float4 q0 = *(const float4*)qr;
    float4 q1 = *(const float4*)(qr + 4);
    const float* kb = k + (size_t)b * S_ * DM_ + h * DK_ + dc * 8;

    float mx = -INFINITY, sm = 0.f;
#pragma unroll
    for (int c = 0; c < 5; ++c) {
        int s = c * 8 + sl;
        int idx = idxs[l * SK_ + s];
        idx = (idx < 0) ? 0 : (idx >= S_ ? S_ - 1 : idx);
        const float* kr = kb + (size_t)idx * DM_;
        float4 k0 = *(const float4*)kr;
        float4 k1 = *(const float4*)(kr + 4);
        float d = q0.x * k0.x + q0.y * k0.y + q0.z * k0.z + q0.w * k0.w +
                  q1.x * k1.x + q1.y * k1.y + q1.z * k1.z + q1.w * k1.w;
        d += __shfl_xor(d, 1, 64);
        d += __shfl_xor(d, 2, 64);
        d += __shfl_xor(d, 4, 64);
        mx = fmaxf(mx, d);
        sm += d;
    }
#pragma unroll
    for (int off = 8; off <= 32; off <<= 1) {
        mx = fmaxf(mx, __shfl_xor(mx, off, 64));
        sm += __shfl_xor(sm, off, 64);
    }
    if (lane == 0) {
        m_out[(size_t)bh * S_ + l] = mx - sm * (1.f / (float)S_);
        rowmap[(size_t)bh * S_ + l] = -1;
    }
}

// top-40, single wave per (b,h), register-resident, barrier-free.
__global__ void topk_wave(const float* __restrict__ m, int* __restrict__ mtop,
                          int* __restrict__ rowmap) {
    int bh = blockIdx.x;
    int lane = threadIdx.x;
    const float* mb = m + (size_t)bh * S_;
    float vals[32];
#pragma unroll
    for (int j = 0; j < 32; ++j) vals[j] = mb[j * 64 + lane];
    float lmax = -INFINITY;
    int lj = 0;
#pragma unroll
    for (int j = 0; j < 32; ++j)
        if (vals[j] > lmax) { lmax = vals[j]; lj = j; }

    for (int it = 0; it < U_; ++it) {
        float wv = lmax;
        int wi = lj * 64 + lane;
#pragma unroll
        for (int off = 1; off < 64; off <<= 1) {
            float ov = __shfl_xor(wv, off, 64);
            int oi = __shfl_xor(wi, off, 64);
            if (ov > wv || (ov == wv && oi < wi)) { wv = ov; wi = oi; }
        }
        if (lane == 0) {
            mtop[bh * U_ + it] = wi;
            rowmap[(size_t)bh * S_ + wi] = it;
        }
        if ((wi & 63) == lane) {
            int jw = wi >> 6;
#pragma unroll
            for (int t = 0; t < 32; ++t)
                if (t == jw) vals[t] = -INFINITY;
            lmax = -INFINITY;
            lj = 0;
#pragma unroll
            for (int t = 0; t < 32; ++t)
                if (vals[t] > lmax) { lmax = vals[t]; lj = t; }
        }
    }
}

// ctx one-pass with INLINE chunk-combine for selected rows (attn_combine fused).
__global__ void ctx_fill4(const float* __restrict__ vm,
                          const float* __restrict__ Opart,
                          const float* __restrict__ Mpart,
                          const float* __restrict__ Lpart,
                          const int* __restrict__ rowmap, u16* __restrict__ ctx) {
    size_t i = ((size_t)blockIdx.x * 256 + threadIdx.x) * 4;  // over B*S*DM
    int c = (int)(i & (DM_ - 1));
    size_t bl = i >> 10;
    int l = (int)(bl & (S_ - 1));
    int b = (int)(bl >> 11);
    int h = c >> 6, d = c & (DK_ - 1);
    int bh = b * H_ + h;
    int u = rowmap[(size_t)bh * S_ + l];
    float4 val;
    if (u >= 0) {
        float m = -1e30f;
#pragma unroll
        for (int c2 = 0; c2 < NCH_; ++c2)
            m = fmaxf(m, Mpart[(size_t)(bh * NCH_ + c2) * 48 + u]);
        float lf = 0.f;
        float o0 = 0.f, o1 = 0.f, o2 = 0.f, o3 = 0.f;
#pragma unroll
        for (int c2 = 0; c2 < NCH_; ++c2) {
            float wf = __expf(Mpart[(size_t)(bh * NCH_ + c2) * 48 + u] - m);
            lf += wf * Lpart[(size_t)(bh * NCH_ + c2) * 48 + u];
            const float* op = Opart + ((size_t)(bh * NCH_ + c2) * 48 + u) * 64 + d;
            o0 += wf * op[0];
            o1 += wf * op[1];
            o2 += wf * op[2];
            o3 += wf * op[3];
        }
        val.x = o0 / lf; val.y = o1 / lf; val.z = o2 / lf; val.w = o3 / lf;
    } else {
        val = *(const float4*)(vm + bh * DK_ + d);
        const float is = 1.f / (float)S_;
        val.x *= is; val.y *= is; val.z *= is; val.w *= is;
    }
    short4v o;
    o[0] = f2bs(val.x); o[1] = f2bs(val.y); o[2] = f2bs(val.z); o[3] = f2bs(val.w);
    *(short4v*)&ctx[i] = o;
}

// fc GEMM v8: ctx(bf16) @ FcT(bf16)^T -> fp32. 128x128 tile (structure of the
// R6-verified gemm_v_v8), BK=32, 2-deep counted-vmcnt pipeline, swizzled LDS,
// XCD-chunked (256 blocks = 1/CU, 16 MFMA per 16 ds_reads).
__global__ __launch_bounds__(256) void gemm_fc_v8(const u16* __restrict__ A,
                                                  const u16* __restrict__ Bt,
                                                  float* __restrict__ C) {
    __shared__ alignas(16) u16 lds[2][2][128 * 32];  // 32 KB
    int bid = (int)blockIdx.x;
    int xcd = bid & 7, ii = bid >> 3;          // 0..31
    int rr = xcd * 32 + ii;                    // 0..255
    int by = rr >> 3, bx = rr & 7;

    int tid = threadIdx.x, lane = tid & 63, w = tid >> 6;
    int wr = w >> 1, wc = w & 1;
    int ml = lane & 15, kq = lane >> 4;

    f32x4 acc[4][4];
#pragma unroll
    for (int i = 0; i < 4; ++i)
#pragma unroll
        for (int j = 0; j < 4; ++j) acc[i][j] = (f32x4){0.f, 0.f, 0.f, 0.f};

    const u16* Agh = A + (size_t)(by * 128) * 1024;
    const u16* Bgh = Bt + (size_t)(bx * 128) * 1024;

    int pl0 = tid * 16, pl1 = 4096 + tid * 16;
    int d0 = swzb(pl0), d1 = swzb(pl1);
    int gs0 = (d0 >> 6) * 1024 + ((d0 & 63) >> 1);
    int gs1 = (d1 >> 6) * 1024 + ((d1 & 63) >> 1);
    int ld0 = tid * 8, ld1 = 2048 + tid * 8;

    int offA[4], offB[4];
#pragma unroll
    for (int mt = 0; mt < 4; ++mt) {
        int d = (wr * 64 + mt * 16 + ml) * 64 + kq * 16;
        offA[mt] = swzb(d);
    }
#pragma unroll
    for (int nt = 0; nt < 4; ++nt) {
        int d = (wc * 64 + nt * 16 + ml) * 64 + kq * 16;
        offB[nt] = swzb(d);
    }

    auto STAGE = [&](int bf, int k0) {
        gload16(Agh + gs0 + k0, &lds[bf][0][ld0]);
        gload16(Agh + gs1 + k0, &lds[bf][0][ld1]);
        gload16(Bgh + gs0 + k0, &lds[bf][1][ld0]);
        gload16(Bgh + gs1 + k0, &lds[bf][1][ld1]);
    };

    STAGE(0, 0);
    STAGE(1, 32);
    int cur = 0;
    for (int t = 0; t < 32; ++t) {
        if (t == 31) asm volatile("s_waitcnt vmcnt(0)" ::: "memory");
        else         asm volatile("s_waitcnt vmcnt(4)" ::: "memory");
        __builtin_amdgcn_s_barrier();
        __builtin_amdgcn_sched_barrier(0);

        const char* Ah_ = (const char*)lds[cur][0];
        const char* Bh_ = (const char*)lds[cur][1];
        short8 a_h[4], b_h[4];
#pragma unroll
        for (int mt = 0; mt < 4; ++mt) a_h[mt] = *(const short8*)(Ah_ + offA[mt]);
#pragma unroll
        for (int nt = 0; nt < 4; ++nt) b_h[nt] = *(const short8*)(Bh_ + offB[nt]);

        __builtin_amdgcn_s_setprio(1);
#pragma unroll
        for (int mt = 0; mt < 4; ++mt)
#pragma unroll
            for (int nt = 0; nt < 4; ++nt)
                acc[mt][nt] = __builtin_amdgcn_mfma_f32_16x16x32_bf16(a_h[mt], b_h[nt], acc[mt][nt], 0, 0, 0);
        __builtin_amdgcn_s_setprio(0);

        if (t < 31) {
            __builtin_amdgcn_s_barrier();
            __builtin_amdgcn_sched_barrier(0);
            if (t < 30) STAGE(cur, (t + 2) * 32);
        }
        cur ^= 1;
    }
#pragma unroll
    for (int mt = 0; mt < 4; ++mt)
#pragma unroll
        for (int nt = 0; nt < 4; ++nt)
#pragma unroll
            for (int r2 = 0; r2 < 4; ++r2) {
                int row = by * 128 + wr * 64 + mt * 16 + kq * 4 + r2;
                int col = bx * 128 + wc * 64 + nt * 16 + ml;
                C[(size_t)row * 1024 + col] = acc[mt][nt][r2];
            }
}

// split-K flash attention with fused Q-gather (reads q + mtop directly).
__global__ __launch_bounds__(256) void attn_chunk2(const float* __restrict__ q,
                                                   const int* __restrict__ mtop,
                                                   const float* __restrict__ k,
                                                   const float* __restrict__ v,
                                                   float* __restrict__ Opart,
                                                   float* __restrict__ Mpart,
                                                   float* __restrict__ Lpart) {
    __shared__ alignas(16) __hip_bfloat16 Qs[48][72];
    __shared__ alignas(16) __hip_bfloat16 Vt[64][136];
    __shared__ alignas(16) __hip_bfloat16 Ps[48][136];
    __shared__ float mpart[4][48], lpart[4][48];
    __shared__ float mrow[48];
    int blk = blockIdx.x;
    int bh = blk / NCH_, ch = blk % NCH_;
    int b = bh >> 4, h = bh & 15;
    int c0 = ch * CH_;
    int tid = threadIdx.x, lane = tid & 63, w = tid >> 6;
    int ml = lane & 15, kq = lane >> 4;

    {
        int u = tid >> 2, dq = (tid & 3) * 16;
        if (u < U_) {
            int row = mtop[bh * U_ + u];
            row = (row < 0) ? 0 : (row >= S_ ? S_ - 1 : row);
            const float* src = q + ((size_t)(b * S_ + row)) * DM_ + h * DK_ + dq;
#pragma unroll
            for (int j = 0; j < 16; j += 4) {
                float4 v4 = *(const float4*)(src + j);
                Qs[u][dq + j + 0] = __float2bfloat16(v4.x);
                Qs[u][dq + j + 1] = __float2bfloat16(v4.y);
                Qs[u][dq + j + 2] = __float2bfloat16(v4.z);
                Qs[u][dq + j + 3] = __float2bfloat16(v4.w);
            }
        } else if (u < 48) {
#pragma unroll
            for (int j = 0; j < 16; ++j) Qs[u][dq + j] = __float2bfloat16(0.f);
        }
    }
    {
        int klocal = tid >> 1, dq = (tid & 1) * 32;
        const float* vr = v + (size_t)(b * S_ + c0 + klocal) * DM_ + h * DK_ + dq;
#pragma unroll
        for (int jj = 0; jj < 32; jj += 4) {
            float4 v4 = *(const float4*)(vr + jj);
            Vt[dq + jj + 0][klocal] = __float2bfloat16(v4.x);
            Vt[dq + jj + 1][klocal] = __float2bfloat16(v4.y);
            Vt[dq + jj + 2][klocal] = __float2bfloat16(v4.z);
            Vt[dq + jj + 3][klocal] = __float2bfloat16(v4.w);
        }
    }
    __syncthreads();

    const float* Kb = k + (size_t)b * S_ * DM_ + h * DK_;
    f32x4 sreg[3][2];
#pragma unroll
    for (int i = 0; i < 3; ++i)
#pragma unroll
        for (int j = 0; j < 2; ++j) sreg[i][j] = (f32x4){0.f, 0.f, 0.f, 0.f};
#pragma unroll
    for (int ntl = 0; ntl < 2; ++ntl) {
        int krow = c0 + (w * 2 + ntl) * 16 + ml;
        const float* kr = Kb + (size_t)krow * DM_;
        float4 x0 = *(const float4*)(kr + kq * 8);
        float4 x1 = *(const float4*)(kr + kq * 8 + 4);
        float4 y0 = *(const float4*)(kr + 32 + kq * 8);
        float4 y1 = *(const float4*)(kr + 32 + kq * 8 + 4);
        short8 b0, b1;
        b0[0] = f2bs(x0.x); b0[1] = f2bs(x0.y); b0[2] = f2bs(x0.z); b0[3] = f2bs(x0.w);
        b0[4] = f2bs(x1.x); b0[5] = f2bs(x1.y); b0[6] = f2bs(x1.z); b0[7] = f2bs(x1.w);
        b1[0] = f2bs(y0.x); b1[1] = f2bs(y0.y); b1[2] = f2bs(y0.z); b1[3] = f2bs(y0.w);
        b1[4] = f2bs(y1.x); b1[5] = f2bs(y1.y); b1[6] = f2bs(y1.z); b1[7] = f2bs(y1.w);
#pragma unroll
        for (int mt = 0; mt < 3; ++mt) {
            short8 a0 = *(const short8*)&Qs[mt * 16 + ml][kq * 8];
            short8 a1 = *(const short8*)&Qs[mt * 16 + ml][32 + kq * 8];
            sreg[mt][ntl] = __builtin_amdgcn_mfma_f32_16x16x32_bf16(a0, b0, sreg[mt][ntl], 0, 0, 0);
            sreg[mt][ntl] = __builtin_amdgcn_mfma_f32_16x16x32_bf16(a1, b1, sreg[mt][ntl], 0, 0, 0);
        }
    }

    {
        float vmx[3][4];
#pragma unroll
        for (int mt = 0; mt < 3; ++mt)
#pragma unroll
            for (int r = 0; r < 4; ++r)
                vmx[mt][r] = fmaxf(sreg[mt][0][r], sreg[mt][1][r]);
#pragma unroll
        for (int mask = 1; mask <= 8; mask <<= 1)
#pragma unroll
            for (int mt = 0; mt < 3; ++mt)
#pragma unroll
                for (int r = 0; r < 4; ++r)
                    vmx[mt][r] = fmaxf(vmx[mt][r], __shfl_xor(vmx[mt][r], mask, 64));
        if (ml == 0)
#pragma unroll
            for (int mt = 0; mt < 3; ++mt)
#pragma unroll
                for (int r = 0; r < 4; ++r)
                    mpart[w][mt * 16 + kq * 4 + r] = vmx[mt][r];
    }
    __syncthreads();
    if (tid < 48)
        mrow[tid] = fmaxf(fmaxf(mpart[0][tid], mpart[1][tid]),
                          fmaxf(mpart[2][tid], mpart[3][tid]));
    __syncthreads();

    {
        float vsum[3][4] = {{0.f}};
#pragma unroll
        for (int mt = 0; mt < 3; ++mt)
#pragma unroll
            for (int ntl = 0; ntl < 2; ++ntl) {
                int col = (w * 2 + ntl) * 16 + ml;
#pragma unroll
                for (int r = 0; r < 4; ++r) {
                    int row = mt * 16 + kq * 4 + r;
                    float p = __expf(sreg[mt][ntl][r] - mrow[row]);
                    Ps[row][col] = __float2bfloat16(p);
                    vsum[mt][r] += p;
                }
            }
#pragma unroll
        for (int mask = 1; mask <= 8; mask <<= 1)
#pragma unroll
            for (int mt = 0; mt < 3; ++mt)
#pragma unroll
                for (int r = 0; r < 4; ++r)
                    vsum[mt][r] += __shfl_xor(vsum[mt][r], mask, 64);
        if (ml == 0)
#pragma unroll
            for (int mt = 0; mt < 3; ++mt)
#pragma unroll
                for (int r = 0; r < 4; ++r)
                    lpart[w][mt * 16 + kq * 4 + r] = vsum[mt][r];
    }
    __syncthreads();

    f32x4 oreg[3];
#pragma unroll
    for (int i = 0; i < 3; ++i) oreg[i] = (f32x4){0.f, 0.f, 0.f, 0.f};
#pragma unroll
    for (int kt = 0; kt < 4; ++kt) {
        short8 bfq = *(const short8*)&Vt[w * 16 + ml][kt * 32 + kq * 8];
#pragma unroll
        for (int mt = 0; mt < 3; ++mt) {
            short8 af = *(const short8*)&Ps[mt * 16 + ml][kt * 32 + kq * 8];
            oreg[mt] = __builtin_amdgcn_mfma_f32_16x16x32_bf16(af, bfq, oreg[mt], 0, 0, 0);
        }
    }
#pragma unroll
    for (int mt = 0; mt < 3; ++mt)
#pragma unroll
        for (int r = 0; r < 4; ++r) {
            int row = mt * 16 + kq * 4 + r;
            Opart[((size_t)blk * 48 + row) * 64 + w * 16 + ml] = oreg[mt][r];
        }
    if (tid < 48) {
        Mpart[(size_t)blk * 48 + tid] = mrow[tid];
        Lpart[(size_t)blk * 48 + tid] =
            lpart[0][tid] + lpart[1][tid] + lpart[2][tid] + lpart[3][tid];
    }
}

// =====================================================================
// OLD PATH kernels (fallback when workspace < 66 MB) — unchanged
// =====================================================================

__global__ __launch_bounds__(256) void gemm_qkv(const float* __restrict__ hs,
                                                const float* __restrict__ wq,
                                                const float* __restrict__ wk,
                                                const float* __restrict__ wv,
                                                float* __restrict__ q,
                                                float* __restrict__ k,
                                                float* __restrict__ v) {
    __shared__ alignas(16) __hip_bfloat16 Ah[64][40], Al[64][40];
    __shared__ alignas(16) __hip_bfloat16 Bh[128][40], Bl[128][40];
    int idx = blockIdx.x;
    int by = idx / 24;
    int r = idx % 24;
    int mode = r >> 3, bx = r & 7;
    const float* Bm = (mode == 0) ? wq : (mode == 1) ? wk : wv;
    float* C = (mode == 0) ? q : (mode == 1) ? k : v;
    float scale = (mode == 0) ? 0.125f : 1.0f;
    bool split = (mode < 2);

    int tid = threadIdx.x, lane = tid & 63, w = tid >> 6;
    int ml = lane & 15, kq = lane >> 4;

    f32x4 acc[4][2];
#pragma unroll
    for (int i = 0; i < 4; ++i)
#pragma unroll
        for (int j = 0; j < 2; ++j) acc[i][j] = (f32x4){0.f, 0.f, 0.f, 0.f};

    const float* Ab = hs + (size_t)(by * 64) * DM_;
    const float* Bb = Bm + bx * 128;
    int ar = tid >> 2, akq = (tid & 3) * 8;
    int bcol = tid & 127, bkh = tid >> 7;

    for (int k0 = 0; k0 < DM_; k0 += 32) {
        {
            float av[8];
            *(float4*)&av[0] = *(const float4*)(Ab + (size_t)ar * DM_ + k0 + akq);
            *(float4*)&av[4] = *(const float4*)(Ab + (size_t)ar * DM_ + k0 + akq + 4);
            short8 hv, lv;
#pragma unroll
            for (int e = 0; e < 8; ++e) {
                __hip_bfloat16 hb = __float2bfloat16(av[e]);
                hv[e] = ((BF16S){hb}).s;
                lv[e] = f2bs(av[e] - __bfloat162float(hb));
            }
            *(short8*)&Ah[ar][akq] = hv;
            if (split) *(short8*)&Al[ar][akq] = lv;
        }
        {
            float be[16];
            const float* bp = Bb + (size_t)(k0 + bkh * 16) * DM_ + bcol;
#pragma unroll
            for (int j = 0; j < 16; ++j) be[j] = bp[(size_t)j * DM_];
            short8 h0, h1, l0, l1;
#pragma unroll
            for (int e = 0; e < 8; ++e) {
                __hip_bfloat16 hb = __float2bfloat16(be[e]);
                h0[e] = ((BF16S){hb}).s;
                l0[e] = f2bs(be[e] - __bfloat162float(hb));
                __hip_bfloat16 hb2 = __float2bfloat16(be[e + 8]);
                h1[e] = ((BF16S){hb2}).s;
                l1[e] = f2bs(be[e + 8] - __bfloat162float(hb2));
            }
            *(short8*)&Bh[bcol][bkh * 16] = h0;
            *(short8*)&Bh[bcol][bkh * 16 + 8] = h1;
            if (split) {
                *(short8*)&Bl[bcol][bkh * 16] = l0;
                *(short8*)&Bl[bcol][bkh * 16 + 8] = l1;
            }
        }
        __syncthreads();
        short8 ah[4], al[4], bh[2], bl[2];
#pragma unroll
        for (int mt = 0; mt < 4; ++mt) ah[mt] = *(const short8*)&Ah[mt * 16 + ml][kq * 8];
#pragma unroll
        for (int nt = 0; nt < 2; ++nt) bh[nt] = *(const short8*)&Bh[w * 32 + nt * 16 + ml][kq * 8];
        if (split) {
#pragma unroll
            for (int mt = 0; mt < 4; ++mt) al[mt] = *(const short8*)&Al[mt * 16 + ml][kq * 8];
#pragma unroll
            for (int nt = 0; nt < 2; ++nt) bl[nt] = *(const short8*)&Bl[w * 32 + nt * 16 + ml][kq * 8];
#pragma unroll
            for (int mt = 0; mt < 4; ++mt)
#pragma unroll
                for (int nt = 0; nt < 2; ++nt) {
                    acc[mt][nt] = __builtin_amdgcn_mfma_f32_16x16x32_bf16(ah[mt], bh[nt], acc[mt][nt], 0, 0, 0);
                    acc[mt][nt] = __builtin_amdgcn_mfma_f32_16x16x32_bf16(ah[mt], bl[nt], acc[mt][nt], 0, 0, 0);
                    acc[mt][nt] = __builtin_amdgcn_mfma_f32_16x16x32_bf16(al[mt], bh[nt], acc[mt][nt], 0, 0, 0);
                }
        } else {
#pragma unroll
            for (int mt = 0; mt < 4; ++mt)
#pragma unroll
                for (int nt = 0; nt < 2; ++nt)
                    acc[mt][nt] = __builtin_amdgcn_mfma_f32_16x16x32_bf16(ah[mt], bh[nt], acc[mt][nt], 0, 0, 0);
        }
        __syncthreads();
    }
#pragma unroll
    for (int mt = 0; mt < 4; ++mt)
#pragma unroll
        for (int nt = 0; nt < 2; ++nt)
#pragma unroll
            for (int r2 = 0; r2 < 4; ++r2) {
                int row = by * 64 + mt * 16 + kq * 4 + r2;
                int col = bx * 128 + w * 32 + nt * 16 + ml;
                C[(size_t)row * DM_ + col] = acc[mt][nt][r2] * scale;
            }
}

__global__ __launch_bounds__(256) void mfma_gemm_v2(const float* __restrict__ A,
                                                    const float* __restrict__ Bm,
                                                    float* __restrict__ C,
                                                    int M, int N, int K, float scale) {
    __shared__ alignas(16) __hip_bfloat16 Asb[64][40];
    __shared__ alignas(16) __hip_bfloat16 Bsb[128][40];
    int nbx = N >> 7;
    int by = blockIdx.x / nbx, bx = blockIdx.x % nbx;
    int tid = threadIdx.x, lane = tid & 63, w = tid >> 6;
    int ml = lane & 15, kq = lane >> 4;

    f32x4 acc[4][2];
#pragma unroll
    for (int i = 0; i < 4; ++i)
#pragma unroll
        for (int j = 0; j < 2; ++j) acc[i][j] = (f32x4){0.f, 0.f, 0.f, 0.f};

    const float* Ab = A + (size_t)(by * 64) * K;
    const float* Bb = Bm + bx * 128;
    int ar = tid >> 2, akq = (tid & 3) * 8;
    int bcol = tid & 127, bkh = tid >> 7;

    for (int k0 = 0; k0 < K; k0 += 32) {
        {
            float av[8];
            *(float4*)&av[0] = *(const float4*)(Ab + (size_t)ar * K + k0 + akq);
            *(float4*)&av[4] = *(const float4*)(Ab + (size_t)ar * K + k0 + akq + 4);
            short8 hv;
#pragma unroll
            for (int e = 0; e < 8; ++e) hv[e] = f2bs(av[e]);
            *(short8*)&Asb[ar][akq] = hv;
        }
        {
            float be[16];
            const float* bp = Bb + (size_t)(k0 + bkh * 16) * N + bcol;
#pragma unroll
            for (int j = 0; j < 16; ++j) be[j] = bp[(size_t)j * N];
            short8 h0, h1;
#pragma unroll
            for (int e = 0; e < 8; ++e) {
                h0[e] = f2bs(be[e]);
                h1[e] = f2bs(be[e + 8]);
            }
            *(short8*)&Bsb[bcol][bkh * 16] = h0;
            *(short8*)&Bsb[bcol][bkh * 16 + 8] = h1;
        }
        __syncthreads();
        short8 af[4], bf[2];
#pragma unroll
        for (int mt = 0; mt < 4; ++mt) af[mt] = *(const short8*)&Asb[mt * 16 + ml][kq * 8];
#pragma unroll
        for (int nt = 0; nt < 2; ++nt) bf[nt] = *(const short8*)&Bsb[w * 32 + nt * 16 + ml][kq * 8];
#pragma unroll
        for (int mt = 0; mt < 4; ++mt)
#pragma unroll
            for (int nt = 0; nt < 2; ++nt)
                acc[mt][nt] = __builtin_amdgcn_mfma_f32_16x16x32_bf16(af[mt], bf[nt], acc[mt][nt], 0, 0, 0);
        __syncthreads();
    }
#pragma unroll
    for (int mt = 0; mt < 4; ++mt)
#pragma unroll
        for (int nt = 0; nt < 2; ++nt)
#pragma unroll
            for (int r = 0; r < 4; ++r) {
                int row = by * 64 + mt * 16 + kq * 4 + r;
                int col = bx * 128 + w * 32 + nt * 16 + ml;
                C[(size_t)row * N + col] = acc[mt][nt][r] * scale;
            }
}

__global__ void vmean_part(const float* __restrict__ v, float* __restrict__ vpart) {
    __shared__ float part[4][DK_];
    int blk = blockIdx.x;
    int bh = blk >> 6, ch = blk & (VCH_ - 1);
    int b = bh >> 4, h = bh & 15;
    int tid = threadIdx.x, wave = tid >> 6, lane = tid & 63;
    const float* vb = v + (size_t)(b * S_ + ch * 32) * DM_ + h * DK_;
    float s = 0.f;
#pragma unroll
    for (int i = 0; i < 8; ++i)
        s += vb[(size_t)(i * 4 + wave) * DM_ + lane];
    part[wave][lane] = s;
    __syncthreads();
    if (tid < DK_)
        vpart[(size_t)blk * DK_ + tid] =
            part[0][tid] + part[1][tid] + part[2][tid] + part[3][tid];
}

__global__ void vmean_comb(const float* __restrict__ vpart, float* __restrict__ vm) {
    int bh = blockIdx.x, lane = threadIdx.x;
    float s = 0.f;
    for (int c = 0; c < VCH_; ++c)
        s += vpart[(size_t)(bh * VCH_ + c) * DK_ + lane];
    vm[bh * DK_ + lane] = s * (1.f / (float)S_);
}

__global__ void gather_qsel(const float* __restrict__ q, const int* __restrict__ mtop,
                            float* __restrict__ qsel) {
    int bh = blockIdx.x;
    int b = bh >> 4, h = bh & 15;
    int tid = threadIdx.x;
    int u = tid >> 2, dq = (tid & 3) * 16;
    if (u >= 48) return;
    float* dst = qsel + ((size_t)bh * 48 + u) * 64 + dq;
    if (u < U_) {
        int row = mtop[bh * U_ + u];
        row = (row < 0) ? 0 : (row >= S_ ? S_ - 1 : row);
        const float* src = q + ((size_t)(b * S_ + row)) * DM_ + h * DK_ + dq;
#pragma unroll
        for (int j = 0; j < 16; j += 4) *(float4*)(dst + j) = *(const float4*)(src + j);
    } else {
        float4 z = {0.f, 0.f, 0.f, 0.f};
#pragma unroll
        for (int j = 0; j < 16; j += 4) *(float4*)(dst + j) = z;
    }
}

__global__ __launch_bounds__(256) void attn_chunk(const float* __restrict__ qsel,
                                                  const float* __restrict__ k,
                                                  const float* __restrict__ v,
                                                  float* __restrict__ Opart,
                                                  float* __restrict__ Mpart,
                                                  float* __restrict__ Lpart) {
    __shared__ alignas(16) __hip_bfloat16 Qs[48][72];
    __shared__ alignas(16) __hip_bfloat16 Vt[64][136];
    __shared__ alignas(16) __hip_bfloat16 Ps[48][136];
    __shared__ float mpart[4][48], lpart[4][48];
    __shared__ float mrow[48];
    int blk = blockIdx.x;
    int bh = blk / NCH_, ch = blk % NCH_;
    int b = bh >> 4, h = bh & 15;
    int c0 = ch * CH_;
    int tid = threadIdx.x, lane = tid & 63, w = tid >> 6;
    int ml = lane & 15, kq = lane >> 4;

    {
        int u = tid >> 2, dq = (tid & 3) * 16;
        if (u < 48) {
            const float* src = qsel + ((size_t)bh * 48 + u) * 64 + dq;
#pragma unroll
            for (int j = 0; j < 16; j += 4) {
                float4 v4 = *(const float4*)(src + j);
                Qs[u][dq + j + 0] = __float2bfloat16(v4.x);
                Qs[u][dq + j + 1] = __float2bfloat16(v4.y);
                Qs[u][dq + j + 2] = __float2bfloat16(v4.z);
                Qs[u][dq + j + 3] = __float2bfloat16(v4.w);
            }
        }
    }
    {
        int klocal = tid >> 1, dq = (tid & 1) * 32;
        const float* vr = v + (size_t)(b * S_ + c0 + klocal) * DM_ + h * DK_ + dq;
#pragma unroll
        for (int jj = 0; jj < 32; jj += 4) {
            float4 v4 = *(const float4*)(vr + jj);
            Vt[dq + jj + 0][klocal] = __float2bfloat16(v4.x);
            Vt[dq + jj + 1][klocal] = __float2bfloat16(v4.y);
            Vt[dq + jj + 2][klocal] = __float2bfloat16(v4.z);
            Vt[dq + jj + 3][klocal] = __float2bfloat16(v4.w);
        }
    }
    __syncthreads();

    const float* Kb = k + (size_t)b * S_ * DM_ + h * DK_;
    f32x4 sreg[3][2];
#pragma unroll
    for (int i = 0; i < 3; ++i)
#pragma unroll
        for (int j = 0; j < 2; ++j) sreg[i][j] = (f32x4){0.f, 0.f, 0.f, 0.f};
#pragma unroll
    for (int ntl = 0; ntl < 2; ++ntl) {
        int krow = c0 + (w * 2 + ntl) * 16 + ml;
        const float* kr = Kb + (size_t)krow * DM_;
        float4 x0 = *(const float4*)(kr + kq * 8);
        float4 x1 = *(const float4*)(kr + kq * 8 + 4);
        float4 y0 = *(const float4*)(kr + 32 + kq * 8);
        float4 y1 = *(const float4*)(kr + 32 + kq * 8 + 4);
        short8 b0, b1;
        b0[0] = f2bs(x0.x); b0[1] = f2bs(x0.y); b0[2] = f2bs(x0.z); b0[3] = f2bs(x0.w);
        b0[4] = f2bs(x1.x); b0[5] = f2bs(x1.y); b0[6] = f2bs(x1.z); b0[7] = f2bs(x1.w);
        b1[0] = f2bs(y0.x); b1[1] = f2bs(y0.y); b1[2] = f2bs(y0.z); b1[3] = f2bs(y0.w);
        b1[4] = f2bs(y1.x); b1[5] = f2bs(y1.y); b1[6] = f2bs(y1.z); b1[7] = f2bs(y1.w);
#pragma unroll
        for (int mt = 0; mt < 3; ++mt) {
            short8 a0 = *(const short8*)&Qs[mt * 16 + ml][kq * 8];
            short8 a1 = *(const short8*)&Qs[mt * 16 + ml][32 + kq * 8];
            sreg[mt][ntl] = __builtin_amdgcn_mfma_f32_16x16x32_bf16(a0, b0, sreg[mt][ntl], 0, 0, 0);
            sreg[mt][ntl] = __builtin_amdgcn_mfma_f32_16x16x32_bf16(a1, b1, sreg[mt][ntl], 0, 0, 0);
        }
    }

    {
        float vmx[3][4];
#pragma unroll
        for (int mt = 0; mt < 3; ++mt)
#pragma unroll
            for (int r = 0; r < 4; ++r)
                vmx[mt][r] = fmaxf(sreg[mt][0][r], sreg[mt][1][r]);
#pragma unroll
        for (int mask = 1; mask <= 8; mask <<= 1)
#pragma unroll
            for (int mt = 0; mt < 3; ++mt)
#pragma unroll
                for (int r = 0; r < 4; ++r)
                    vmx[mt][r] = fmaxf(vmx[mt][r], __shfl_xor(vmx[mt][r], mask, 64));
        if (ml == 0)
#pragma unroll
            for (int mt = 0; mt < 3; ++mt)
#pragma unroll
                for (int r = 0; r < 4; ++r)
                    mpart[w][mt * 16 + kq * 4 + r] = vmx[mt][r];
    }
    __syncthreads();
    if (tid < 48)
        mrow[tid] = fmaxf(fmaxf(mpart[0][tid], mpart[1][tid]),
                          fmaxf(mpart[2][tid], mpart[3][tid]));
    __syncthreads();

    {
        float vsum[3][4] = {{0.f}};
#pragma unroll
        for (int mt = 0; mt < 3; ++mt)
#pragma unroll
            for (int ntl = 0; ntl < 2; ++ntl) {
                int col = (w * 2 + ntl) * 16 + ml;
#pragma unroll
                for (int r = 0; r < 4; ++r) {
                    int row = mt * 16 + kq * 4 + r;
                    float p = __expf(sreg[mt][ntl][r] - mrow[row]);
                    Ps[row][col] = __float2bfloat16(p);
                    vsum[mt][r] += p;
                }
            }
#pragma unroll
        for (int mask = 1; mask <= 8; mask <<= 1)
#pragma unroll
            for (int mt = 0; mt < 3; ++mt)
#pragma unroll
                for (int r = 0; r < 4; ++r)
                    vsum[mt][r] += __shfl_xor(vsum[mt][r], mask, 64);
        if (ml == 0)
#pragma unroll
            for (int mt = 0; mt < 3; ++mt)
#pragma unroll
                for (int r = 0; r < 4; ++r)
                    lpart[w][mt * 16 + kq * 4 + r] = vsum[mt][r];
    }
    __syncthreads();

    f32x4 oreg[3];
#pragma unroll
    for (int i = 0; i < 3; ++i) oreg[i] = (f32x4){0.f, 0.f, 0.f, 0.f};
#pragma unroll
    for (int kt = 0; kt < 4; ++kt) {
        short8 bfq = *(const short8*)&Vt[w * 16 + ml][kt * 32 + kq * 8];
#pragma unroll
        for (int mt = 0; mt < 3; ++mt) {
            short8 af = *(const short8*)&Ps[mt * 16 + ml][kt * 32 + kq * 8];
            oreg[mt] = __builtin_amdgcn_mfma_f32_16x16x32_bf16(af, bfq, oreg[mt], 0, 0, 0);
        }
    }
#pragma unroll
    for (int mt = 0; mt < 3; ++mt)
#pragma unroll
        for (int r = 0; r < 4; ++r) {
            int row = mt * 16 + kq * 4 + r;
            Opart[((size_t)blk * 48 + row) * 64 + w * 16 + ml] = oreg[mt][r];
        }
    if (tid < 48) {
        Mpart[(size_t)blk * 48 + tid] = mrow[tid];
        Lpart[(size_t)blk * 48 + tid] =
            lpart[0][tid] + lpart[1][tid] + lpart[2][tid] + lpart[3][tid];
    }
}

__global__ void attn_combine(const float* __restrict__ Opart, const float* __restrict__ Mpart,
                             const float* __restrict__ Lpart, float* __restrict__ upd) {
    __shared__ float wfac[NCH_][48];
    __shared__ float lfin[48];
    int bh = blockIdx.x, tid = threadIdx.x;
    if (tid < 48) {
        float m = -1e30f;
        for (int c = 0; c < NCH_; ++c)
            m = fmaxf(m, Mpart[(size_t)(bh * NCH_ + c) * 48 + tid]);
        float l = 0.f;
        for (int c = 0; c < NCH_; ++c) {
            float wf = __expf(Mpart[(size_t)(bh * NCH_ + c) * 48 + tid] - m);
            wfac[c][tid] = wf;
            l += wf * Lpart[(size_t)(bh * NCH_ + c) * 48 + tid];
        }
        lfin[tid] = l;
    }
    __syncthreads();
    for (int e = tid; e < U_ * DK_; e += 256) {
        int row = e >> 6, col = e & 63;
        float o = 0.f;
        for (int c = 0; c < NCH_; ++c)
            o += wfac[c][row] * Opart[((size_t)(bh * NCH_ + c) * 48 + row) * 64 + col];
        upd[((size_t)bh * U_ + row) * DK_ + col] = o / lfin[row];
    }
}

__global__ void ctx_fill2(const float* __restrict__ vm, const float* __restrict__ upd,
                          const int* __restrict__ rowmap, float* __restrict__ ctx) {
    size_t i = ((size_t)blockIdx.x * 256 + threadIdx.x) * 4;
    int c = (int)(i & (DM_ - 1));
    size_t bl = i >> 10;
    int l = (int)(bl & (S_ - 1));
    int b = (int)(bl >> 11);
    int h = c >> 6, d = c & (DK_ - 1);
    int bh = b * H_ + h;
    int u = rowmap[(size_t)bh * S_ + l];
    float4 val;
    if (u >= 0)
        val = *(const float4*)(upd + ((size_t)bh * U_ + u) * DK_ + d);
    else
        val = *(const float4*)(vm + bh * DK_ + d);
    *(float4*)(ctx + i) = val;
}

// bias + residual + LayerNorm. Wave shfl reduce + 2 barriers, float4 I/O.
__global__ void ln_kernel(const float* __restrict__ fcout, const float* __restrict__ fcb,
                          const float* __restrict__ resid,
                          const float* __restrict__ lnw, const float* __restrict__ lnb,
                          float* __restrict__ out) {
    __shared__ float sred[8];
    int row = blockIdx.x, tid = threadIdx.x, lane = tid & 63, w = tid >> 6;
    size_t base = (size_t)row * DM_ + tid * 4;
    float4 f = *(const float4*)(fcout + base);
    float4 bb = *(const float4*)(fcb + tid * 4);
    float4 rs = *(const float4*)(resid + base);
    float x[4] = {f.x + bb.x + rs.x, f.y + bb.y + rs.y,
                  f.z + bb.z + rs.z, f.w + bb.w + rs.w};
    float s = x[0] + x[1] + x[2] + x[3];
#pragma unroll
    for (int off = 1; off < 64; off <<= 1) s += __shfl_xor(s, off, 64);
    if (lane == 0) sred[w] = s;
    __syncthreads();
    float mu = (sred[0] + sred[1] + sred[2] + sred[3]) * (1.f / (float)DM_);
    float vs = 0.f;
#pragma unroll
    for (int j = 0; j < 4; ++j) { float d = x[j] - mu; vs += d * d; }
#pragma unroll
    for (int off = 1; off < 64; off <<= 1) vs += __shfl_xor(vs, off, 64);
    if (lane == 0) sred[4 + w] = vs;
    __syncthreads();
    float rstd = rsqrtf((sred[4] + sred[5] + sred[6] + sred[7]) * (1.f / (float)DM_) + 1e-6f);
    float4 wv = *(const float4*)(lnw + tid * 4);
    float4 bv = *(const float4*)(lnb + tid * 4);
    float4 o;
    o.x = (x[0] - mu) * rstd * wv.x + bv.x;
    o.y = (x[1] - mu) * rstd * wv.y + bv.y;
    o.z = (x[2] - mu) * rstd * wv.z + bv.z;
    o.w = (x[3] - mu) * rstd * wv.w + bv.w;
    *(float4*)(out + base) = o;
}

// ================= launch =================

extern "C" void kernel_launch(void* const* d_in, const int* in_sizes, int n_in,
                              void* d_out, int out_size, void* d_ws, size_t ws_size,
                              hipStream_t stream) {
    if (n_in < 9 || d_ws == nullptr || d_out == nullptr) return;

    const float* hs  = (const float*)d_in[0];
    const float* wq  = (const float*)d_in[1];
    const float* wk  = (const float*)d_in[2];
    const float* wv  = (const float*)d_in[3];
    const float* fcw = (const float*)d_in[4];
    const float* fcb = (const float*)d_in[5];
    const float* lnw = (const float*)d_in[6];
    const float* lnb = (const float*)d_in[7];
    const int* idxs  = (const int*)d_in[8];

    const size_t MD = (size_t)B_ * S_ * DM_;  // 4194304
    const int M = B_ * S_;                    // 4096
    float* out = (float*)d_out;
    char* base = (char*)d_ws;

    if (ws_size >= 66ull * 1024 * 1024) {
        // ---- NEW PATH
        float* q   = (float*)base;                       // 16 MB [later ctx]
        float* k   = (float*)(base + (16ull << 20));     // 16 MB [later fcout]
        u16* Ahi   = (u16*)(base + (32ull << 20));       // 8 MB [later Opart]
        u16* Alo   = (u16*)(base + (40ull << 20));       // 8 MB
        u16* Wqh   = (u16*)(base + (48ull << 20));       // 6 x 2 MB
        u16* Wql   = Wqh + (1u << 20);
        u16* Wkh   = Wql + (1u << 20);
        u16* Wkl   = Wkh + (1u << 20);
        u16* Wvh   = Wkl + (1u << 20);
        u16* Fct   = Wvh + (1u << 20);
        float* mbuf  = (float*)(base + (60ull << 20));         // B*H*S = 65536 f
        float* vmean = mbuf + (size_t)B_ * H_ * S_;            // 2048 f (raw sum)
        int* mtop    = (int*)(vmean + B_ * H_ * DK_);          // 1280 i
        int* rowmap  = (int*)(mtop + B_ * H_ * U_);            // 65536 i
        float* v = out;
        // Opart over Ahi/Alo (dead after gemm_qkv_v7); q stays live for attn gather
        float* Opart = (float*)(base + (32ull << 20));
        float* Mpart = Opart + (size_t)512 * 48 * 64;
        float* Lpart = Mpart + (size_t)512 * 48;
        u16* ctxb = (u16*)q;     // after attn (q dead post-attn_chunk2)
        float* fcout = k;        // after k dead (post-attn_chunk2)

        conv_all<<<3073, 256, 0, stream>>>(hs, wq, wk, wv, fcw, Ahi, Alo,
                                           Wqh, Wql, Wkh, Wkl, Wvh, Fct, vmean);
        gemm_qkv_v7<<<768, 256, 0, stream>>>(Ahi, Alo, Wqh, Wql, Wkh, Wkl, Wvh,
                                             q, k, v, vmean);

        m_score_v3<<<(B_ * H_ * S_) / 4, 256, 0, stream>>>(q, k, idxs, mbuf, rowmap);
        topk_wave<<<B_ * H_, 64, 0, stream>>>(mbuf, mtop, rowmap);

        attn_chunk2<<<B_ * H_ * NCH_, 256, 0, stream>>>(q, mtop, k, v, Opart, Mpart, Lpart);

        ctx_fill4<<<(int)(MD / 1024), 256, 0, stream>>>(vmean, Opart, Mpart, Lpart, rowmap, ctxb);

        gemm_fc_v8<<<256, 256, 0, stream>>>(ctxb, Fct, fcout);
        ln_kernel<<<M, 256, 0, stream>>>(fcout, fcb, hs, lnw, lnb, out);
        return;
    }

    // ---- OLD PATH (fallback, needs >= 34 MB)
    if (ws_size < 34ull * 1024 * 1024) return;
    float* ws = (float*)d_ws;
    float* q = ws;
    float* k = ws + MD;
    float* mbuf = ws + 2 * MD;
    float* vmean = mbuf + (size_t)B_ * H_ * S_;
    float* upd = vmean + B_ * H_ * DK_;
    int* mtop = (int*)(upd + (size_t)B_ * H_ * U_ * DK_);
    float* qsel = (float*)(mtop + B_ * H_ * U_);
    float* vpart = qsel + (size_t)B_ * H_ * 48 * 64;
    int* rowmap = (int*)(vpart + (size_t)B_ * H_ * VCH_ * DK_);
    float* v = out;
    float* Opart = q;
    float* Mpart = Opart + (size_t)512 * 48 * 64;
    float* Lpart = Mpart + (size_t)512 * 48;
    float* ctx = q;
    float* fcout = k;

    gemm_qkv<<<1536, 256, 0, stream>>>(hs, wq, wk, wv, q, k, v);

    m_score_v3<<<(B_ * H_ * S_) / 4, 256, 0, stream>>>(q, k, idxs, mbuf, rowmap);
    topk_wave<<<B_ * H_, 64, 0, stream>>>(mbuf, mtop, rowmap);
    vmean_part<<<B_ * H_ * VCH_, 256, 0, stream>>>(v, vpart);
    vmean_comb<<<B_ * H_, 64, 0, stream>>>(vpart, vmean);
    gather_qsel<<<B_ * H_, 256, 0, stream>>>(q, mtop, qsel);

    attn_chunk<<<B_ * H_ * NCH_, 256, 0, stream>>>(qsel, k, v, Opart, Mpart, Lpart);
    attn_combine<<<B_ * H_, 256, 0, stream>>>(Opart, Mpart, Lpart, upd);

    ctx_fill2<<<(int)(MD / 1024), 256, 0, stream>>>(vmean, upd, rowmap, ctx);

    mfma_gemm_v2<<<512, 256, 0, stream>>>(ctx, fcw, fcout, M, DM_, DM_, 1.0f);
    ln_kernel<<<M, 256, 0, stream>>>(fcout, fcb, hs, lnw, lnb, out);
}

// Round 9
// 282.870 us; speedup vs baseline: 1.1625x; 1.0046x over previous
//
#include <hip/hip_runtime.h>
#include <hip/hip_bf16.h>

#define B_  2
#define S_  2048
#define DM_ 1024
#define H_  16
#define DK_ 64
#define SK_ 40   // SAMPLE_K
#define U_  40   // top-k u
#define CH_ 128  // attn chunk columns
#define NCH_ (S_ / CH_)  // 16
#define VCH_ 64  // vmean chunks per (b,h)

typedef __attribute__((ext_vector_type(8))) short short8;
typedef __attribute__((ext_vector_type(4))) short short4v;
typedef __attribute__((ext_vector_type(4))) float f32x4;
typedef unsigned short u16;

union BF16S { __hip_bfloat16 h; short s; };
static __device__ __forceinline__ short f2bs(float x) {
    BF16S u; u.h = __float2bfloat16(x); return u.s;
}
static __device__ __forceinline__ void fsplit(float x, short& h, short& l) {
    BF16S u; u.h = __float2bfloat16(x);
    h = u.s;
    BF16S v; v.h = __float2bfloat16(x - __bfloat162float(u.h));
    l = v.s;
}

// async global->LDS, 16 bytes per lane. LDS dest must be wave-uniform base + lane*16.
static __device__ __forceinline__ void gload16(const void* g, void* s) {
    __builtin_amdgcn_global_load_lds(
        (const __attribute__((address_space(1))) void*)g,
        (__attribute__((address_space(3))) void*)s, 16, 0, 0);
}

// LDS bank swizzle (involution): flip byte bits [6:4] with bits [9:7] (row bits 1..3).
static __device__ __forceinline__ int swzb(int b) {
    return b ^ (((b >> 7) & 7) << 4);
}

// =====================================================================
// NEW PATH kernels
// =====================================================================

// One-dispatch prep: [0,2048) hs->hi/lo planes, [2048,3072) weight transpose+cvt,
// [3072] zero the vmean accumulator.
__global__ __launch_bounds__(256) void conv_all(
    const float* __restrict__ hs,
    const float* __restrict__ wq, const float* __restrict__ wk,
    const float* __restrict__ wv, const float* __restrict__ fcw,
    u16* __restrict__ Ahi, u16* __restrict__ Alo,
    u16* __restrict__ qh, u16* __restrict__ ql,
    u16* __restrict__ kh, u16* __restrict__ kl,
    u16* __restrict__ vh, u16* __restrict__ fh,
    float* __restrict__ vmean_acc) {
    __shared__ float T[64][65];
    int bid = blockIdx.x, tid = threadIdx.x;
    if (bid < 2048) {
        size_t i = ((size_t)bid * 256 + tid) * 8;
        float a[8];
        *(float4*)&a[0] = *(const float4*)(hs + i);
        *(float4*)&a[4] = *(const float4*)(hs + i + 4);
        short8 h, l;
#pragma unroll
        for (int e = 0; e < 8; ++e) {
            short hh, ll;
            fsplit(a[e], hh, ll);
            h[e] = hh; l[e] = ll;
        }
        *(short8*)&Ahi[i] = h;
        *(short8*)&Alo[i] = l;
        return;
    }
    if (bid >= 3072) {
        for (int j = tid; j < B_ * H_ * DK_; j += 256) vmean_acc[j] = 0.f;
        return;
    }
    int mode = (bid - 2048) >> 8;
    int tb = (bid - 2048) & 255;
    int ty = tb >> 4, tx = tb & 15;
    const float* src = (mode == 0) ? wq : (mode == 1) ? wk : (mode == 2) ? wv : fcw;
    u16* dh = (mode == 0) ? qh : (mode == 1) ? kh : (mode == 2) ? vh : fh;
    u16* dl = (mode == 0) ? ql : kl;
    bool split = (mode < 2);
    int r = tid >> 2, cq = (tid & 3) * 16;

    const float* sp = src + (size_t)(ty * 64 + r) * 1024 + tx * 64 + cq;
#pragma unroll
    for (int j = 0; j < 16; j += 4) *(float4*)&T[r][cq + j] = *(const float4*)(sp + j);
    __syncthreads();

    short8 h0, h1, l0, l1;
#pragma unroll
    for (int j = 0; j < 8; ++j) {
        short hh, ll;
        fsplit(T[cq + j][r], hh, ll);
        h0[j] = hh; l0[j] = ll;
        fsplit(T[cq + 8 + j][r], hh, ll);
        h1[j] = hh; l1[j] = ll;
    }
    size_t off = (size_t)(tx * 64 + r) * 1024 + ty * 64 + cq;
    *(short8*)&dh[off] = h0;
    *(short8*)&dh[off + 8] = h1;
    if (split) {
        *(short8*)&dl[off] = l0;
        *(short8*)&dl[off + 8] = l1;
    }
}

// fused q/k/v projection. 2-deep counted-vmcnt pipeline, MFMA-before-bar2,
// swizzled LDS, mode-striped XCD chunking. Epilogue: q fp32; k fp32 + kb16
// (bit-identical to consumers' f2bs of the stored fp32); v as vb16 ONLY
// (only attn consumes v, and it converts to bf16 anyway); vmean column sums.
__global__ __launch_bounds__(256) void gemm_qkv_v9(
    const u16* __restrict__ Ahi, const u16* __restrict__ Alo,
    const u16* __restrict__ Wqh, const u16* __restrict__ Wql,
    const u16* __restrict__ Wkh, const u16* __restrict__ Wkl,
    const u16* __restrict__ Wvh,
    float* __restrict__ q, float* __restrict__ k,
    u16* __restrict__ kb16, u16* __restrict__ vb16,
    float* __restrict__ vmean_acc) {
    __shared__ alignas(16) u16 lds[2][4][128 * 32];  // 64 KB
    int bid = (int)blockIdx.x;
    int xcd = bid & 7, ii = bid >> 3;          // ii in 0..95
    int mode = ii >> 5;                        // 0..2 (q,k,v)
    int rr = xcd * 32 + (ii & 31);             // tile within mode, 0..255
    int by = rr >> 3, bx = rr & 7;
    const u16* Bh = (mode == 0) ? Wqh : (mode == 1) ? Wkh : Wvh;
    const u16* Bl = (mode == 0) ? Wql : Wkl;  // unused for v
    float scale = (mode == 0) ? 0.125f : 1.0f;
    bool split = (mode < 2);

    int tid = threadIdx.x, lane = tid & 63, w = tid >> 6;
    int wr = w >> 1, wc = w & 1;
    int ml = lane & 15, kq = lane >> 4;

    f32x4 acc[4][4];
#pragma unroll
    for (int i = 0; i < 4; ++i)
#pragma unroll
        for (int j = 0; j < 4; ++j) acc[i][j] = (f32x4){0.f, 0.f, 0.f, 0.f};

    const u16* Agh = Ahi + (size_t)(by * 128) * 1024;
    const u16* Agl = Alo + (size_t)(by * 128) * 1024;
    const u16* Bgh = Bh + (size_t)(bx * 128) * 1024;
    const u16* Bgl = Bl + (size_t)(bx * 128) * 1024;

    int pl0 = tid * 16, pl1 = 4096 + tid * 16;
    int d0 = swzb(pl0), d1 = swzb(pl1);
    int gs0 = (d0 >> 6) * 1024 + ((d0 & 63) >> 1);
    int gs1 = (d1 >> 6) * 1024 + ((d1 & 63) >> 1);
    int ld0 = tid * 8, ld1 = 2048 + tid * 8;

    int offA[4], offB[4];
#pragma unroll
    for (int mt = 0; mt < 4; ++mt) {
        int d = (wr * 64 + mt * 16 + ml) * 64 + kq * 16;
        offA[mt] = swzb(d);
    }
#pragma unroll
    for (int nt = 0; nt < 4; ++nt) {
        int d = (wc * 64 + nt * 16 + ml) * 64 + kq * 16;
        offB[nt] = swzb(d);
    }

    auto STAGE = [&](int bf, int k0) {
        gload16(Agh + gs0 + k0, &lds[bf][0][ld0]);
        gload16(Agh + gs1 + k0, &lds[bf][0][ld1]);
        gload16(Bgh + gs0 + k0, &lds[bf][2][ld0]);
        gload16(Bgh + gs1 + k0, &lds[bf][2][ld1]);
        if (split) {
            gload16(Agl + gs0 + k0, &lds[bf][1][ld0]);
            gload16(Agl + gs1 + k0, &lds[bf][1][ld1]);
            gload16(Bgl + gs0 + k0, &lds[bf][3][ld0]);
            gload16(Bgl + gs1 + k0, &lds[bf][3][ld1]);
        }
    };

    STAGE(0, 0);
    STAGE(1, 32);
    int cur = 0;
    for (int t = 0; t < 32; ++t) {
        if (t == 31)      asm volatile("s_waitcnt vmcnt(0)" ::: "memory");
        else if (split)   asm volatile("s_waitcnt vmcnt(8)" ::: "memory");
        else              asm volatile("s_waitcnt vmcnt(4)" ::: "memory");
        __builtin_amdgcn_s_barrier();           // tile t visible to all waves
        __builtin_amdgcn_sched_barrier(0);

        const char* Ah_ = (const char*)lds[cur][0];
        const char* Al_ = (const char*)lds[cur][1];
        const char* Bh_ = (const char*)lds[cur][2];
        const char* Bl_ = (const char*)lds[cur][3];
        short8 a_h[4], b_h[4], a_l[4], b_l[4];
#pragma unroll
        for (int mt = 0; mt < 4; ++mt) a_h[mt] = *(const short8*)(Ah_ + offA[mt]);
#pragma unroll
        for (int nt = 0; nt < 4; ++nt) b_h[nt] = *(const short8*)(Bh_ + offB[nt]);
        if (split) {
#pragma unroll
            for (int mt = 0; mt < 4; ++mt) a_l[mt] = *(const short8*)(Al_ + offA[mt]);
#pragma unroll
            for (int nt = 0; nt < 4; ++nt) b_l[nt] = *(const short8*)(Bl_ + offB[nt]);
        }

        __builtin_amdgcn_s_setprio(1);
#pragma unroll
        for (int mt = 0; mt < 4; ++mt)
#pragma unroll
            for (int nt = 0; nt < 4; ++nt)
                acc[mt][nt] = __builtin_amdgcn_mfma_f32_16x16x32_bf16(a_h[mt], b_h[nt], acc[mt][nt], 0, 0, 0);
        if (split) {
#pragma unroll
            for (int mt = 0; mt < 4; ++mt)
#pragma unroll
                for (int nt = 0; nt < 4; ++nt) {
                    acc[mt][nt] = __builtin_amdgcn_mfma_f32_16x16x32_bf16(a_h[mt], b_l[nt], acc[mt][nt], 0, 0, 0);
                    acc[mt][nt] = __builtin_amdgcn_mfma_f32_16x16x32_bf16(a_l[mt], b_h[nt], acc[mt][nt], 0, 0, 0);
                }
        }
        __builtin_amdgcn_s_setprio(0);

        if (t < 31) {
            __builtin_amdgcn_s_barrier();       // all waves consumed buf[cur]
            __builtin_amdgcn_sched_barrier(0);
            if (t < 30) STAGE(cur, (t + 2) * 32);
        }
        cur ^= 1;
    }
#pragma unroll
    for (int mt = 0; mt < 4; ++mt)
#pragma unroll
        for (int nt = 0; nt < 4; ++nt)
#pragma unroll
            for (int r2 = 0; r2 < 4; ++r2) {
                int row = by * 128 + wr * 64 + mt * 16 + kq * 4 + r2;
                int col = bx * 128 + wc * 64 + nt * 16 + ml;
                size_t idx = (size_t)row * 1024 + col;
                float val = acc[mt][nt][r2] * scale;
                if (mode == 0) {
                    q[idx] = val;
                } else if (mode == 1) {
                    k[idx] = val;
                    kb16[idx] = (u16)f2bs(val);
                } else {
                    vb16[idx] = (u16)f2bs(val);
                }
            }
    if (mode == 2) {
        int b = by >> 4;
#pragma unroll
        for (int nt = 0; nt < 4; ++nt) {
            float s = 0.f;
#pragma unroll
            for (int mt = 0; mt < 4; ++mt)
#pragma unroll
                for (int r2 = 0; r2 < 4; ++r2) s += acc[mt][nt][r2];
            s += __shfl_xor(s, 16, 64);
            s += __shfl_xor(s, 32, 64);
            if (kq == 0) {
                int col = bx * 128 + wc * 64 + nt * 16 + ml;
                int h = col >> 6, d = col & 63;
                atomicAdd(&vmean_acc[(b * H_ + h) * DK_ + d], s);
            }
        }
    }
}

// m-score v3 + rowmap init (high-TLP config: 4 waves/block, 16384 blocks).
__global__ void m_score_v3(const float* __restrict__ q, const float* __restrict__ k,
                           const int* __restrict__ idxs, float* __restrict__ m_out,
                           int* __restrict__ rowmap) {
    int gwave = blockIdx.x * 4 + (threadIdx.x >> 6);
    int lane = threadIdx.x & 63;
    if (gwave >= B_ * H_ * S_) return;
    int l = gwave % S_;
    int bh = gwave / S_;
    int h = bh & 15, b = bh >> 4;
    int sl = lane >> 3;
    int dc = lane & 7;

    const float* qr = q + ((size_t)(b * S_ + l)) * DM_ + h * DK_ + dc * 8;
    float4 q0 = *(const float4*)qr;
    float4 q1 = *(const float4*)(qr + 4);
    const float* kb = k + (size_t)b * S_ * DM_ + h * DK_ + dc * 8;

    float mx = -INFINITY, sm = 0.f;
#pragma unroll
    for (int c = 0; c < 5; ++c) {
        int s = c * 8 + sl;
        int idx = idxs[l * SK_ + s];
        idx = (idx < 0) ? 0 : (idx >= S_ ? S_ - 1 : idx);
        const float* kr = kb + (size_t)idx * DM_;
        float4 k0 = *(const float4*)kr;
        float4 k1 = *(const float4*)(kr + 4);
        float d = q0.x * k0.x + q0.y * k0.y + q0.z * k0.z + q0.w * k0.w +
                  q1.x * k1.x + q1.y * k1.y + q1.z * k1.z + q1.w * k1.w;
        d += __shfl_xor(d, 1, 64);
        d += __shfl_xor(d, 2, 64);
        d += __shfl_xor(d, 4, 64);
        mx = fmaxf(mx, d);
        sm += d;
    }
#pragma unroll
    for (int off = 8; off <= 32; off <<= 1) {
        mx = fmaxf(mx, __shfl_xor(mx, off, 64));
        sm += __shfl_xor(sm, off, 64);
    }
    if (lane == 0) {
        m_out[(size_t)bh * S_ + l] = mx - sm * (1.f / (float)S_);
        rowmap[(size_t)bh * S_ + l] = -1;
    }
}

// top-40, single wave per (b,h), register-resident, barrier-free.
__global__ void topk_wave(const float* __restrict__ m, int* __restrict__ mtop,
                          int* __restrict__ rowmap) {
    int bh = blockIdx.x;
    int lane = threadIdx.x;
    const float* mb = m + (size_t)bh * S_;
    float vals[32];
#pragma unroll
    for (int j = 0; j < 32; ++j) vals[j] = mb[j * 64 + lane];
    float lmax = -INFINITY;
    int lj = 0;
#pragma unroll
    for (int j = 0; j < 32; ++j)
        if (vals[j] > lmax) { lmax = vals[j]; lj = j; }

    for (int it = 0; it < U_; ++it) {
        float wv = lmax;
        int wi = lj * 64 + lane;
#pragma unroll
        for (int off = 1; off < 64; off <<= 1) {
            float ov = __shfl_xor(wv, off, 64);
            int oi = __shfl_xor(wi, off, 64);
            if (ov > wv || (ov == wv && oi < wi)) { wv = ov; wi = oi; }
        }
        if (lane == 0) {
            mtop[bh * U_ + it] = wi;
            rowmap[(size_t)bh * S_ + wi] = it;
        }
        if ((wi & 63) == lane) {
            int jw = wi >> 6;
#pragma unroll
            for (int t = 0; t < 32; ++t)
                if (t == jw) vals[t] = -INFINITY;
            lmax = -INFINITY;
            lj = 0;
#pragma unroll
            for (int t = 0; t < 32; ++t)
                if (vals[t] > lmax) { lmax = vals[t]; lj = t; }
        }
    }
}

// ctx one-pass with INLINE chunk-combine for selected rows (attn_combine fused).
__global__ void ctx_fill4(const float* __restrict__ vm,
                          const float* __restrict__ Opart,
                          const float* __restrict__ Mpart,
                          const float* __restrict__ Lpart,
                          const int* __restrict__ rowmap, u16* __restrict__ ctx) {
    size_t i = ((size_t)blockIdx.x * 256 + threadIdx.x) * 4;  // over B*S*DM
    int c = (int)(i & (DM_ - 1));
    size_t bl = i >> 10;
    int l = (int)(bl & (S_ - 1));
    int b = (int)(bl >> 11);
    int h = c >> 6, d = c & (DK_ - 1);
    int bh = b * H_ + h;
    int u = rowmap[(size_t)bh * S_ + l];
    float4 val;
    if (u >= 0) {
        float m = -1e30f;
#pragma unroll
        for (int c2 = 0; c2 < NCH_; ++c2)
            m = fmaxf(m, Mpart[(size_t)(bh * NCH_ + c2) * 48 + u]);
        float lf = 0.f;
        float o0 = 0.f, o1 = 0.f, o2 = 0.f, o3 = 0.f;
#pragma unroll
        for (int c2 = 0; c2 < NCH_; ++c2) {
            float wf = __expf(Mpart[(size_t)(bh * NCH_ + c2) * 48 + u] - m);
            lf += wf * Lpart[(size_t)(bh * NCH_ + c2) * 48 + u];
            const float* op = Opart + ((size_t)(bh * NCH_ + c2) * 48 + u) * 64 + d;
            o0 += wf * op[0];
            o1 += wf * op[1];
            o2 += wf * op[2];
            o3 += wf * op[3];
        }
        val.x = o0 / lf; val.y = o1 / lf; val.z = o2 / lf; val.w = o3 / lf;
    } else {
        val = *(const float4*)(vm + bh * DK_ + d);
        const float is = 1.f / (float)S_;
        val.x *= is; val.y *= is; val.z *= is; val.w *= is;
    }
    short4v o;
    o[0] = f2bs(val.x); o[1] = f2bs(val.y); o[2] = f2bs(val.z); o[3] = f2bs(val.w);
    *(short4v*)&ctx[i] = o;
}

// fc GEMM v8: ctx(bf16) @ FcT(bf16)^T -> fp32. 128x128 tile, BK=32, 2-deep
// counted-vmcnt pipeline, swizzled LDS, XCD-chunked (256 blocks).
__global__ __launch_bounds__(256) void gemm_fc_v8(const u16* __restrict__ A,
                                                  const u16* __restrict__ Bt,
                                                  float* __restrict__ C) {
    __shared__ alignas(16) u16 lds[2][2][128 * 32];  // 32 KB
    int bid = (int)blockIdx.x;
    int xcd = bid & 7, ii = bid >> 3;          // 0..31
    int rr = xcd * 32 + ii;                    // 0..255
    int by = rr >> 3, bx = rr & 7;

    int tid = threadIdx.x, lane = tid & 63, w = tid >> 6;
    int wr = w >> 1, wc = w & 1;
    int ml = lane & 15, kq = lane >> 4;

    f32x4 acc[4][4];
#pragma unroll
    for (int i = 0; i < 4; ++i)
#pragma unroll
        for (int j = 0; j < 4; ++j) acc[i][j] = (f32x4){0.f, 0.f, 0.f, 0.f};

    const u16* Agh = A + (size_t)(by * 128) * 1024;
    const u16* Bgh = Bt + (size_t)(bx * 128) * 1024;

    int pl0 = tid * 16, pl1 = 4096 + tid * 16;
    int d0 = swzb(pl0), d1 = swzb(pl1);
    int gs0 = (d0 >> 6) * 1024 + ((d0 & 63) >> 1);
    int gs1 = (d1 >> 6) * 1024 + ((d1 & 63) >> 1);
    int ld0 = tid * 8, ld1 = 2048 + tid * 8;

    int offA[4], offB[4];
#pragma unroll
    for (int mt = 0; mt < 4; ++mt) {
        int d = (wr * 64 + mt * 16 + ml) * 64 + kq * 16;
        offA[mt] = swzb(d);
    }
#pragma unroll
    for (int nt = 0; nt < 4; ++nt) {
        int d = (wc * 64 + nt * 16 + ml) * 64 + kq * 16;
        offB[nt] = swzb(d);
    }

    auto STAGE = [&](int bf, int k0) {
        gload16(Agh + gs0 + k0, &lds[bf][0][ld0]);
        gload16(Agh + gs1 + k0, &lds[bf][0][ld1]);
        gload16(Bgh + gs0 + k0, &lds[bf][1][ld0]);
        gload16(Bgh + gs1 + k0, &lds[bf][1][ld1]);
    };

    STAGE(0, 0);
    STAGE(1, 32);
    int cur = 0;
    for (int t = 0; t < 32; ++t) {
        if (t == 31) asm volatile("s_waitcnt vmcnt(0)" ::: "memory");
        else         asm volatile("s_waitcnt vmcnt(4)" ::: "memory");
        __builtin_amdgcn_s_barrier();
        __builtin_amdgcn_sched_barrier(0);

        const char* Ah_ = (const char*)lds[cur][0];
        const char* Bh_ = (const char*)lds[cur][1];
        short8 a_h[4], b_h[4];
#pragma unroll
        for (int mt = 0; mt < 4; ++mt) a_h[mt] = *(const short8*)(Ah_ + offA[mt]);
#pragma unroll
        for (int nt = 0; nt < 4; ++nt) b_h[nt] = *(const short8*)(Bh_ + offB[nt]);

        __builtin_amdgcn_s_setprio(1);
#pragma unroll
        for (int mt = 0; mt < 4; ++mt)
#pragma unroll
            for (int nt = 0; nt < 4; ++nt)
                acc[mt][nt] = __builtin_amdgcn_mfma_f32_16x16x32_bf16(a_h[mt], b_h[nt], acc[mt][nt], 0, 0, 0);
        __builtin_amdgcn_s_setprio(0);

        if (t < 31) {
            __builtin_amdgcn_s_barrier();
            __builtin_amdgcn_sched_barrier(0);
            if (t < 30) STAGE(cur, (t + 2) * 32);
        }
        cur ^= 1;
    }
#pragma unroll
    for (int mt = 0; mt < 4; ++mt)
#pragma unroll
        for (int nt = 0; nt < 4; ++nt)
#pragma unroll
            for (int r2 = 0; r2 < 4; ++r2) {
                int row = by * 128 + wr * 64 + mt * 16 + kq * 4 + r2;
                int col = bx * 128 + wc * 64 + nt * 16 + ml;
                C[(size_t)row * 1024 + col] = acc[mt][nt][r2];
            }
}

// split-K flash attention: fused Q-gather; K/V read as pre-converted bf16
// (zero VALU conversion, half the bytes). Bit-identical: kb16/vb16 were
// produced by f2bs of the exact fp32 values this kernel used to convert.
__global__ __launch_bounds__(256) void attn_chunk3(const float* __restrict__ q,
                                                   const int* __restrict__ mtop,
                                                   const u16* __restrict__ kb16,
                                                   const u16* __restrict__ vb16,
                                                   float* __restrict__ Opart,
                                                   float* __restrict__ Mpart,
                                                   float* __restrict__ Lpart) {
    __shared__ alignas(16) __hip_bfloat16 Qs[48][72];
    __shared__ alignas(16) __hip_bfloat16 Vt[64][136];
    __shared__ alignas(16) __hip_bfloat16 Ps[48][136];
    __shared__ float mpart[4][48], lpart[4][48];
    __shared__ float mrow[48];
    int blk = blockIdx.x;
    int bh = blk / NCH_, ch = blk % NCH_;
    int b = bh >> 4, h = bh & 15;
    int c0 = ch * CH_;
    int tid = threadIdx.x, lane = tid & 63, w = tid >> 6;
    int ml = lane & 15, kq = lane >> 4;

    {
        int u = tid >> 2, dq = (tid & 3) * 16;
        if (u < U_) {
            int row = mtop[bh * U_ + u];
            row = (row < 0) ? 0 : (row >= S_ ? S_ - 1 : row);
            const float* src = q + ((size_t)(b * S_ + row)) * DM_ + h * DK_ + dq;
#pragma unroll
            for (int j = 0; j < 16; j += 4) {
                float4 v4 = *(const float4*)(src + j);
                Qs[u][dq + j + 0] = __float2bfloat16(v4.x);
                Qs[u][dq + j + 1] = __float2bfloat16(v4.y);
                Qs[u][dq + j + 2] = __float2bfloat16(v4.z);
                Qs[u][dq + j + 3] = __float2bfloat16(v4.w);
            }
        } else if (u < 48) {
#pragma unroll
            for (int j = 0; j < 16; ++j) Qs[u][dq + j] = __float2bfloat16(0.f);
        }
    }
    {
        int klocal = tid >> 1, dq = (tid & 1) * 32;
        const u16* vr = vb16 + (size_t)(b * S_ + c0 + klocal) * DM_ + h * DK_ + dq;
#pragma unroll
        for (int jj = 0; jj < 32; jj += 8) {
            short8 v8 = *(const short8*)(vr + jj);
#pragma unroll
            for (int e = 0; e < 8; ++e)
                *(short*)&Vt[dq + jj + e][klocal] = v8[e];
        }
    }
    __syncthreads();

    const u16* Kb = kb16 + (size_t)b * S_ * DM_ + h * DK_;
    f32x4 sreg[3][2];
#pragma unroll
    for (int i = 0; i < 3; ++i)
#pragma unroll
        for (int j = 0; j < 2; ++j) sreg[i][j] = (f32x4){0.f, 0.f, 0.f, 0.f};
#pragma unroll
    for (int ntl = 0; ntl < 2; ++ntl) {
        int krow = c0 + (w * 2 + ntl) * 16 + ml;
        const u16* kr = Kb + (size_t)krow * DM_;
        short8 b0 = *(const short8*)(kr + kq * 8);
        short8 b1 = *(const short8*)(kr + 32 + kq * 8);
#pragma unroll
        for (int mt = 0; mt < 3; ++mt) {
            short8 a0 = *(const short8*)&Qs[mt * 16 + ml][kq * 8];
            short8 a1 = *(const short8*)&Qs[mt * 16 + ml][32 + kq * 8];
            sreg[mt][ntl] = __builtin_amdgcn_mfma_f32_16x16x32_bf16(a0, b0, sreg[mt][ntl], 0, 0, 0);
            sreg[mt][ntl] = __builtin_amdgcn_mfma_f32_16x16x32_bf16(a1, b1, sreg[mt][ntl], 0, 0, 0);
        }
    }

    {
        float vmx[3][4];
#pragma unroll
        for (int mt = 0; mt < 3; ++mt)
#pragma unroll
            for (int r = 0; r < 4; ++r)
                vmx[mt][r] = fmaxf(sreg[mt][0][r], sreg[mt][1][r]);
#pragma unroll
        for (int mask = 1; mask <= 8; mask <<= 1)
#pragma unroll
            for (int mt = 0; mt < 3; ++mt)
#pragma unroll
                for (int r = 0; r < 4; ++r)
                    vmx[mt][r] = fmaxf(vmx[mt][r], __shfl_xor(vmx[mt][r], mask, 64));
        if (ml == 0)
#pragma unroll
            for (int mt = 0; mt < 3; ++mt)
#pragma unroll
                for (int r = 0; r < 4; ++r)
                    mpart[w][mt * 16 + kq * 4 + r] = vmx[mt][r];
    }
    __syncthreads();
    if (tid < 48)
        mrow[tid] = fmaxf(fmaxf(mpart[0][tid], mpart[1][tid]),
                          fmaxf(mpart[2][tid], mpart[3][tid]));
    __syncthreads();

    {
        float vsum[3][4] = {{0.f}};
#pragma unroll
        for (int mt = 0; mt < 3; ++mt)
#pragma unroll
            for (int ntl = 0; ntl < 2; ++ntl) {
                int col = (w * 2 + ntl) * 16 + ml;
#pragma unroll
                for (int r = 0; r < 4; ++r) {
                    int row = mt * 16 + kq * 4 + r;
                    float p = __expf(sreg[mt][ntl][r] - mrow[row]);
                    Ps[row][col] = __float2bfloat16(p);
                    vsum[mt][r] += p;
                }
            }
#pragma unroll
        for (int mask = 1; mask <= 8; mask <<= 1)
#pragma unroll
            for (int mt = 0; mt < 3; ++mt)
#pragma unroll
                for (int r = 0; r < 4; ++r)
                    vsum[mt][r] += __shfl_xor(vsum[mt][r], mask, 64);
        if (ml == 0)
#pragma unroll
            for (int mt = 0; mt < 3; ++mt)
#pragma unroll
                for (int r = 0; r < 4; ++r)
                    lpart[w][mt * 16 + kq * 4 + r] = vsum[mt][r];
    }
    __syncthreads();

    f32x4 oreg[3];
#pragma unroll
    for (int i = 0; i < 3; ++i) oreg[i] = (f32x4){0.f, 0.f, 0.f, 0.f};
#pragma unroll
    for (int kt = 0; kt < 4; ++kt) {
        short8 bfq = *(const short8*)&Vt[w * 16 + ml][kt * 32 + kq * 8];
#pragma unroll
        for (int mt = 0; mt < 3; ++mt) {
            short8 af = *(const short8*)&Ps[mt * 16 + ml][kt * 32 + kq * 8];
            oreg[mt] = __builtin_amdgcn_mfma_f32_16x16x32_bf16(af, bfq, oreg[mt], 0, 0, 0);
        }
    }
#pragma unroll
    for (int mt = 0; mt < 3; ++mt)
#pragma unroll
        for (int r = 0; r < 4; ++r) {
            int row = mt * 16 + kq * 4 + r;
            Opart[((size_t)blk * 48 + row) * 64 + w * 16 + ml] = oreg[mt][r];
        }
    if (tid < 48) {
        Mpart[(size_t)blk * 48 + tid] = mrow[tid];
        Lpart[(size_t)blk * 48 + tid] =
            lpart[0][tid] + lpart[1][tid] + lpart[2][tid] + lpart[3][tid];
    }
}

// bias + residual + LayerNorm. Wave shfl reduce + 2 barriers, float4 I/O.
__global__ void ln_kernel(const float* __restrict__ fcout, const float* __restrict__ fcb,
                          const float* __restrict__ resid,
                          const float* __restrict__ lnw, const float* __restrict__ lnb,
                          float* __restrict__ out) {
    __shared__ float sred[8];
    int row = blockIdx.x, tid = threadIdx.x, lane = tid & 63, w = tid >> 6;
    size_t base = (size_t)row * DM_ + tid * 4;
    float4 f = *(const float4*)(fcout + base);
    float4 bb = *(const float4*)(fcb + tid * 4);
    float4 rs = *(const float4*)(resid + base);
    float x[4] = {f.x + bb.x + rs.x, f.y + bb.y + rs.y,
                  f.z + bb.z + rs.z, f.w + bb.w + rs.w};
    float s = x[0] + x[1] + x[2] + x[3];
#pragma unroll
    for (int off = 1; off < 64; off <<= 1) s += __shfl_xor(s, off, 64);
    if (lane == 0) sred[w] = s;
    __syncthreads();
    float mu = (sred[0] + sred[1] + sred[2] + sred[3]) * (1.f / (float)DM_);
    float vs = 0.f;
#pragma unroll
    for (int j = 0; j < 4; ++j) { float d = x[j] - mu; vs += d * d; }
#pragma unroll
    for (int off = 1; off < 64; off <<= 1) vs += __shfl_xor(vs, off, 64);
    if (lane == 0) sred[4 + w] = vs;
    __syncthreads();
    float rstd = rsqrtf((sred[4] + sred[5] + sred[6] + sred[7]) * (1.f / (float)DM_) + 1e-6f);
    float4 wv = *(const float4*)(lnw + tid * 4);
    float4 bv = *(const float4*)(lnb + tid * 4);
    float4 o;
    o.x = (x[0] - mu) * rstd * wv.x + bv.x;
    o.y = (x[1] - mu) * rstd * wv.y + bv.y;
    o.z = (x[2] - mu) * rstd * wv.z + bv.z;
    o.w = (x[3] - mu) * rstd * wv.w + bv.w;
    *(float4*)(out + base) = o;
}

// =====================================================================
// OLD PATH kernels (fallback when workspace < 66 MB) — unchanged
// =====================================================================

__global__ __launch_bounds__(256) void gemm_qkv(const float* __restrict__ hs,
                                                const float* __restrict__ wq,
                                                const float* __restrict__ wk,
                                                const float* __restrict__ wv,
                                                float* __restrict__ q,
                                                float* __restrict__ k,
                                                float* __restrict__ v) {
    __shared__ alignas(16) __hip_bfloat16 Ah[64][40], Al[64][40];
    __shared__ alignas(16) __hip_bfloat16 Bh[128][40], Bl[128][40];
    int idx = blockIdx.x;
    int by = idx / 24;
    int r = idx % 24;
    int mode = r >> 3, bx = r & 7;
    const float* Bm = (mode == 0) ? wq : (mode == 1) ? wk : wv;
    float* C = (mode == 0) ? q : (mode == 1) ? k : v;
    float scale = (mode == 0) ? 0.125f : 1.0f;
    bool split = (mode < 2);

    int tid = threadIdx.x, lane = tid & 63, w = tid >> 6;
    int ml = lane & 15, kq = lane >> 4;

    f32x4 acc[4][2];
#pragma unroll
    for (int i = 0; i < 4; ++i)
#pragma unroll
        for (int j = 0; j < 2; ++j) acc[i][j] = (f32x4){0.f, 0.f, 0.f, 0.f};

    const float* Ab = hs + (size_t)(by * 64) * DM_;
    const float* Bb = Bm + bx * 128;
    int ar = tid >> 2, akq = (tid & 3) * 8;
    int bcol = tid & 127, bkh = tid >> 7;

    for (int k0 = 0; k0 < DM_; k0 += 32) {
        {
            float av[8];
            *(float4*)&av[0] = *(const float4*)(Ab + (size_t)ar * DM_ + k0 + akq);
            *(float4*)&av[4] = *(const float4*)(Ab + (size_t)ar * DM_ + k0 + akq + 4);
            short8 hv, lv;
#pragma unroll
            for (int e = 0; e < 8; ++e) {
                __hip_bfloat16 hb = __float2bfloat16(av[e]);
                hv[e] = ((BF16S){hb}).s;
                lv[e] = f2bs(av[e] - __bfloat162float(hb));
            }
            *(short8*)&Ah[ar][akq] = hv;
            if (split) *(short8*)&Al[ar][akq] = lv;
        }
        {
            float be[16];
            const float* bp = Bb + (size_t)(k0 + bkh * 16) * DM_ + bcol;
#pragma unroll
            for (int j = 0; j < 16; ++j) be[j] = bp[(size_t)j * DM_];
            short8 h0, h1, l0, l1;
#pragma unroll
            for (int e = 0; e < 8; ++e) {
                __hip_bfloat16 hb = __float2bfloat16(be[e]);
                h0[e] = ((BF16S){hb}).s;
                l0[e] = f2bs(be[e] - __bfloat162float(hb));
                __hip_bfloat16 hb2 = __float2bfloat16(be[e + 8]);
                h1[e] = ((BF16S){hb2}).s;
                l1[e] = f2bs(be[e + 8] - __bfloat162float(hb2));
            }
            *(short8*)&Bh[bcol][bkh * 16] = h0;
            *(short8*)&Bh[bcol][bkh * 16 + 8] = h1;
            if (split) {
                *(short8*)&Bl[bcol][bkh * 16] = l0;
                *(short8*)&Bl[bcol][bkh * 16 + 8] = l1;
            }
        }
        __syncthreads();
        short8 ah[4], al[4], bh[2], bl[2];
#pragma unroll
        for (int mt = 0; mt < 4; ++mt) ah[mt] = *(const short8*)&Ah[mt * 16 + ml][kq * 8];
#pragma unroll
        for (int nt = 0; nt < 2; ++nt) bh[nt] = *(const short8*)&Bh[w * 32 + nt * 16 + ml][kq * 8];
        if (split) {
#pragma unroll
            for (int mt = 0; mt < 4; ++mt) al[mt] = *(const short8*)&Al[mt * 16 + ml][kq * 8];
#pragma unroll
            for (int nt = 0; nt < 2; ++nt) bl[nt] = *(const short8*)&Bl[w * 32 + nt * 16 + ml][kq * 8];
#pragma unroll
            for (int mt = 0; mt < 4; ++mt)
#pragma unroll
                for (int nt = 0; nt < 2; ++nt) {
                    acc[mt][nt] = __builtin_amdgcn_mfma_f32_16x16x32_bf16(ah[mt], bh[nt], acc[mt][nt], 0, 0, 0);
                    acc[mt][nt] = __builtin_amdgcn_mfma_f32_16x16x32_bf16(ah[mt], bl[nt], acc[mt][nt], 0, 0, 0);
                    acc[mt][nt] = __builtin_amdgcn_mfma_f32_16x16x32_bf16(al[mt], bh[nt], acc[mt][nt], 0, 0, 0);
                }
        } else {
#pragma unroll
            for (int mt = 0; mt < 4; ++mt)
#pragma unroll
                for (int nt = 0; nt < 2; ++nt)
                    acc[mt][nt] = __builtin_amdgcn_mfma_f32_16x16x32_bf16(ah[mt], bh[nt], acc[mt][nt], 0, 0, 0);
        }
        __syncthreads();
    }
#pragma unroll
    for (int mt = 0; mt < 4; ++mt)
#pragma unroll
        for (int nt = 0; nt < 2; ++nt)
#pragma unroll
            for (int r2 = 0; r2 < 4; ++r2) {
                int row = by * 64 + mt * 16 + kq * 4 + r2;
                int col = bx * 128 + w * 32 + nt * 16 + ml;
                C[(size_t)row * DM_ + col] = acc[mt][nt][r2] * scale;
            }
}

__global__ __launch_bounds__(256) void mfma_gemm_v2(const float* __restrict__ A,
                                                    const float* __restrict__ Bm,
                                                    float* __restrict__ C,
                                                    int M, int N, int K, float scale) {
    __shared__ alignas(16) __hip_bfloat16 Asb[64][40];
    __shared__ alignas(16) __hip_bfloat16 Bsb[128][40];
    int nbx = N >> 7;
    int by = blockIdx.x / nbx, bx = blockIdx.x % nbx;
    int tid = threadIdx.x, lane = tid & 63, w = tid >> 6;
    int ml = lane & 15, kq = lane >> 4;

    f32x4 acc[4][2];
#pragma unroll
    for (int i = 0; i < 4; ++i)
#pragma unroll
        for (int j = 0; j < 2; ++j) acc[i][j] = (f32x4){0.f, 0.f, 0.f, 0.f};

    const float* Ab = A + (size_t)(by * 64) * K;
    const float* Bb = Bm + bx * 128;
    int ar = tid >> 2, akq = (tid & 3) * 8;
    int bcol = tid & 127, bkh = tid >> 7;

    for (int k0 = 0; k0 < K; k0 += 32) {
        {
            float av[8];
            *(float4*)&av[0] = *(const float4*)(Ab + (size_t)ar * K + k0 + akq);
            *(float4*)&av[4] = *(const float4*)(Ab + (size_t)ar * K + k0 + akq + 4);
            short8 hv;
#pragma unroll
            for (int e = 0; e < 8; ++e) hv[e] = f2bs(av[e]);
            *(short8*)&Asb[ar][akq] = hv;
        }
        {
            float be[16];
            const float* bp = Bb + (size_t)(k0 + bkh * 16) * N + bcol;
#pragma unroll
            for (int j = 0; j < 16; ++j) be[j] = bp[(size_t)j * N];
            short8 h0, h1;
#pragma unroll
            for (int e = 0; e < 8; ++e) {
                h0[e] = f2bs(be[e]);
                h1[e] = f2bs(be[e + 8]);
            }
            *(short8*)&Bsb[bcol][bkh * 16] = h0;
            *(short8*)&Bsb[bcol][bkh * 16 + 8] = h1;
        }
        __syncthreads();
        short8 af[4], bf[2];
#pragma unroll
        for (int mt = 0; mt < 4; ++mt) af[mt] = *(const short8*)&Asb[mt * 16 + ml][kq * 8];
#pragma unroll
        for (int nt = 0; nt < 2; ++nt) bf[nt] = *(const short8*)&Bsb[w * 32 + nt * 16 + ml][kq * 8];
#pragma unroll
        for (int mt = 0; mt < 4; ++mt)
#pragma unroll
            for (int nt = 0; nt < 2; ++nt)
                acc[mt][nt] = __builtin_amdgcn_mfma_f32_16x16x32_bf16(af[mt], bf[nt], acc[mt][nt], 0, 0, 0);
        __syncthreads();
    }
#pragma unroll
    for (int mt = 0; mt < 4; ++mt)
#pragma unroll
        for (int nt = 0; nt < 2; ++nt)
#pragma unroll
            for (int r = 0; r < 4; ++r) {
                int row = by * 64 + mt * 16 + kq * 4 + r;
                int col = bx * 128 + w * 32 + nt * 16 + ml;
                C[(size_t)row * N + col] = acc[mt][nt][r] * scale;
            }
}

__global__ void vmean_part(const float* __restrict__ v, float* __restrict__ vpart) {
    __shared__ float part[4][DK_];
    int blk = blockIdx.x;
    int bh = blk >> 6, ch = blk & (VCH_ - 1);
    int b = bh >> 4, h = bh & 15;
    int tid = threadIdx.x, wave = tid >> 6, lane = tid & 63;
    const float* vb = v + (size_t)(b * S_ + ch * 32) * DM_ + h * DK_;
    float s = 0.f;
#pragma unroll
    for (int i = 0; i < 8; ++i)
        s += vb[(size_t)(i * 4 + wave) * DM_ + lane];
    part[wave][lane] = s;
    __syncthreads();
    if (tid < DK_)
        vpart[(size_t)blk * DK_ + tid] =
            part[0][tid] + part[1][tid] + part[2][tid] + part[3][tid];
}

__global__ void vmean_comb(const float* __restrict__ vpart, float* __restrict__ vm) {
    int bh = blockIdx.x, lane = threadIdx.x;
    float s = 0.f;
    for (int c = 0; c < VCH_; ++c)
        s += vpart[(size_t)(bh * VCH_ + c) * DK_ + lane];
    vm[bh * DK_ + lane] = s * (1.f / (float)S_);
}

__global__ void gather_qsel(const float* __restrict__ q, const int* __restrict__ mtop,
                            float* __restrict__ qsel) {
    int bh = blockIdx.x;
    int b = bh >> 4, h = bh & 15;
    int tid = threadIdx.x;
    int u = tid >> 2, dq = (tid & 3) * 16;
    if (u >= 48) return;
    float* dst = qsel + ((size_t)bh * 48 + u) * 64 + dq;
    if (u < U_) {
        int row = mtop[bh * U_ + u];
        row = (row < 0) ? 0 : (row >= S_ ? S_ - 1 : row);
        const float* src = q + ((size_t)(b * S_ + row)) * DM_ + h * DK_ + dq;
#pragma unroll
        for (int j = 0; j < 16; j += 4) *(float4*)(dst + j) = *(const float4*)(src + j);
    } else {
        float4 z = {0.f, 0.f, 0.f, 0.f};
#pragma unroll
        for (int j = 0; j < 16; j += 4) *(float4*)(dst + j) = z;
    }
}

__global__ __launch_bounds__(256) void attn_chunk(const float* __restrict__ qsel,
                                                  const float* __restrict__ k,
                                                  const float* __restrict__ v,
                                                  float* __restrict__ Opart,
                                                  float* __restrict__ Mpart,
                                                  float* __restrict__ Lpart) {
    __shared__ alignas(16) __hip_bfloat16 Qs[48][72];
    __shared__ alignas(16) __hip_bfloat16 Vt[64][136];
    __shared__ alignas(16) __hip_bfloat16 Ps[48][136];
    __shared__ float mpart[4][48], lpart[4][48];
    __shared__ float mrow[48];
    int blk = blockIdx.x;
    int bh = blk / NCH_, ch = blk % NCH_;
    int b = bh >> 4, h = bh & 15;
    int c0 = ch * CH_;
    int tid = threadIdx.x, lane = tid & 63, w = tid >> 6;
    int ml = lane & 15, kq = lane >> 4;

    {
        int u = tid >> 2, dq = (tid & 3) * 16;
        if (u < 48) {
            const float* src = qsel + ((size_t)bh * 48 + u) * 64 + dq;
#pragma unroll
            for (int j = 0; j < 16; j += 4) {
                float4 v4 = *(const float4*)(src + j);
                Qs[u][dq + j + 0] = __float2bfloat16(v4.x);
                Qs[u][dq + j + 1] = __float2bfloat16(v4.y);
                Qs[u][dq + j + 2] = __float2bfloat16(v4.z);
                Qs[u][dq + j + 3] = __float2bfloat16(v4.w);
            }
        }
    }
    {
        int klocal = tid >> 1, dq = (tid & 1) * 32;
        const float* vr = v + (size_t)(b * S_ + c0 + klocal) * DM_ + h * DK_ + dq;
#pragma unroll
        for (int jj = 0; jj < 32; jj += 4) {
            float4 v4 = *(const float4*)(vr + jj);
            Vt[dq + jj + 0][klocal] = __float2bfloat16(v4.x);
            Vt[dq + jj + 1][klocal] = __float2bfloat16(v4.y);
            Vt[dq + jj + 2][klocal] = __float2bfloat16(v4.z);
            Vt[dq + jj + 3][klocal] = __float2bfloat16(v4.w);
        }
    }
    __syncthreads();

    const float* Kb = k + (size_t)b * S_ * DM_ + h * DK_;
    f32x4 sreg[3][2];
#pragma unroll
    for (int i = 0; i < 3; ++i)
#pragma unroll
        for (int j = 0; j < 2; ++j) sreg[i][j] = (f32x4){0.f, 0.f, 0.f, 0.f};
#pragma unroll
    for (int ntl = 0; ntl < 2; ++ntl) {
        int krow = c0 + (w * 2 + ntl) * 16 + ml;
        const float* kr = Kb + (size_t)krow * DM_;
        float4 x0 = *(const float4*)(kr + kq * 8);
        float4 x1 = *(const float4*)(kr + kq * 8 + 4);
        float4 y0 = *(const float4*)(kr + 32 + kq * 8);
        float4 y1 = *(const float4*)(kr + 32 + kq * 8 + 4);
        short8 b0, b1;
        b0[0] = f2bs(x0.x); b0[1] = f2bs(x0.y); b0[2] = f2bs(x0.z); b0[3] = f2bs(x0.w);
        b0[4] = f2bs(x1.x); b0[5] = f2bs(x1.y); b0[6] = f2bs(x1.z); b0[7] = f2bs(x1.w);
        b1[0] = f2bs(y0.x); b1[1] = f2bs(y0.y); b1[2] = f2bs(y0.z); b1[3] = f2bs(y0.w);
        b1[4] = f2bs(y1.x); b1[5] = f2bs(y1.y); b1[6] = f2bs(y1.z); b1[7] = f2bs(y1.w);
#pragma unroll
        for (int mt = 0; mt < 3; ++mt) {
            short8 a0 = *(const short8*)&Qs[mt * 16 + ml][kq * 8];
            short8 a1 = *(const short8*)&Qs[mt * 16 + ml][32 + kq * 8];
            sreg[mt][ntl] = __builtin_amdgcn_mfma_f32_16x16x32_bf16(a0, b0, sreg[mt][ntl], 0, 0, 0);
            sreg[mt][ntl] = __builtin_amdgcn_mfma_f32_16x16x32_bf16(a1, b1, sreg[mt][ntl], 0, 0, 0);
        }
    }

    {
        float vmx[3][4];
#pragma unroll
        for (int mt = 0; mt < 3; ++mt)
#pragma unroll
            for (int r = 0; r < 4; ++r)
                vmx[mt][r] = fmaxf(sreg[mt][0][r], sreg[mt][1][r]);
#pragma unroll
        for (int mask = 1; mask <= 8; mask <<= 1)
#pragma unroll
            for (int mt = 0; mt < 3; ++mt)
#pragma unroll
                for (int r = 0; r < 4; ++r)
                    vmx[mt][r] = fmaxf(vmx[mt][r], __shfl_xor(vmx[mt][r], mask, 64));
        if (ml == 0)
#pragma unroll
            for (int mt = 0; mt < 3; ++mt)
#pragma unroll
                for (int r = 0; r < 4; ++r)
                    mpart[w][mt * 16 + kq * 4 + r] = vmx[mt][r];
    }
    __syncthreads();
    if (tid < 48)
        mrow[tid] = fmaxf(fmaxf(mpart[0][tid], mpart[1][tid]),
                          fmaxf(mpart[2][tid], mpart[3][tid]));
    __syncthreads();

    {
        float vsum[3][4] = {{0.f}};
#pragma unroll
        for (int mt = 0; mt < 3; ++mt)
#pragma unroll
            for (int ntl = 0; ntl < 2; ++ntl) {
                int col = (w * 2 + ntl) * 16 + ml;
#pragma unroll
                for (int r = 0; r < 4; ++r) {
                    int row = mt * 16 + kq * 4 + r;
                    float p = __expf(sreg[mt][ntl][r] - mrow[row]);
                    Ps[row][col] = __float2bfloat16(p);
                    vsum[mt][r] += p;
                }
            }
#pragma unroll
        for (int mask = 1; mask <= 8; mask <<= 1)
#pragma unroll
            for (int mt = 0; mt < 3; ++mt)
#pragma unroll
                for (int r = 0; r < 4; ++r)
                    vsum[mt][r] += __shfl_xor(vsum[mt][r], mask, 64);
        if (ml == 0)
#pragma unroll
            for (int mt = 0; mt < 3; ++mt)
#pragma unroll
                for (int r = 0; r < 4; ++r)
                    lpart[w][mt * 16 + kq * 4 + r] = vsum[mt][r];
    }
    __syncthreads();

    f32x4 oreg[3];
#pragma unroll
    for (int i = 0; i < 3; ++i) oreg[i] = (f32x4){0.f, 0.f, 0.f, 0.f};
#pragma unroll
    for (int kt = 0; kt < 4; ++kt) {
        short8 bfq = *(const short8*)&Vt[w * 16 + ml][kt * 32 + kq * 8];
#pragma unroll
        for (int mt = 0; mt < 3; ++mt) {
            short8 af = *(const short8*)&Ps[mt * 16 + ml][kt * 32 + kq * 8];
            oreg[mt] = __builtin_amdgcn_mfma_f32_16x16x32_bf16(af, bfq, oreg[mt], 0, 0, 0);
        }
    }
#pragma unroll
    for (int mt = 0; mt < 3; ++mt)
#pragma unroll
        for (int r = 0; r < 4; ++r) {
            int row = mt * 16 + kq * 4 + r;
            Opart[((size_t)blk * 48 + row) * 64 + w * 16 + ml] = oreg[mt][r];
        }
    if (tid < 48) {
        Mpart[(size_t)blk * 48 + tid] = mrow[tid];
        Lpart[(size_t)blk * 48 + tid] =
            lpart[0][tid] + lpart[1][tid] + lpart[2][tid] + lpart[3][tid];
    }
}

__global__ void attn_combine(const float* __restrict__ Opart, const float* __restrict__ Mpart,
                             const float* __restrict__ Lpart, float* __restrict__ upd) {
    __shared__ float wfac[NCH_][48];
    __shared__ float lfin[48];
    int bh = blockIdx.x, tid = threadIdx.x;
    if (tid < 48) {
        float m = -1e30f;
        for (int c = 0; c < NCH_; ++c)
            m = fmaxf(m, Mpart[(size_t)(bh * NCH_ + c) * 48 + tid]);
        float l = 0.f;
        for (int c = 0; c < NCH_; ++c) {
            float wf = __expf(Mpart[(size_t)(bh * NCH_ + c) * 48 + tid] - m);
            wfac[c][tid] = wf;
            l += wf * Lpart[(size_t)(bh * NCH_ + c) * 48 + tid];
        }
        lfin[tid] = l;
    }
    __syncthreads();
    for (int e = tid; e < U_ * DK_; e += 256) {
        int row = e >> 6, col = e & 63;
        float o = 0.f;
        for (int c = 0; c < NCH_; ++c)
            o += wfac[c][row] * Opart[((size_t)(bh * NCH_ + c) * 48 + row) * 64 + col];
        upd[((size_t)bh * U_ + row) * DK_ + col] = o / lfin[row];
    }
}

__global__ void ctx_fill2(const float* __restrict__ vm, const float* __restrict__ upd,
                          const int* __restrict__ rowmap, float* __restrict__ ctx) {
    size_t i = ((size_t)blockIdx.x * 256 + threadIdx.x) * 4;
    int c = (int)(i & (DM_ - 1));
    size_t bl = i >> 10;
    int l = (int)(bl & (S_ - 1));
    int b = (int)(bl >> 11);
    int h = c >> 6, d = c & (DK_ - 1);
    int bh = b * H_ + h;
    int u = rowmap[(size_t)bh * S_ + l];
    float4 val;
    if (u >= 0)
        val = *(const float4*)(upd + ((size_t)bh * U_ + u) * DK_ + d);
    else
        val = *(const float4*)(vm + bh * DK_ + d);
    *(float4*)(ctx + i) = val;
}

// ================= launch =================

extern "C" void kernel_launch(void* const* d_in, const int* in_sizes, int n_in,
                              void* d_out, int out_size, void* d_ws, size_t ws_size,
                              hipStream_t stream) {
    if (n_in < 9 || d_ws == nullptr || d_out == nullptr) return;

    const float* hs  = (const float*)d_in[0];
    const float* wq  = (const float*)d_in[1];
    const float* wk  = (const float*)d_in[2];
    const float* wv  = (const float*)d_in[3];
    const float* fcw = (const float*)d_in[4];
    const float* fcb = (const float*)d_in[5];
    const float* lnw = (const float*)d_in[6];
    const float* lnb = (const float*)d_in[7];
    const int* idxs  = (const int*)d_in[8];

    const size_t MD = (size_t)B_ * S_ * DM_;  // 4194304
    const int M = B_ * S_;                    // 4096
    float* out = (float*)d_out;
    char* base = (char*)d_ws;

    if (ws_size >= 66ull * 1024 * 1024) {
        // ---- NEW PATH
        float* q   = (float*)base;                       // 16 MB [later ctx]
        float* k   = (float*)(base + (16ull << 20));     // 16 MB [later fcout]
        u16* Ahi   = (u16*)(base + (32ull << 20));       // 8 MB [later Opart]
        u16* Alo   = (u16*)(base + (40ull << 20));       // 8 MB
        u16* Wqh   = (u16*)(base + (48ull << 20));       // 6 x 2 MB
        u16* Wql   = Wqh + (1u << 20);
        u16* Wkh   = Wql + (1u << 20);
        u16* Wkl   = Wkh + (1u << 20);
        u16* Wvh   = Wkl + (1u << 20);
        u16* Fct   = Wvh + (1u << 20);
        float* mbuf  = (float*)(base + (60ull << 20));         // B*H*S = 65536 f
        float* vmean = mbuf + (size_t)B_ * H_ * S_;            // 2048 f (raw sum)
        int* mtop    = (int*)(vmean + B_ * H_ * DK_);          // 1280 i
        int* rowmap  = (int*)(mtop + B_ * H_ * U_);            // 65536 i
        // vb16 + kb16 exactly fill d_out (8 + 8 MB); dead until ln overwrites.
        u16* vb16 = (u16*)out;
        u16* kb16 = vb16 + MD;
        // Opart over Ahi (dead after gemm_qkv); q stays live for attn gather
        float* Opart = (float*)(base + (32ull << 20));
        float* Mpart = Opart + (size_t)512 * 48 * 64;
        float* Lpart = Mpart + (size_t)512 * 48;
        u16* ctxb = (u16*)q;     // after attn (q dead post-attn_chunk3)
        float* fcout = k;        // after k dead (post-attn_chunk3)

        conv_all<<<3073, 256, 0, stream>>>(hs, wq, wk, wv, fcw, Ahi, Alo,
                                           Wqh, Wql, Wkh, Wkl, Wvh, Fct, vmean);
        gemm_qkv_v9<<<768, 256, 0, stream>>>(Ahi, Alo, Wqh, Wql, Wkh, Wkl, Wvh,
                                             q, k, kb16, vb16, vmean);

        m_score_v3<<<(B_ * H_ * S_) / 4, 256, 0, stream>>>(q, k, idxs, mbuf, rowmap);
        topk_wave<<<B_ * H_, 64, 0, stream>>>(mbuf, mtop, rowmap);

        attn_chunk3<<<B_ * H_ * NCH_, 256, 0, stream>>>(q, mtop, kb16, vb16,
                                                        Opart, Mpart, Lpart);

        ctx_fill4<<<(int)(MD / 1024), 256, 0, stream>>>(vmean, Opart, Mpart, Lpart, rowmap, ctxb);

        gemm_fc_v8<<<256, 256, 0, stream>>>(ctxb, Fct, fcout);
        ln_kernel<<<M, 256, 0, stream>>>(fcout, fcb, hs, lnw, lnb, out);
        return;
    }

    // ---- OLD PATH (fallback, needs >= 34 MB)
    if (ws_size < 34ull * 1024 * 1024) return;
    float* ws = (float*)d_ws;
    float* q = ws;
    float* k = ws + MD;
    float* mbuf = ws + 2 * MD;
    float* vmean = mbuf + (size_t)B_ * H_ * S_;
    float* upd = vmean + B_ * H_ * DK_;
    int* mtop = (int*)(upd + (size_t)B_ * H_ * U_ * DK_);
    float* qsel = (float*)(mtop + B_ * H_ * U_);
    float* vpart = qsel + (size_t)B_ * H_ * 48 * 64;
    int* rowmap = (int*)(vpart + (size_t)B_ * H_ * VCH_ * DK_);
    float* v = out;
    float* Opart = q;
    float* Mpart = Opart + (size_t)512 * 48 * 64;
    float* Lpart = Mpart + (size_t)512 * 48;
    float* ctx = q;
    float* fcout = k;

    gemm_qkv<<<1536, 256, 0, stream>>>(hs, wq, wk, wv, q, k, v);

    m_score_v3<<<(B_ * H_ * S_) / 4, 256, 0, stream>>>(q, k, idxs, mbuf, rowmap);
    topk_wave<<<B_ * H_, 64, 0, stream>>>(mbuf, mtop, rowmap);
    vmean_part<<<B_ * H_ * VCH_, 256, 0, stream>>>(v, vpart);
    vmean_comb<<<B_ * H_, 64, 0, stream>>>(vpart, vmean);
    gather_qsel<<<B_ * H_, 256, 0, stream>>>(q, mtop, qsel);

    attn_chunk<<<B_ * H_ * NCH_, 256, 0, stream>>>(qsel, k, v, Opart, Mpart, Lpart);
    attn_combine<<<B_ * H_, 256, 0, stream>>>(Opart, Mpart, Lpart, upd);

    ctx_fill2<<<(int)(MD / 1024), 256, 0, stream>>>(vmean, upd, rowmap, ctx);

    mfma_gemm_v2<<<512, 256, 0, stream>>>(ctx, fcw, fcout, M, DM_, DM_, 1.0f);
    ln_kernel<<<M, 256, 0, stream>>>(fcout, fcb, hs, lnw, lnb, out);
}